// Round 1
// baseline (583.712 us; speedup 1.0000x reference)
//
#include <hip/hip_runtime.h>
#include <hip/hip_bf16.h>
#include <math.h>

// Problem constants (from reference)
#define B_    2
#define N_    2048
#define D_    1024
#define DHAT_ 512
#define H_    16
#define F_    32      // qk head dim
#define G_    64      // v head dim
#define CHUNK 128
#define NCHUNK (N_ / CHUNK)   // 16

__device__ __forceinline__ float phi_fn(float x) {
    // elu(x)+1 : x>0 -> x+1 ; x<=0 -> exp(x)
    return x > 0.0f ? x + 1.0f : expf(x);
}

// ---------------------------------------------------------------------------
// Generic tiled SGEMM: C[M,N] = A[M,K] @ W[K,N] + bias[N], optional phi.
// BM=BN=64, BK=16, 256 threads, 4x4 micro-tile per thread.
// M % 64 == 0, N % 64 == 0, K % 16 == 0 (true for all four GEMMs here).
// ---------------------------------------------------------------------------
template<bool PHI>
__global__ __launch_bounds__(256) void gemm_bias_kernel(
    const float* __restrict__ A, const float* __restrict__ W,
    const float* __restrict__ bias, float* __restrict__ C,
    int M, int K, int N)
{
    __shared__ float As[16][64];   // [k][m]
    __shared__ float Ws[16][68];   // [k][n], padded to 68 (16B-aligned rows)

    const int bm  = blockIdx.y * 64;
    const int bn  = blockIdx.x * 64;
    const int tid = threadIdx.x;

    const int tm = (tid >> 4) << 2;   // 0..60
    const int tn = (tid & 15) << 2;   // 0..60

    // load assignments
    const int lm  = tid >> 2;          // A row 0..63
    const int lk  = (tid & 3) << 2;    // A k offset 0,4,8,12
    const int wkk = tid >> 4;          // W k 0..15
    const int wn  = (tid & 15) << 2;   // W n 0..60

    float acc[4][4] = {};

    for (int k0 = 0; k0 < K; k0 += 16) {
        float4 a4 = *reinterpret_cast<const float4*>(&A[(size_t)(bm + lm) * K + k0 + lk]);
        float4 w4 = *reinterpret_cast<const float4*>(&W[(size_t)(k0 + wkk) * N + bn + wn]);
        __syncthreads();   // previous tile fully consumed
        As[lk + 0][lm] = a4.x;
        As[lk + 1][lm] = a4.y;
        As[lk + 2][lm] = a4.z;
        As[lk + 3][lm] = a4.w;
        *reinterpret_cast<float4*>(&Ws[wkk][wn]) = w4;
        __syncthreads();
        #pragma unroll
        for (int k = 0; k < 16; ++k) {
            float4 av = *reinterpret_cast<const float4*>(&As[k][tm]);
            float4 bv = *reinterpret_cast<const float4*>(&Ws[k][tn]);
            acc[0][0] += av.x * bv.x; acc[0][1] += av.x * bv.y; acc[0][2] += av.x * bv.z; acc[0][3] += av.x * bv.w;
            acc[1][0] += av.y * bv.x; acc[1][1] += av.y * bv.y; acc[1][2] += av.y * bv.z; acc[1][3] += av.y * bv.w;
            acc[2][0] += av.z * bv.x; acc[2][1] += av.z * bv.y; acc[2][2] += av.z * bv.z; acc[2][3] += av.z * bv.w;
            acc[3][0] += av.w * bv.x; acc[3][1] += av.w * bv.y; acc[3][2] += av.w * bv.z; acc[3][3] += av.w * bv.w;
        }
    }

    const float4 bb = *reinterpret_cast<const float4*>(&bias[bn + tn]);
    #pragma unroll
    for (int i = 0; i < 4; ++i) {
        float4 v;
        v.x = acc[i][0] + bb.x;
        v.y = acc[i][1] + bb.y;
        v.z = acc[i][2] + bb.z;
        v.w = acc[i][3] + bb.w;
        if (PHI) {
            v.x = phi_fn(v.x); v.y = phi_fn(v.y); v.z = phi_fn(v.z); v.w = phi_fn(v.w);
        }
        *reinterpret_cast<float4*>(&C[(size_t)(bm + tm + i) * N + bn + tn]) = v;
    }
}

// ---------------------------------------------------------------------------
// Pass A: per-chunk sums  S_c[f][g] = sum_{t in chunk} K[t][f]*V[t][g]
//                         z_c[f]    = sum_{t in chunk} K[t][f]
// grid (NCHUNK, H, B), 256 threads. Thread owns (f = tid>>3, g0 = (tid&7)*8).
// ---------------------------------------------------------------------------
__global__ __launch_bounds__(256) void chunk_kv_kernel(
    const float* __restrict__ Kb, const float* __restrict__ Vb,
    float* __restrict__ Sb, float* __restrict__ zb)
{
    __shared__ float Kl[CHUNK][F_];   // 16 KB
    __shared__ float Vl[CHUNK][G_];   // 32 KB

    const int c = blockIdx.x, h = blockIdx.y, b = blockIdx.z;
    const int tid = threadIdx.x;
    const size_t row0 = (size_t)b * N_ + (size_t)c * CHUNK;

    #pragma unroll
    for (int r = 0; r < 4; ++r) {               // K chunk: 1024 float4
        int fi = r * 256 + tid;
        int t = fi >> 3, f4 = (fi & 7) << 2;
        *reinterpret_cast<float4*>(&Kl[t][f4]) =
            *reinterpret_cast<const float4*>(&Kb[(row0 + t) * DHAT_ + h * F_ + f4]);
    }
    #pragma unroll
    for (int r = 0; r < 8; ++r) {               // V chunk: 2048 float4
        int fi = r * 256 + tid;
        int t = fi >> 4, g4 = (fi & 15) << 2;
        *reinterpret_cast<float4*>(&Vl[t][g4]) =
            *reinterpret_cast<const float4*>(&Vb[(row0 + t) * D_ + h * G_ + g4]);
    }
    __syncthreads();

    const int f  = tid >> 3;
    const int g0 = (tid & 7) << 3;
    float acc[8] = {};
    float zacc = 0.0f;

    for (int t = 0; t < CHUNK; ++t) {
        float kf = Kl[t][f];
        zacc += kf;
        float4 v0 = *reinterpret_cast<const float4*>(&Vl[t][g0]);
        float4 v1 = *reinterpret_cast<const float4*>(&Vl[t][g0 + 4]);
        acc[0] += kf * v0.x; acc[1] += kf * v0.y; acc[2] += kf * v0.z; acc[3] += kf * v0.w;
        acc[4] += kf * v1.x; acc[5] += kf * v1.y; acc[6] += kf * v1.z; acc[7] += kf * v1.w;
    }

    const size_t sbase = ((size_t)((b * H_ + h) * NCHUNK + c)) * (F_ * G_);
    *reinterpret_cast<float4*>(&Sb[sbase + f * G_ + g0])     = make_float4(acc[0], acc[1], acc[2], acc[3]);
    *reinterpret_cast<float4*>(&Sb[sbase + f * G_ + g0 + 4]) = make_float4(acc[4], acc[5], acc[6], acc[7]);
    if ((tid & 7) == 0)
        zb[((size_t)(b * H_ + h) * NCHUNK + c) * F_ + f] = zacc;
}

// ---------------------------------------------------------------------------
// Pass B: in-place exclusive prefix scan of chunk states per (b,h).
// grid (B*H), 256 threads. 16 chunks, trivial.
// ---------------------------------------------------------------------------
__global__ __launch_bounds__(256) void scan_kernel(float* __restrict__ Sb, float* __restrict__ zb)
{
    const int bh = blockIdx.x;
    const int tid = threadIdx.x;
    float4 p0 = make_float4(0, 0, 0, 0), p1 = make_float4(0, 0, 0, 0);
    for (int c = 0; c < NCHUNK; ++c) {
        size_t base = ((size_t)bh * NCHUNK + c) * (F_ * G_) + (size_t)tid * 8;
        float4 t0 = *reinterpret_cast<const float4*>(&Sb[base]);
        float4 t1 = *reinterpret_cast<const float4*>(&Sb[base + 4]);
        *reinterpret_cast<float4*>(&Sb[base])     = p0;
        *reinterpret_cast<float4*>(&Sb[base + 4]) = p1;
        p0.x += t0.x; p0.y += t0.y; p0.z += t0.z; p0.w += t0.w;
        p1.x += t1.x; p1.y += t1.y; p1.z += t1.z; p1.w += t1.w;
    }
    if (tid < F_) {
        float pz = 0.0f;
        for (int c = 0; c < NCHUNK; ++c) {
            size_t base = ((size_t)bh * NCHUNK + c) * F_ + tid;
            float t = zb[base];
            zb[base] = pz;
            pz += t;
        }
    }
}

// ---------------------------------------------------------------------------
// Pass C: per-chunk outputs.
// out[t][g] = (q_t . (S_prefix + sum_{s<=t} K_s (x) V_s))[g] * Z_t
// Z_t = 1/(q_t . (z_prefix + sum_{s<=t} K_s) + 1e-6)
// grid (NCHUNK, H, B), 256 threads: thread = (t = tid>>1, half g0 = (tid&1)*32)
// ---------------------------------------------------------------------------
__global__ __launch_bounds__(256) void attn_out_kernel(
    const float* __restrict__ Qb, const float* __restrict__ Kb,
    const float* __restrict__ Vb, const float* __restrict__ Sb,
    const float* __restrict__ zb, float* __restrict__ Ob)
{
    __shared__ float Kl[CHUNK][F_];   // 16 KB
    __shared__ float Vl[CHUNK][G_];   // 32 KB
    __shared__ float Sl[F_][G_];      // 8 KB
    __shared__ float zl[F_];

    const int c = blockIdx.x, h = blockIdx.y, b = blockIdx.z;
    const int tid = threadIdx.x;
    const size_t row0 = (size_t)b * N_ + (size_t)c * CHUNK;

    #pragma unroll
    for (int r = 0; r < 4; ++r) {
        int fi = r * 256 + tid;
        int t = fi >> 3, f4 = (fi & 7) << 2;
        *reinterpret_cast<float4*>(&Kl[t][f4]) =
            *reinterpret_cast<const float4*>(&Kb[(row0 + t) * DHAT_ + h * F_ + f4]);
    }
    #pragma unroll
    for (int r = 0; r < 8; ++r) {
        int fi = r * 256 + tid;
        int t = fi >> 4, g4 = (fi & 15) << 2;
        *reinterpret_cast<float4*>(&Vl[t][g4]) =
            *reinterpret_cast<const float4*>(&Vb[(row0 + t) * D_ + h * G_ + g4]);
    }
    const size_t sbase = ((size_t)((b * H_ + h) * NCHUNK + c)) * (F_ * G_);
    #pragma unroll
    for (int r = 0; r < 2; ++r) {
        int fi = r * 256 + tid;   // 0..511 float4s
        *reinterpret_cast<float4*>(&Sl[0][0] + (size_t)fi * 4) =  // note: float4* arithmetic on base
            *reinterpret_cast<const float4*>(&Sb[sbase + (size_t)fi * 4]);
    }
    if (tid < F_) zl[tid] = zb[((size_t)(b * H_ + h) * NCHUNK + c) * F_ + tid];

    // Q row into registers
    const int t  = tid >> 1;
    const int g0 = (tid & 1) << 5;   // 0 or 32
    float q[F_];
    {
        const float* qrow = &Qb[(row0 + t) * DHAT_ + h * F_];
        #pragma unroll
        for (int f4 = 0; f4 < F_; f4 += 4) {
            float4 qq = *reinterpret_cast<const float4*>(&qrow[f4]);
            q[f4] = qq.x; q[f4 + 1] = qq.y; q[f4 + 2] = qq.z; q[f4 + 3] = qq.w;
        }
    }
    __syncthreads();

    float acc[32];
    #pragma unroll
    for (int j = 0; j < 32; ++j) acc[j] = 0.0f;
    float den = 1e-6f;

    // inter-chunk contribution: q . S_prefix, q . z_prefix
    #pragma unroll 4
    for (int f = 0; f < F_; ++f) {
        float qf = q[f];
        #pragma unroll
        for (int j4 = 0; j4 < 32; j4 += 4) {
            float4 s4 = *reinterpret_cast<const float4*>(&Sl[f][g0 + j4]);
            acc[j4 + 0] += qf * s4.x;
            acc[j4 + 1] += qf * s4.y;
            acc[j4 + 2] += qf * s4.z;
            acc[j4 + 3] += qf * s4.w;
        }
    }
    #pragma unroll
    for (int f = 0; f < F_; ++f) den += q[f] * zl[f];

    // intra-chunk causal contribution
    for (int s = 0; s <= t; ++s) {
        float a = 0.0f;
        #pragma unroll
        for (int f4 = 0; f4 < F_; f4 += 4) {
            float4 k4 = *reinterpret_cast<const float4*>(&Kl[s][f4]);
            a += q[f4] * k4.x + q[f4 + 1] * k4.y + q[f4 + 2] * k4.z + q[f4 + 3] * k4.w;
        }
        den += a;
        #pragma unroll
        for (int j4 = 0; j4 < 32; j4 += 4) {
            float4 v4 = *reinterpret_cast<const float4*>(&Vl[s][g0 + j4]);
            acc[j4 + 0] += a * v4.x;
            acc[j4 + 1] += a * v4.y;
            acc[j4 + 2] += a * v4.z;
            acc[j4 + 3] += a * v4.w;
        }
    }

    const float zinv = 1.0f / den;
    float* orow = &Ob[(row0 + t) * D_ + h * G_ + g0];
    #pragma unroll
    for (int j4 = 0; j4 < 32; j4 += 4) {
        float4 o;
        o.x = acc[j4 + 0] * zinv;
        o.y = acc[j4 + 1] * zinv;
        o.z = acc[j4 + 2] * zinv;
        o.w = acc[j4 + 3] * zinv;
        *reinterpret_cast<float4*>(&orow[j4]) = o;
    }
}

// ---------------------------------------------------------------------------
extern "C" void kernel_launch(void* const* d_in, const int* in_sizes, int n_in,
                              void* d_out, int out_size, void* d_ws, size_t ws_size,
                              hipStream_t stream) {
    const float* x  = (const float*)d_in[0];
    const float* wq = (const float*)d_in[1];
    const float* bq = (const float*)d_in[2];
    const float* wk = (const float*)d_in[3];
    const float* bk = (const float*)d_in[4];
    const float* wv = (const float*)d_in[5];
    const float* bv = (const float*)d_in[6];
    const float* wo = (const float*)d_in[7];
    const float* bo = (const float*)d_in[8];
    float* out = (float*)d_out;

    float* ws = (float*)d_ws;
    float* Qb = ws;                                   // B*N*DHAT
    float* Kb = Qb + (size_t)B_ * N_ * DHAT_;         // B*N*DHAT
    float* Vb = Kb + (size_t)B_ * N_ * DHAT_;         // B*N*D
    float* Ob = Vb + (size_t)B_ * N_ * D_;            // B*N*D
    float* Sb = Ob + (size_t)B_ * N_ * D_;            // B*H*NCHUNK*F*G
    float* zb = Sb + (size_t)B_ * H_ * NCHUNK * F_ * G_;  // B*H*NCHUNK*F

    const int M = B_ * N_;   // 4096

    // QKV projections
    gemm_bias_kernel<true ><<<dim3(DHAT_ / 64, M / 64), 256, 0, stream>>>(x, wq, bq, Qb, M, D_, DHAT_);
    gemm_bias_kernel<true ><<<dim3(DHAT_ / 64, M / 64), 256, 0, stream>>>(x, wk, bk, Kb, M, D_, DHAT_);
    gemm_bias_kernel<false><<<dim3(D_    / 64, M / 64), 256, 0, stream>>>(x, wv, bv, Vb, M, D_, D_);

    // chunked linear attention
    chunk_kv_kernel<<<dim3(NCHUNK, H_, B_), 256, 0, stream>>>(Kb, Vb, Sb, zb);
    scan_kernel<<<dim3(B_ * H_), 256, 0, stream>>>(Sb, zb);
    attn_out_kernel<<<dim3(NCHUNK, H_, B_), 256, 0, stream>>>(Qb, Kb, Vb, Sb, zb, Ob);

    // output projection
    gemm_bias_kernel<false><<<dim3(D_ / 64, M / 64), 256, 0, stream>>>(Ob, wo, bo, out, M, D_, D_);
}

// Round 3
// 264.161 us; speedup vs baseline: 2.2097x; 2.2097x over previous
//
#include <hip/hip_runtime.h>
#include <hip/hip_bf16.h>
#include <math.h>

// Problem constants (from reference)
#define B_    2
#define N_    2048
#define D_    1024
#define DHAT_ 512
#define H_    16
#define F_    32      // qk head dim
#define G_    64      // v head dim
#define CHUNK 128
#define NCHUNK (N_ / CHUNK)   // 16

typedef __attribute__((ext_vector_type(8))) short bf16x8;
typedef __attribute__((ext_vector_type(4))) float f32x4;

__device__ __forceinline__ float phi_fn(float x) {
    // elu(x)+1 : x>0 -> x+1 ; x<=0 -> exp(x)
    return x > 0.0f ? x + 1.0f : expf(x);
}

__device__ __forceinline__ ushort f2bf(float f) {
    // round-to-nearest-even fp32 -> bf16
    unsigned u = __float_as_uint(f);
    u += 0x7FFFu + ((u >> 16) & 1u);
    return (ushort)(u >> 16);
}

#define GLOAD_LDS16(g, l) __builtin_amdgcn_global_load_lds( \
    (const __attribute__((address_space(1))) void*)(g),     \
    (__attribute__((address_space(3))) void*)(l), 16, 0, 0)

// ---------------------------------------------------------------------------
// fp32 -> bf16 elementwise convert (4 elems/thread)
// ---------------------------------------------------------------------------
__global__ __launch_bounds__(256) void convert_bf16_kernel(
    const float* __restrict__ in, ushort* __restrict__ out, int n4)
{
    int i = blockIdx.x * 256 + threadIdx.x;
    if (i < n4) {
        float4 a = reinterpret_cast<const float4*>(in)[i];
        ushort4 o;
        o.x = f2bf(a.x); o.y = f2bf(a.y); o.z = f2bf(a.z); o.w = f2bf(a.w);
        reinterpret_cast<ushort4*>(out)[i] = o;
    }
}

// ---------------------------------------------------------------------------
// W[K][N] fp32  ->  Wt[N][K] bf16   (32x32 LDS tile transpose)
// grid (N/32, K/32), 256 threads (32x8)
// ---------------------------------------------------------------------------
__global__ __launch_bounds__(256) void transpose_bf16_kernel(
    const float* __restrict__ W, ushort* __restrict__ Wt, int K, int N)
{
    __shared__ ushort tile[32][33];
    const int ti = blockIdx.y * 32;   // K base
    const int tj = blockIdx.x * 32;   // N base
    const int tx = threadIdx.x & 31, ty = threadIdx.x >> 5;   // ty 0..7
    #pragma unroll
    for (int r = 0; r < 4; ++r)
        tile[ty + r * 8][tx] = f2bf(W[(size_t)(ti + ty + r * 8) * N + tj + tx]);
    __syncthreads();
    #pragma unroll
    for (int r = 0; r < 4; ++r)
        Wt[(size_t)(tj + ty + r * 8) * K + ti + tx] = tile[tx][ty + r * 8];
}

// ---------------------------------------------------------------------------
// MFMA bf16 GEMM: C[M,N] = A[M,K] @ W[K,N] + bias (optional phi), fp32 out.
// A: bf16 row-major [M][K]; Wt: bf16 [N][K] (= W^T row-major).
// BM=BN=128, BK=32; 256 threads = 4 waves (2x2), 64x64 per wave, 4x4 frags.
// m97 structure: global_load_lds(16B) staging, 2 barriers/K-step.
// ---------------------------------------------------------------------------
template<bool PHI>
__global__ __launch_bounds__(256) void mfma_gemm_kernel(
    const ushort* __restrict__ A, const ushort* __restrict__ Wt,
    const float* __restrict__ bias, float* __restrict__ C,
    int M, int K, int N)
{
    __shared__ ushort Asm[128 * 32];   // [row][k] 8 KB
    __shared__ ushort Bsm[128 * 32];   // [col][k] 8 KB

    const int tid  = threadIdx.x;
    const int lane = tid & 63;
    const int wave = tid >> 6;
    const int wr   = wave >> 1, wc = wave & 1;
    const int brow = blockIdx.y * 128, bcol = blockIdx.x * 128;
    const int l16  = lane & 15, lk = lane >> 4;   // lk 0..3

    f32x4 acc[4][4];
    #pragma unroll
    for (int m = 0; m < 4; ++m)
        #pragma unroll
        for (int n = 0; n < 4; ++n)
            acc[m][n] = (f32x4){0.f, 0.f, 0.f, 0.f};

    for (int k0 = 0; k0 < K; k0 += 32) {
        __syncthreads();   // all waves done reading LDS from previous step
        #pragma unroll
        for (int r = 0; r < 2; ++r) {
            int fi  = r * 256 + tid;          // 0..511 chunks of 8 bf16
            int row = fi >> 2;                // 0..127
            int c8  = (fi & 3) << 3;          // 0,8,16,24
            GLOAD_LDS16(&A [(size_t)(brow + row) * K + k0 + c8], &Asm[fi * 8]);
            GLOAD_LDS16(&Wt[(size_t)(bcol + row) * K + k0 + c8], &Bsm[fi * 8]);
        }
        __syncthreads();   // compiler drains vmcnt(0) before barrier

        bf16x8 af[4], bf[4];
        #pragma unroll
        for (int m = 0; m < 4; ++m)
            af[m] = *reinterpret_cast<const bf16x8*>(&Asm[(wr * 64 + m * 16 + l16) * 32 + lk * 8]);
        #pragma unroll
        for (int n = 0; n < 4; ++n)
            bf[n] = *reinterpret_cast<const bf16x8*>(&Bsm[(wc * 64 + n * 16 + l16) * 32 + lk * 8]);
        #pragma unroll
        for (int m = 0; m < 4; ++m)
            #pragma unroll
            for (int n = 0; n < 4; ++n)
                acc[m][n] = __builtin_amdgcn_mfma_f32_16x16x32_bf16(af[m], bf[n], acc[m][n], 0, 0, 0);
    }

    // epilogue: C/D layout col=lane&15, row=(lane>>4)*4+j  [m89/m91 verified]
    #pragma unroll
    for (int n = 0; n < 4; ++n) {
        int col = bcol + wc * 64 + n * 16 + l16;
        float bv = bias[col];
        #pragma unroll
        for (int m = 0; m < 4; ++m) {
            int row0 = brow + wr * 64 + m * 16 + lk * 4;
            #pragma unroll
            for (int j = 0; j < 4; ++j) {
                float v = acc[m][n][j] + bv;
                if (PHI) v = phi_fn(v);
                C[(size_t)(row0 + j) * N + col] = v;
            }
        }
    }
}

// ---------------------------------------------------------------------------
// Pass A: per-chunk sums  S_c[f][g] = sum_{t in chunk} K[t][f]*V[t][g]
//                         z_c[f]    = sum_{t in chunk} K[t][f]
// grid (NCHUNK, H, B), 256 threads.
// ---------------------------------------------------------------------------
__global__ __launch_bounds__(256) void chunk_kv_kernel(
    const float* __restrict__ Kb, const float* __restrict__ Vb,
    float* __restrict__ Sb, float* __restrict__ zb)
{
    __shared__ float Kl[CHUNK][F_];   // 16 KB
    __shared__ float Vl[CHUNK][G_];   // 32 KB

    const int c = blockIdx.x, h = blockIdx.y, b = blockIdx.z;
    const int tid = threadIdx.x;
    const size_t row0 = (size_t)b * N_ + (size_t)c * CHUNK;

    #pragma unroll
    for (int r = 0; r < 4; ++r) {               // K chunk: 1024 float4
        int fi = r * 256 + tid;
        int t = fi >> 3, f4 = (fi & 7) << 2;
        *reinterpret_cast<float4*>(&Kl[t][f4]) =
            *reinterpret_cast<const float4*>(&Kb[(row0 + t) * DHAT_ + h * F_ + f4]);
    }
    #pragma unroll
    for (int r = 0; r < 8; ++r) {               // V chunk: 2048 float4
        int fi = r * 256 + tid;
        int t = fi >> 4, g4 = (fi & 15) << 2;
        *reinterpret_cast<float4*>(&Vl[t][g4]) =
            *reinterpret_cast<const float4*>(&Vb[(row0 + t) * D_ + h * G_ + g4]);
    }
    __syncthreads();

    const int f  = tid >> 3;
    const int g0 = (tid & 7) << 3;
    float acc[8] = {};
    float zacc = 0.0f;

    for (int t = 0; t < CHUNK; ++t) {
        float kf = Kl[t][f];
        zacc += kf;
        float4 v0 = *reinterpret_cast<const float4*>(&Vl[t][g0]);
        float4 v1 = *reinterpret_cast<const float4*>(&Vl[t][g0 + 4]);
        acc[0] += kf * v0.x; acc[1] += kf * v0.y; acc[2] += kf * v0.z; acc[3] += kf * v0.w;
        acc[4] += kf * v1.x; acc[5] += kf * v1.y; acc[6] += kf * v1.z; acc[7] += kf * v1.w;
    }

    const size_t sbase = ((size_t)((b * H_ + h) * NCHUNK + c)) * (F_ * G_);
    *reinterpret_cast<float4*>(&Sb[sbase + f * G_ + g0])     = make_float4(acc[0], acc[1], acc[2], acc[3]);
    *reinterpret_cast<float4*>(&Sb[sbase + f * G_ + g0 + 4]) = make_float4(acc[4], acc[5], acc[6], acc[7]);
    if ((tid & 7) == 0)
        zb[((size_t)(b * H_ + h) * NCHUNK + c) * F_ + f] = zacc;
}

// ---------------------------------------------------------------------------
// Pass B: in-place exclusive prefix scan of chunk states per (b,h).
// ---------------------------------------------------------------------------
__global__ __launch_bounds__(256) void scan_kernel(float* __restrict__ Sb, float* __restrict__ zb)
{
    const int bh = blockIdx.x;
    const int tid = threadIdx.x;
    float4 p0 = make_float4(0, 0, 0, 0), p1 = make_float4(0, 0, 0, 0);
    for (int c = 0; c < NCHUNK; ++c) {
        size_t base = ((size_t)bh * NCHUNK + c) * (F_ * G_) + (size_t)tid * 8;
        float4 t0 = *reinterpret_cast<const float4*>(&Sb[base]);
        float4 t1 = *reinterpret_cast<const float4*>(&Sb[base + 4]);
        *reinterpret_cast<float4*>(&Sb[base])     = p0;
        *reinterpret_cast<float4*>(&Sb[base + 4]) = p1;
        p0.x += t0.x; p0.y += t0.y; p0.z += t0.z; p0.w += t0.w;
        p1.x += t1.x; p1.y += t1.y; p1.z += t1.z; p1.w += t1.w;
    }
    if (tid < F_) {
        float pz = 0.0f;
        for (int c = 0; c < NCHUNK; ++c) {
            size_t base = ((size_t)bh * NCHUNK + c) * F_ + tid;
            float t = zb[base];
            zb[base] = pz;
            pz += t;
        }
    }
}

// ---------------------------------------------------------------------------
// Pass C: per-chunk outputs, written directly as bf16 (feeds final GEMM).
// ---------------------------------------------------------------------------
__global__ __launch_bounds__(256) void attn_out_kernel(
    const float* __restrict__ Qb, const float* __restrict__ Kb,
    const float* __restrict__ Vb, const float* __restrict__ Sb,
    const float* __restrict__ zb, ushort* __restrict__ Obf)
{
    __shared__ float Kl[CHUNK][F_];   // 16 KB
    __shared__ float Vl[CHUNK][G_];   // 32 KB
    __shared__ float Sl[F_][G_];      // 8 KB
    __shared__ float zl[F_];

    const int c = blockIdx.x, h = blockIdx.y, b = blockIdx.z;
    const int tid = threadIdx.x;
    const size_t row0 = (size_t)b * N_ + (size_t)c * CHUNK;

    #pragma unroll
    for (int r = 0; r < 4; ++r) {
        int fi = r * 256 + tid;
        int t = fi >> 3, f4 = (fi & 7) << 2;
        *reinterpret_cast<float4*>(&Kl[t][f4]) =
            *reinterpret_cast<const float4*>(&Kb[(row0 + t) * DHAT_ + h * F_ + f4]);
    }
    #pragma unroll
    for (int r = 0; r < 8; ++r) {
        int fi = r * 256 + tid;
        int t = fi >> 4, g4 = (fi & 15) << 2;
        *reinterpret_cast<float4*>(&Vl[t][g4]) =
            *reinterpret_cast<const float4*>(&Vb[(row0 + t) * D_ + h * G_ + g4]);
    }
    const size_t sbase = ((size_t)((b * H_ + h) * NCHUNK + c)) * (F_ * G_);
    #pragma unroll
    for (int r = 0; r < 2; ++r) {
        int fi = r * 256 + tid;   // 512 float4s total
        *(reinterpret_cast<float4*>(&Sl[0][0]) + fi) =
            *(reinterpret_cast<const float4*>(&Sb[sbase]) + fi);
    }
    if (tid < F_) zl[tid] = zb[((size_t)(b * H_ + h) * NCHUNK + c) * F_ + tid];

    const int t  = tid >> 1;
    const int g0 = (tid & 1) << 5;   // 0 or 32
    float q[F_];
    {
        const float* qrow = &Qb[(row0 + t) * DHAT_ + h * F_];
        #pragma unroll
        for (int f4 = 0; f4 < F_; f4 += 4) {
            float4 qq = *reinterpret_cast<const float4*>(&qrow[f4]);
            q[f4] = qq.x; q[f4 + 1] = qq.y; q[f4 + 2] = qq.z; q[f4 + 3] = qq.w;
        }
    }
    __syncthreads();

    float acc[32];
    #pragma unroll
    for (int j = 0; j < 32; ++j) acc[j] = 0.0f;
    float den = 1e-6f;

    #pragma unroll 4
    for (int f = 0; f < F_; ++f) {
        float qf = q[f];
        #pragma unroll
        for (int j4 = 0; j4 < 32; j4 += 4) {
            float4 s4 = *reinterpret_cast<const float4*>(&Sl[f][g0 + j4]);
            acc[j4 + 0] += qf * s4.x;
            acc[j4 + 1] += qf * s4.y;
            acc[j4 + 2] += qf * s4.z;
            acc[j4 + 3] += qf * s4.w;
        }
    }
    #pragma unroll
    for (int f = 0; f < F_; ++f) den += q[f] * zl[f];

    for (int s = 0; s <= t; ++s) {
        float a = 0.0f;
        #pragma unroll
        for (int f4 = 0; f4 < F_; f4 += 4) {
            float4 k4 = *reinterpret_cast<const float4*>(&Kl[s][f4]);
            a += q[f4] * k4.x + q[f4 + 1] * k4.y + q[f4 + 2] * k4.z + q[f4 + 3] * k4.w;
        }
        den += a;
        #pragma unroll
        for (int j4 = 0; j4 < 32; j4 += 4) {
            float4 v4 = *reinterpret_cast<const float4*>(&Vl[s][g0 + j4]);
            acc[j4 + 0] += a * v4.x;
            acc[j4 + 1] += a * v4.y;
            acc[j4 + 2] += a * v4.z;
            acc[j4 + 3] += a * v4.w;
        }
    }

    const float zinv = 1.0f / den;
    ushort* orow = &Obf[(row0 + t) * D_ + h * G_ + g0];
    #pragma unroll
    for (int j4 = 0; j4 < 32; j4 += 4) {
        ushort4 o;
        o.x = f2bf(acc[j4 + 0] * zinv);
        o.y = f2bf(acc[j4 + 1] * zinv);
        o.z = f2bf(acc[j4 + 2] * zinv);
        o.w = f2bf(acc[j4 + 3] * zinv);
        *reinterpret_cast<ushort4*>(&orow[j4]) = o;
    }
}

// ---------------------------------------------------------------------------
extern "C" void kernel_launch(void* const* d_in, const int* in_sizes, int n_in,
                              void* d_out, int out_size, void* d_ws, size_t ws_size,
                              hipStream_t stream) {
    const float* x  = (const float*)d_in[0];
    const float* wq = (const float*)d_in[1];
    const float* bq = (const float*)d_in[2];
    const float* wk = (const float*)d_in[3];
    const float* bk = (const float*)d_in[4];
    const float* wv = (const float*)d_in[5];
    const float* bv = (const float*)d_in[6];
    const float* wo = (const float*)d_in[7];
    const float* bo = (const float*)d_in[8];
    float* out = (float*)d_out;

    // workspace layout (256B-aligned chunks)
    size_t off = 0;
    char* base = (char*)d_ws;
    auto alloc = [&](size_t bytes) -> void* {
        void* p = base + off;
        off += (bytes + 255) & ~(size_t)255;
        return p;
    };
    const size_t MN = (size_t)B_ * N_;                 // 4096
    float*  Qb  = (float*) alloc(MN * DHAT_ * 4);      // fp32 (phi applied)
    float*  Kb  = (float*) alloc(MN * DHAT_ * 4);
    float*  Vb  = (float*) alloc(MN * D_ * 4);
    float*  Sb  = (float*) alloc((size_t)B_ * H_ * NCHUNK * F_ * G_ * 4);
    float*  zb  = (float*) alloc((size_t)B_ * H_ * NCHUNK * F_ * 4);
    ushort* xbf = (ushort*)alloc(MN * D_ * 2);         // bf16 x
    ushort* wqt = (ushort*)alloc((size_t)DHAT_ * D_ * 2);
    ushort* wkt = (ushort*)alloc((size_t)DHAT_ * D_ * 2);
    ushort* wvt = (ushort*)alloc((size_t)D_ * D_ * 2);
    ushort* wot = (ushort*)alloc((size_t)D_ * D_ * 2);
    ushort* obf = (ushort*)alloc(MN * D_ * 2);         // bf16 attention out

    const int M = (int)MN;   // 4096

    // convert inputs to bf16 (weights transposed to [N][K])
    convert_bf16_kernel<<<dim3((M * D_ / 4 + 255) / 256), 256, 0, stream>>>(x, xbf, M * D_ / 4);
    transpose_bf16_kernel<<<dim3(DHAT_ / 32, D_ / 32), 256, 0, stream>>>(wq, wqt, D_, DHAT_);
    transpose_bf16_kernel<<<dim3(DHAT_ / 32, D_ / 32), 256, 0, stream>>>(wk, wkt, D_, DHAT_);
    transpose_bf16_kernel<<<dim3(D_ / 32,    D_ / 32), 256, 0, stream>>>(wv, wvt, D_, D_);
    transpose_bf16_kernel<<<dim3(D_ / 32,    D_ / 32), 256, 0, stream>>>(wo, wot, D_, D_);

    // QKV projections (bf16 MFMA, fp32 out, phi fused for Q/K)
    mfma_gemm_kernel<true ><<<dim3(DHAT_ / 128, M / 128), 256, 0, stream>>>(xbf, wqt, bq, Qb, M, D_, DHAT_);
    mfma_gemm_kernel<true ><<<dim3(DHAT_ / 128, M / 128), 256, 0, stream>>>(xbf, wkt, bk, Kb, M, D_, DHAT_);
    mfma_gemm_kernel<false><<<dim3(D_    / 128, M / 128), 256, 0, stream>>>(xbf, wvt, bv, Vb, M, D_, D_);

    // chunked linear attention (fp32), writes bf16 O
    chunk_kv_kernel<<<dim3(NCHUNK, H_, B_), 256, 0, stream>>>(Kb, Vb, Sb, zb);
    scan_kernel<<<dim3(B_ * H_), 256, 0, stream>>>(Sb, zb);
    attn_out_kernel<<<dim3(NCHUNK, H_, B_), 256, 0, stream>>>(Qb, Kb, Vb, Sb, zb, obf);

    // output projection
    mfma_gemm_kernel<false><<<dim3(D_ / 128, M / 128), 256, 0, stream>>>(obf, wot, bo, out, M, D_, D_);
}

// Round 4
// 223.946 us; speedup vs baseline: 2.6065x; 1.1796x over previous
//
#include <hip/hip_runtime.h>
#include <hip/hip_bf16.h>
#include <math.h>

// Problem constants (from reference)
#define B_    2
#define N_    2048
#define D_    1024
#define DHAT_ 512
#define H_    16
#define F_    32      // qk head dim
#define G_    64      // v head dim
#define CHUNK 128
#define NCHUNK (N_ / CHUNK)   // 16

typedef __attribute__((ext_vector_type(8))) short bf16x8;
typedef __attribute__((ext_vector_type(4))) float f32x4;

__device__ __forceinline__ float phi_fn(float x) {
    // elu(x)+1 : x>0 -> x+1 ; x<=0 -> exp(x)
    return x > 0.0f ? x + 1.0f : expf(x);
}

__device__ __forceinline__ ushort f2bf(float f) {
    // round-to-nearest-even fp32 -> bf16
    unsigned u = __float_as_uint(f);
    u += 0x7FFFu + ((u >> 16) & 1u);
    return (ushort)(u >> 16);
}

__device__ __forceinline__ float bf2f(ushort u) {
    return __uint_as_float(((unsigned)u) << 16);
}

#define GLOAD_LDS16(g, l) __builtin_amdgcn_global_load_lds( \
    (const __attribute__((address_space(1))) void*)(g),     \
    (__attribute__((address_space(3))) void*)(l), 16, 0, 0)

// swizzle for 64B-row LDS tiles (rows of 32 bf16, 4 slots of 16B):
// slot ^= (row&3)^((row>>2)&3)  -> max 2-way conflict on frag reads (free)
__device__ __forceinline__ int sw64(int row) { return (row & 3) ^ ((row >> 2) & 3); }
// swizzle for Ps (rows of 128 bf16 = 256B, 16 slots of 16B): XOR low-3 slot bits
__device__ __forceinline__ int swP(int t) { return (t & 7) ^ (((t >> 3) & 1) << 1); }

// ---------------------------------------------------------------------------
// fp32 -> bf16 elementwise convert (4 elems/thread)
// ---------------------------------------------------------------------------
__global__ __launch_bounds__(256) void convert_bf16_kernel(
    const float* __restrict__ in, ushort* __restrict__ out, int n4)
{
    int i = blockIdx.x * 256 + threadIdx.x;
    if (i < n4) {
        float4 a = reinterpret_cast<const float4*>(in)[i];
        ushort4 o;
        o.x = f2bf(a.x); o.y = f2bf(a.y); o.z = f2bf(a.z); o.w = f2bf(a.w);
        reinterpret_cast<ushort4*>(out)[i] = o;
    }
}

// ---------------------------------------------------------------------------
// W[K][N] fp32  ->  Wt[N][K] bf16   (32x32 LDS tile transpose)
// ---------------------------------------------------------------------------
__global__ __launch_bounds__(256) void transpose_bf16_kernel(
    const float* __restrict__ W, ushort* __restrict__ Wt, int K, int N)
{
    __shared__ ushort tile[32][33];
    const int ti = blockIdx.y * 32;   // K base
    const int tj = blockIdx.x * 32;   // N base
    const int tx = threadIdx.x & 31, ty = threadIdx.x >> 5;   // ty 0..7
    #pragma unroll
    for (int r = 0; r < 4; ++r)
        tile[ty + r * 8][tx] = f2bf(W[(size_t)(ti + ty + r * 8) * N + tj + tx]);
    __syncthreads();
    #pragma unroll
    for (int r = 0; r < 4; ++r)
        Wt[(size_t)(tj + ty + r * 8) * K + ti + tx] = tile[tx][ty + r * 8];
}

// ---------------------------------------------------------------------------
// MFMA bf16 GEMM: C[M,N] = A[M,K] @ W[K,N] + bias, optional phi.
// A: bf16 [M][K]; Wt: bf16 [N][K]. Output fp32 or bf16 (OUTBF).
// BM=BN=128, BK=32; 256 threads = 4 waves (2x2), 64x64/wave, 4x4 frags.
// ---------------------------------------------------------------------------
template<bool PHI, bool OUTBF>
__global__ __launch_bounds__(256) void mfma_gemm_kernel(
    const ushort* __restrict__ A, const ushort* __restrict__ Wt,
    const float* __restrict__ bias, void* __restrict__ Cout,
    int M, int K, int N)
{
    __shared__ __attribute__((aligned(16))) ushort Asm[128 * 32];
    __shared__ __attribute__((aligned(16))) ushort Bsm[128 * 32];

    const int tid  = threadIdx.x;
    const int lane = tid & 63;
    const int wave = tid >> 6;
    const int wr   = wave >> 1, wc = wave & 1;
    const int brow = blockIdx.y * 128, bcol = blockIdx.x * 128;
    const int l16  = lane & 15, lk = lane >> 4;

    f32x4 acc[4][4];
    #pragma unroll
    for (int m = 0; m < 4; ++m)
        #pragma unroll
        for (int n = 0; n < 4; ++n)
            acc[m][n] = (f32x4){0.f, 0.f, 0.f, 0.f};

    for (int k0 = 0; k0 < K; k0 += 32) {
        __syncthreads();
        #pragma unroll
        for (int r = 0; r < 2; ++r) {
            int fi  = r * 256 + tid;
            int row = fi >> 2;
            int c8  = (fi & 3) << 3;
            GLOAD_LDS16(&A [(size_t)(brow + row) * K + k0 + c8], &Asm[fi * 8]);
            GLOAD_LDS16(&Wt[(size_t)(bcol + row) * K + k0 + c8], &Bsm[fi * 8]);
        }
        __syncthreads();

        bf16x8 af[4], bf[4];
        #pragma unroll
        for (int m = 0; m < 4; ++m)
            af[m] = *reinterpret_cast<const bf16x8*>(&Asm[(wr * 64 + m * 16 + l16) * 32 + lk * 8]);
        #pragma unroll
        for (int n = 0; n < 4; ++n)
            bf[n] = *reinterpret_cast<const bf16x8*>(&Bsm[(wc * 64 + n * 16 + l16) * 32 + lk * 8]);
        #pragma unroll
        for (int m = 0; m < 4; ++m)
            #pragma unroll
            for (int n = 0; n < 4; ++n)
                acc[m][n] = __builtin_amdgcn_mfma_f32_16x16x32_bf16(af[m], bf[n], acc[m][n], 0, 0, 0);
    }

    // C/D layout: col=lane&15, row=(lane>>4)*4+j  [m89/m91 verified]
    #pragma unroll
    for (int n = 0; n < 4; ++n) {
        int col = bcol + wc * 64 + n * 16 + l16;
        float bv = bias[col];
        #pragma unroll
        for (int m = 0; m < 4; ++m) {
            int row0 = brow + wr * 64 + m * 16 + lk * 4;
            #pragma unroll
            for (int j = 0; j < 4; ++j) {
                float v = acc[m][n][j] + bv;
                if (PHI) v = phi_fn(v);
                if (OUTBF)
                    ((ushort*)Cout)[(size_t)(row0 + j) * N + col] = f2bf(v);
                else
                    ((float*)Cout)[(size_t)(row0 + j) * N + col] = v;
            }
        }
    }
}

// ---------------------------------------------------------------------------
// Pass A: per-chunk sums  S_c[f][g] = sum_t K[t][f]*V[t][g],  z_c[f] = sum_t K[t][f]
// bf16 inputs, fp32 accumulation. grid (NCHUNK, H, B), 256 threads.
// ---------------------------------------------------------------------------
__global__ __launch_bounds__(256) void chunk_kv_kernel(
    const ushort* __restrict__ Kb, const ushort* __restrict__ Vb,
    float* __restrict__ Sb, float* __restrict__ zb)
{
    __shared__ float Kl[CHUNK][F_];   // 16 KB
    __shared__ float Vl[CHUNK][G_];   // 32 KB

    const int c = blockIdx.x, h = blockIdx.y, b = blockIdx.z;
    const int tid = threadIdx.x;
    const size_t row0 = (size_t)b * N_ + (size_t)c * CHUNK;

    #pragma unroll
    for (int r = 0; r < 2; ++r) {               // K chunk: 512 bf16x8
        int fi = r * 256 + tid;
        int t = fi >> 2, f8 = (fi & 3) << 3;
        bf16x8 v = *reinterpret_cast<const bf16x8*>(&Kb[(row0 + t) * DHAT_ + h * F_ + f8]);
        #pragma unroll
        for (int i = 0; i < 8; ++i) Kl[t][f8 + i] = bf2f((ushort)v[i]);
    }
    #pragma unroll
    for (int r = 0; r < 4; ++r) {               // V chunk: 1024 bf16x8
        int fi = r * 256 + tid;
        int t = fi >> 3, g8 = (fi & 7) << 3;
        bf16x8 v = *reinterpret_cast<const bf16x8*>(&Vb[(row0 + t) * D_ + h * G_ + g8]);
        #pragma unroll
        for (int i = 0; i < 8; ++i) Vl[t][g8 + i] = bf2f((ushort)v[i]);
    }
    __syncthreads();

    const int f  = tid >> 3;
    const int g0 = (tid & 7) << 3;
    float acc[8] = {};
    float zacc = 0.0f;

    for (int t = 0; t < CHUNK; ++t) {
        float kf = Kl[t][f];
        zacc += kf;
        float4 v0 = *reinterpret_cast<const float4*>(&Vl[t][g0]);
        float4 v1 = *reinterpret_cast<const float4*>(&Vl[t][g0 + 4]);
        acc[0] += kf * v0.x; acc[1] += kf * v0.y; acc[2] += kf * v0.z; acc[3] += kf * v0.w;
        acc[4] += kf * v1.x; acc[5] += kf * v1.y; acc[6] += kf * v1.z; acc[7] += kf * v1.w;
    }

    const size_t sbase = ((size_t)((b * H_ + h) * NCHUNK + c)) * (F_ * G_);
    *reinterpret_cast<float4*>(&Sb[sbase + f * G_ + g0])     = make_float4(acc[0], acc[1], acc[2], acc[3]);
    *reinterpret_cast<float4*>(&Sb[sbase + f * G_ + g0 + 4]) = make_float4(acc[4], acc[5], acc[6], acc[7]);
    if ((tid & 7) == 0)
        zb[((size_t)(b * H_ + h) * NCHUNK + c) * F_ + f] = zacc;
}

// ---------------------------------------------------------------------------
// Pass B: exclusive prefix scan over chunks. Reads Sb fp32 [f][g];
// writes SbT bf16 TRANSPOSED [g][f] (exclusive); zb fp32 in-place exclusive.
// grid (B*H), 256 threads: thread owns g = tid>>2, f0 = (tid&3)*8.
// ---------------------------------------------------------------------------
__global__ __launch_bounds__(256) void scan_kernel(
    const float* __restrict__ Sb, ushort* __restrict__ SbT, float* __restrict__ zb)
{
    const int bh = blockIdx.x;
    const int tid = threadIdx.x;
    const int g = tid >> 2, f0 = (tid & 3) << 3;

    float p[8] = {};
    for (int c = 0; c < NCHUNK; ++c) {
        const size_t sbase = ((size_t)bh * NCHUNK + c) * (F_ * G_);
        float t[8];
        #pragma unroll
        for (int i = 0; i < 8; ++i) t[i] = Sb[sbase + (size_t)(f0 + i) * G_ + g];
        bf16x8 w;
        #pragma unroll
        for (int i = 0; i < 8; ++i) w[i] = (short)f2bf(p[i]);
        *reinterpret_cast<bf16x8*>(&SbT[(((size_t)bh * NCHUNK + c) * G_ + g) * F_ + f0]) = w;
        #pragma unroll
        for (int i = 0; i < 8; ++i) p[i] += t[i];
    }
    if (tid < F_) {
        float pz = 0.0f;
        for (int c = 0; c < NCHUNK; ++c) {
            size_t base = ((size_t)bh * NCHUNK + c) * F_ + tid;
            float t = zb[base];
            zb[base] = pz;
            pz += t;
        }
    }
}

// ---------------------------------------------------------------------------
// Pass C (MFMA): per-chunk outputs.
//   P = tril(Q K^T)        (128x128, MFMA, masked, bf16 -> swizzled LDS)
//   den[t] = rowsum(P[t]) + q_t . z_prefix + 1e-6     (fp32)
//   out = (P @ V + Q @ S_prefix) / den                (MFMA, fp32 accum)
// grid (NCHUNK, H, B), 256 thr = 4 waves; wave w owns rows 32w..32w+31.
// Single barrier: after staging, everything is wave-local.
// ---------------------------------------------------------------------------
__global__ __launch_bounds__(256) void attn_mfma_kernel(
    const ushort* __restrict__ Qb, const ushort* __restrict__ Kb,
    const ushort* __restrict__ Vb, const ushort* __restrict__ SbT,
    const float* __restrict__ zb, ushort* __restrict__ Obf)
{
    __shared__ __attribute__((aligned(16))) ushort Qs[128 * 32];   //  8 KB [t][f]   sw64
    __shared__ __attribute__((aligned(16))) ushort Ks[128 * 32];   //  8 KB [s][f]   sw64
    __shared__ __attribute__((aligned(16))) ushort VsT[64 * 128];  // 16 KB [g][s]   (g&7) swz
    __shared__ __attribute__((aligned(16))) ushort Ss[64 * 32];    //  4 KB [g][f]   sw64
    __shared__ __attribute__((aligned(16))) ushort Ps[128 * 128];  // 32 KB [t][s]   swP
    __shared__ float zl[F_];
    __shared__ float denl[CHUNK];

    const int c = blockIdx.x, h = blockIdx.y, b = blockIdx.z;
    const int tid = threadIdx.x;
    const int lane = tid & 63, wave = tid >> 6;
    const int l16 = lane & 15, lk = lane >> 4;
    const size_t row0 = (size_t)b * N_ + (size_t)c * CHUNK;
    const int bh = b * H_ + h;

    // ---- stage Q, K (global bf16 -> linear-chunk LDS, source pre-swizzled) ----
    #pragma unroll
    for (int r = 0; r < 2; ++r) {
        int fi = r * 256 + tid;
        int row = fi >> 2;
        int c8 = ((fi & 3) ^ sw64(row)) << 3;
        GLOAD_LDS16(&Qb[(row0 + row) * DHAT_ + h * F_ + c8], &Qs[fi * 8]);
        GLOAD_LDS16(&Kb[(row0 + row) * DHAT_ + h * F_ + c8], &Ks[fi * 8]);
    }
    // ---- stage S_prefix^T (64x32) ----
    {
        int g = tid >> 2;
        int f8 = ((tid & 3) ^ sw64(g)) << 3;
        GLOAD_LDS16(&SbT[(((size_t)bh * NCHUNK + c) * G_ + g) * F_ + f8], &Ss[tid * 8]);
    }
    if (tid < F_) zl[tid] = zb[((size_t)bh * NCHUNK + c) * F_ + tid];
    // ---- stage V transposed [g][s], swizzled (reg staging) ----
    {
        int s = tid & 127, gh = tid >> 7;
        const ushort* vsrc = &Vb[(row0 + s) * D_ + h * G_ + gh * 32];
        #pragma unroll
        for (int w = 0; w < 4; ++w) {
            bf16x8 v = *reinterpret_cast<const bf16x8*>(&vsrc[w * 8]);
            #pragma unroll
            for (int i = 0; i < 8; ++i) {
                int g = gh * 32 + w * 8 + i;
                VsT[g * 128 + (s ^ ((g & 7) << 3))] = (ushort)v[i];
            }
        }
    }
    __syncthreads();

    const int mbase = wave * 32;

    // ---- A-fragments of Q (reused for P and Q@S) ----
    bf16x8 aq[2];
    #pragma unroll
    for (int m = 0; m < 2; ++m) {
        int row = mbase + m * 16 + l16;
        aq[m] = *reinterpret_cast<const bf16x8*>(&Qs[row * 32 + ((lk ^ sw64(row)) << 3)]);
    }

    // ---- P = Q K^T over this wave's 32 rows x all 128 cols ----
    f32x4 p[2][8];
    #pragma unroll
    for (int m = 0; m < 2; ++m)
        #pragma unroll
        for (int n = 0; n < 8; ++n)
            p[m][n] = (f32x4){0.f, 0.f, 0.f, 0.f};
    #pragma unroll
    for (int n = 0; n < 8; ++n) {
        int srow = n * 16 + l16;
        bf16x8 bk = *reinterpret_cast<const bf16x8*>(&Ks[srow * 32 + ((lk ^ sw64(srow)) << 3)]);
        p[0][n] = __builtin_amdgcn_mfma_f32_16x16x32_bf16(aq[0], bk, p[0][n], 0, 0, 0);
        p[1][n] = __builtin_amdgcn_mfma_f32_16x16x32_bf16(aq[1], bk, p[1][n], 0, 0, 0);
    }

    // ---- causal mask + cvt + store Ps (swizzled) ----
    #pragma unroll
    for (int m = 0; m < 2; ++m)
        #pragma unroll
        for (int n = 0; n < 8; ++n) {
            int s = n * 16 + l16;
            #pragma unroll
            for (int j = 0; j < 4; ++j) {
                int t = mbase + m * 16 + lk * 4 + j;
                float v = (s <= t) ? p[m][n][j] : 0.0f;
                Ps[t * 128 + ((s & 7) | (((s >> 3) ^ swP(t)) << 3))] = f2bf(v);
            }
        }

    // ---- den[t]: thread pair (t = tid>>1, half = tid&1) ----
    {
        int t = tid >> 1, h2 = tid & 1;
        float rs = 0.0f;
        #pragma unroll
        for (int r = 0; r < 8; ++r) {
            int sl = h2 * 8 + r;
            bf16x8 pv = *reinterpret_cast<const bf16x8*>(&Ps[t * 128 + ((sl ^ swP(t)) << 3)]);
            #pragma unroll
            for (int i = 0; i < 8; ++i) rs += bf2f((ushort)pv[i]);
        }
        #pragma unroll
        for (int ss = 0; ss < 2; ++ss) {
            int sl = h2 * 2 + ss;
            bf16x8 qv = *reinterpret_cast<const bf16x8*>(&Qs[t * 32 + ((sl ^ sw64(t)) << 3)]);
            #pragma unroll
            for (int i = 0; i < 8; ++i) rs += bf2f((ushort)qv[i]) * zl[sl * 8 + i];
        }
        rs += __shfl_xor(rs, 1);
        if (h2 == 0) denl[t] = rs + 1e-6f;
    }

    // ---- out = Q @ S_prefix + P @ V ----
    f32x4 o[2][4];
    #pragma unroll
    for (int m = 0; m < 2; ++m)
        #pragma unroll
        for (int n = 0; n < 4; ++n)
            o[m][n] = (f32x4){0.f, 0.f, 0.f, 0.f};
    #pragma unroll
    for (int n = 0; n < 4; ++n) {
        int g = n * 16 + l16;
        bf16x8 bs = *reinterpret_cast<const bf16x8*>(&Ss[g * 32 + ((lk ^ sw64(g)) << 3)]);
        o[0][n] = __builtin_amdgcn_mfma_f32_16x16x32_bf16(aq[0], bs, o[0][n], 0, 0, 0);
        o[1][n] = __builtin_amdgcn_mfma_f32_16x16x32_bf16(aq[1], bs, o[1][n], 0, 0, 0);
    }
    #pragma unroll
    for (int ks = 0; ks < 4; ++ks) {
        bf16x8 ap[2];
        #pragma unroll
        for (int m = 0; m < 2; ++m) {
            int t = mbase + m * 16 + l16;
            int sl = ks * 4 + lk;
            ap[m] = *reinterpret_cast<const bf16x8*>(&Ps[t * 128 + ((sl ^ swP(t)) << 3)]);
        }
        #pragma unroll
        for (int n = 0; n < 4; ++n) {
            int g = n * 16 + l16;
            bf16x8 bv = *reinterpret_cast<const bf16x8*>(&VsT[g * 128 + (((ks * 4 + lk) ^ (g & 7)) << 3)]);
            o[0][n] = __builtin_amdgcn_mfma_f32_16x16x32_bf16(ap[0], bv, o[0][n], 0, 0, 0);
            o[1][n] = __builtin_amdgcn_mfma_f32_16x16x32_bf16(ap[1], bv, o[1][n], 0, 0, 0);
        }
    }

    // ---- epilogue: scale by 1/den, write bf16 ----
    #pragma unroll
    for (int m = 0; m < 2; ++m)
        #pragma unroll
        for (int j = 0; j < 4; ++j) {
            int t = mbase + m * 16 + lk * 4 + j;
            float rinv = 1.0f / denl[t];
            #pragma unroll
            for (int n = 0; n < 4; ++n) {
                int g = n * 16 + l16;
                Obf[(row0 + t) * D_ + h * G_ + g] = f2bf(o[m][n][j] * rinv);
            }
        }
}

// ---------------------------------------------------------------------------
extern "C" void kernel_launch(void* const* d_in, const int* in_sizes, int n_in,
                              void* d_out, int out_size, void* d_ws, size_t ws_size,
                              hipStream_t stream) {
    const float* x  = (const float*)d_in[0];
    const float* wq = (const float*)d_in[1];
    const float* bq = (const float*)d_in[2];
    const float* wk = (const float*)d_in[3];
    const float* bk = (const float*)d_in[4];
    const float* wv = (const float*)d_in[5];
    const float* bv = (const float*)d_in[6];
    const float* wo = (const float*)d_in[7];
    const float* bo = (const float*)d_in[8];
    float* out = (float*)d_out;

    size_t off = 0;
    char* base = (char*)d_ws;
    auto alloc = [&](size_t bytes) -> void* {
        void* p = base + off;
        off += (bytes + 255) & ~(size_t)255;
        return p;
    };
    const size_t MN = (size_t)B_ * N_;   // 4096
    ushort* Qbf = (ushort*)alloc(MN * DHAT_ * 2);    // bf16 phi(Q)
    ushort* Kbf = (ushort*)alloc(MN * DHAT_ * 2);    // bf16 phi(K)
    ushort* Vbf = (ushort*)alloc(MN * D_ * 2);       // bf16 V
    float*  Sb  = (float*) alloc((size_t)B_ * H_ * NCHUNK * F_ * G_ * 4);
    ushort* SbT = (ushort*)alloc((size_t)B_ * H_ * NCHUNK * G_ * F_ * 2);
    float*  zb  = (float*) alloc((size_t)B_ * H_ * NCHUNK * F_ * 4);
    ushort* xbf = (ushort*)alloc(MN * D_ * 2);
    ushort* wqt = (ushort*)alloc((size_t)DHAT_ * D_ * 2);
    ushort* wkt = (ushort*)alloc((size_t)DHAT_ * D_ * 2);
    ushort* wvt = (ushort*)alloc((size_t)D_ * D_ * 2);
    ushort* wot = (ushort*)alloc((size_t)D_ * D_ * 2);
    ushort* obf = (ushort*)alloc(MN * D_ * 2);

    const int M = (int)MN;   // 4096

    convert_bf16_kernel<<<dim3((M * D_ / 4 + 255) / 256), 256, 0, stream>>>(x, xbf, M * D_ / 4);
    transpose_bf16_kernel<<<dim3(DHAT_ / 32, D_ / 32), 256, 0, stream>>>(wq, wqt, D_, DHAT_);
    transpose_bf16_kernel<<<dim3(DHAT_ / 32, D_ / 32), 256, 0, stream>>>(wk, wkt, D_, DHAT_);
    transpose_bf16_kernel<<<dim3(D_ / 32,    D_ / 32), 256, 0, stream>>>(wv, wvt, D_, D_);
    transpose_bf16_kernel<<<dim3(D_ / 32,    D_ / 32), 256, 0, stream>>>(wo, wot, D_, D_);

    // projections -> bf16 (phi fused for Q/K)
    mfma_gemm_kernel<true,  true ><<<dim3(DHAT_ / 128, M / 128), 256, 0, stream>>>(xbf, wqt, bq, Qbf, M, D_, DHAT_);
    mfma_gemm_kernel<true,  true ><<<dim3(DHAT_ / 128, M / 128), 256, 0, stream>>>(xbf, wkt, bk, Kbf, M, D_, DHAT_);
    mfma_gemm_kernel<false, true ><<<dim3(D_    / 128, M / 128), 256, 0, stream>>>(xbf, wvt, bv, Vbf, M, D_, D_);

    // chunked linear attention
    chunk_kv_kernel<<<dim3(NCHUNK, H_, B_), 256, 0, stream>>>(Kbf, Vbf, Sb, zb);
    scan_kernel<<<dim3(B_ * H_), 256, 0, stream>>>(Sb, SbT, zb);
    attn_mfma_kernel<<<dim3(NCHUNK, H_, B_), 256, 0, stream>>>(Qbf, Kbf, Vbf, SbT, zb, obf);

    // output projection (fp32 out)
    mfma_gemm_kernel<false, false><<<dim3(D_ / 128, M / 128), 256, 0, stream>>>(obf, wot, bo, out, M, D_, D_);
}

// Round 5
// 179.733 us; speedup vs baseline: 3.2477x; 1.2460x over previous
//
#include <hip/hip_runtime.h>
#include <hip/hip_bf16.h>
#include <math.h>

// Problem constants (from reference)
#define B_    2
#define N_    2048
#define D_    1024
#define DHAT_ 512
#define H_    16
#define F_    32      // qk head dim
#define G_    64      // v head dim
#define CHUNK 128
#define NCHUNK (N_ / CHUNK)   // 16
#define QKVLD 2048            // fused QKV row stride (cols: Q 0..511, K 512..1023, V 1024..2047)

typedef __attribute__((ext_vector_type(8))) short bf16x8;
typedef __attribute__((ext_vector_type(4))) float f32x4;

__device__ __forceinline__ float phi_fn(float x) {
    // elu(x)+1 : x>0 -> x+1 ; x<=0 -> exp(x)
    return x > 0.0f ? x + 1.0f : expf(x);
}

__device__ __forceinline__ ushort f2bf(float f) {
    unsigned u = __float_as_uint(f);
    u += 0x7FFFu + ((u >> 16) & 1u);
    return (ushort)(u >> 16);
}

__device__ __forceinline__ float bf2f(ushort u) {
    return __uint_as_float(((unsigned)u) << 16);
}

#define GLOAD_LDS16(g, l) __builtin_amdgcn_global_load_lds( \
    (const __attribute__((address_space(1))) void*)(g),     \
    (__attribute__((address_space(3))) void*)(l), 16, 0, 0)

// swizzle for 64B-row LDS tiles (rows of 32 bf16, 4 slots of 16B)
__device__ __forceinline__ int sw64(int row) { return (row & 3) ^ ((row >> 2) & 3); }
// swizzle for 256B-row tiles (rows of 128 bf16, 16 slots): slot ^= row&7 variants
__device__ __forceinline__ int swP(int t) { return (t & 7) ^ (((t >> 3) & 1) << 1); }

// ---------------------------------------------------------------------------
// fp32 -> bf16 elementwise convert (4 elems/thread)
// ---------------------------------------------------------------------------
__global__ __launch_bounds__(256) void convert_bf16_kernel(
    const float* __restrict__ in, ushort* __restrict__ out, int n4)
{
    int i = blockIdx.x * 256 + threadIdx.x;
    if (i < n4) {
        float4 a = reinterpret_cast<const float4*>(in)[i];
        ushort4 o;
        o.x = f2bf(a.x); o.y = f2bf(a.y); o.z = f2bf(a.z); o.w = f2bf(a.w);
        reinterpret_cast<ushort4*>(out)[i] = o;
    }
}

// ---------------------------------------------------------------------------
// W[K][N] fp32  ->  Wt[N][K] bf16   (32x32 LDS tile transpose)
// ---------------------------------------------------------------------------
__global__ __launch_bounds__(256) void transpose_bf16_kernel(
    const float* __restrict__ W, ushort* __restrict__ Wt, int K, int N)
{
    __shared__ ushort tile[32][33];
    const int ti = blockIdx.y * 32;   // K base
    const int tj = blockIdx.x * 32;   // N base
    const int tx = threadIdx.x & 31, ty = threadIdx.x >> 5;
    #pragma unroll
    for (int r = 0; r < 4; ++r)
        tile[ty + r * 8][tx] = f2bf(W[(size_t)(ti + ty + r * 8) * N + tj + tx]);
    __syncthreads();
    #pragma unroll
    for (int r = 0; r < 4; ++r)
        Wt[(size_t)(tj + ty + r * 8) * K + ti + tx] = tile[tx][ty + r * 8];
}

// ---------------------------------------------------------------------------
// pack bqkv[2048] = [bq | bk | bv]
// ---------------------------------------------------------------------------
__global__ __launch_bounds__(256) void pack_bias_kernel(
    const float* __restrict__ bq, const float* __restrict__ bk,
    const float* __restrict__ bv, float* __restrict__ bqkv)
{
    int i = blockIdx.x * 256 + threadIdx.x;
    if (i < DHAT_)            bqkv[i] = bq[i];
    else if (i < 2 * DHAT_)   bqkv[i] = bk[i - DHAT_];
    else if (i < QKVLD)       bqkv[i] = bv[i - 2 * DHAT_];
}

// ---------------------------------------------------------------------------
// MFMA bf16 GEMM: C[M,N] = A[M,K] @ W[K,N] + bias; phi applied to col<phi_upto.
// A: bf16 [M][K]; Wt: bf16 [N][K]. OUTBF selects bf16/fp32 output.
// BM=BN=128, BK=32; 256 threads = 4 waves (2x2), 64x64/wave, 4x4 frags.
// ---------------------------------------------------------------------------
template<bool OUTBF>
__global__ __launch_bounds__(256) void mfma_gemm_kernel(
    const ushort* __restrict__ A, const ushort* __restrict__ Wt,
    const float* __restrict__ bias, void* __restrict__ Cout,
    int M, int K, int N, int phi_upto)
{
    __shared__ __attribute__((aligned(16))) ushort Asm[128 * 32];
    __shared__ __attribute__((aligned(16))) ushort Bsm[128 * 32];

    const int tid  = threadIdx.x;
    const int lane = tid & 63;
    const int wave = tid >> 6;
    const int wr   = wave >> 1, wc = wave & 1;
    const int brow = blockIdx.y * 128, bcol = blockIdx.x * 128;
    const int l16  = lane & 15, lk = lane >> 4;

    f32x4 acc[4][4];
    #pragma unroll
    for (int m = 0; m < 4; ++m)
        #pragma unroll
        for (int n = 0; n < 4; ++n)
            acc[m][n] = (f32x4){0.f, 0.f, 0.f, 0.f};

    for (int k0 = 0; k0 < K; k0 += 32) {
        __syncthreads();
        #pragma unroll
        for (int r = 0; r < 2; ++r) {
            int fi  = r * 256 + tid;
            int row = fi >> 2;
            int c8  = (fi & 3) << 3;
            GLOAD_LDS16(&A [(size_t)(brow + row) * K + k0 + c8], &Asm[fi * 8]);
            GLOAD_LDS16(&Wt[(size_t)(bcol + row) * K + k0 + c8], &Bsm[fi * 8]);
        }
        __syncthreads();

        bf16x8 af[4], bf[4];
        #pragma unroll
        for (int m = 0; m < 4; ++m)
            af[m] = *reinterpret_cast<const bf16x8*>(&Asm[(wr * 64 + m * 16 + l16) * 32 + lk * 8]);
        #pragma unroll
        for (int n = 0; n < 4; ++n)
            bf[n] = *reinterpret_cast<const bf16x8*>(&Bsm[(wc * 64 + n * 16 + l16) * 32 + lk * 8]);
        #pragma unroll
        for (int m = 0; m < 4; ++m)
            #pragma unroll
            for (int n = 0; n < 4; ++n)
                acc[m][n] = __builtin_amdgcn_mfma_f32_16x16x32_bf16(af[m], bf[n], acc[m][n], 0, 0, 0);
    }

    // C/D layout: col=lane&15, row=(lane>>4)*4+j  [m89/m91 verified]
    #pragma unroll
    for (int n = 0; n < 4; ++n) {
        int col = bcol + wc * 64 + n * 16 + l16;
        float bv = bias[col];
        const bool do_phi = col < phi_upto;   // block-uniform segment
        #pragma unroll
        for (int m = 0; m < 4; ++m) {
            int row0 = brow + wr * 64 + m * 16 + lk * 4;
            #pragma unroll
            for (int j = 0; j < 4; ++j) {
                float v = acc[m][n][j] + bv;
                if (do_phi) v = phi_fn(v);
                if (OUTBF)
                    ((ushort*)Cout)[(size_t)(row0 + j) * N + col] = f2bf(v);
                else
                    ((float*)Cout)[(size_t)(row0 + j) * N + col] = v;
            }
        }
    }
}

// ---------------------------------------------------------------------------
// Pass A (MFMA): S_c[f][g] = sum_t K[t][f]*V[t][g],  z_c[f] = sum_t K[t][f]
// K,V from fused QKV buffer (stride QKVLD). grid (NCHUNK, H, B), 256 thr.
// KsT [32][128], VsT [64][128] staged transposed+swizzled; S via 16x16x32.
// ---------------------------------------------------------------------------
__global__ __launch_bounds__(256) void chunk_kv_kernel(
    const ushort* __restrict__ QKV, float* __restrict__ Sb, float* __restrict__ zb)
{
    __shared__ __attribute__((aligned(16))) ushort KsT[32 * 128];   //  8 KB [f][t]
    __shared__ __attribute__((aligned(16))) ushort VsT[64 * 128];   // 16 KB [g][t]

    const int c = blockIdx.x, h = blockIdx.y, b = blockIdx.z;
    const int tid = threadIdx.x;
    const int lane = tid & 63, wave = tid >> 6;
    const int l16 = lane & 15, lk = lane >> 4;
    const size_t row0 = (size_t)b * N_ + (size_t)c * CHUNK;
    const size_t koff = 2 * DHAT_ - DHAT_ + (size_t)h * F_;   // K cols start at 512
    const size_t voff = 2 * (size_t)DHAT_ + (size_t)h * G_;   // V cols start at 1024

    // stage K^T: thread loads (t, 8 f's), scatters to KsT[f][t]
    #pragma unroll
    for (int r = 0; r < 2; ++r) {
        int fi = r * 256 + tid;
        int t = fi >> 2, f8 = (fi & 3) << 3;
        bf16x8 v = *reinterpret_cast<const bf16x8*>(&QKV[(row0 + t) * QKVLD + DHAT_ + h * F_ + f8]);
        #pragma unroll
        for (int i = 0; i < 8; ++i) {
            int f = f8 + i;
            KsT[f * 128 + (t ^ ((f & 7) << 3))] = (ushort)v[i];
        }
    }
    // stage V^T: thread (s = tid&127, gh = tid>>7) scatters 32 g's
    {
        int s = tid & 127, gh = tid >> 7;
        const ushort* vsrc = &QKV[(row0 + s) * QKVLD + voff + gh * 32];
        #pragma unroll
        for (int w = 0; w < 4; ++w) {
            bf16x8 v = *reinterpret_cast<const bf16x8*>(&vsrc[w * 8]);
            #pragma unroll
            for (int i = 0; i < 8; ++i) {
                int g = gh * 32 + w * 8 + i;
                VsT[g * 128 + (s ^ ((g & 7) << 3))] = (ushort)v[i];
            }
        }
    }
    __syncthreads();

    // wave w owns g-tile w (cols w*16..w*16+15), f-tiles 0..1
    f32x4 sacc[2];
    sacc[0] = (f32x4){0.f, 0.f, 0.f, 0.f};
    sacc[1] = (f32x4){0.f, 0.f, 0.f, 0.f};
    const int g = wave * 16 + l16;
    #pragma unroll
    for (int ks = 0; ks < 4; ++ks) {
        int sl = ks * 4 + lk;
        bf16x8 bv = *reinterpret_cast<const bf16x8*>(&VsT[g * 128 + ((sl ^ (g & 7)) << 3)]);
        #pragma unroll
        for (int m = 0; m < 2; ++m) {
            int f = m * 16 + l16;
            bf16x8 ak = *reinterpret_cast<const bf16x8*>(&KsT[f * 128 + ((sl ^ (f & 7)) << 3)]);
            sacc[m] = __builtin_amdgcn_mfma_f32_16x16x32_bf16(ak, bv, sacc[m], 0, 0, 0);
        }
    }

    const size_t sbase = ((size_t)((b * H_ + h) * NCHUNK + c)) * (F_ * G_);
    #pragma unroll
    for (int m = 0; m < 2; ++m)
        #pragma unroll
        for (int j = 0; j < 4; ++j) {
            int f = m * 16 + lk * 4 + j;
            Sb[sbase + (size_t)f * G_ + g] = sacc[m][j];
        }

    // z[f]: thread (f = tid>>3, i = tid&7) sums 2 slots, shfl-reduce over 8 lanes
    {
        int f = tid >> 3, i = tid & 7;
        float zs = 0.0f;
        #pragma unroll
        for (int ss = 0; ss < 2; ++ss) {
            int sl = i * 2 + ss;
            bf16x8 kv = *reinterpret_cast<const bf16x8*>(&KsT[f * 128 + ((sl ^ (f & 7)) << 3)]);
            #pragma unroll
            for (int e = 0; e < 8; ++e) zs += bf2f((ushort)kv[e]);
        }
        zs += __shfl_xor(zs, 1);
        zs += __shfl_xor(zs, 2);
        zs += __shfl_xor(zs, 4);
        if (i == 0) zb[((size_t)(b * H_ + h) * NCHUNK + c) * F_ + f] = zs;
    }
}

// ---------------------------------------------------------------------------
// Pass B: exclusive prefix scan over chunks. Reads Sb fp32 [f][g];
// writes SbT bf16 TRANSPOSED [g][f] (exclusive); zb fp32 in-place exclusive.
// ---------------------------------------------------------------------------
__global__ __launch_bounds__(256) void scan_kernel(
    const float* __restrict__ Sb, ushort* __restrict__ SbT, float* __restrict__ zb)
{
    const int bh = blockIdx.x;
    const int tid = threadIdx.x;
    const int g = tid >> 2, f0 = (tid & 3) << 3;

    float p[8] = {};
    for (int c = 0; c < NCHUNK; ++c) {
        const size_t sbase = ((size_t)bh * NCHUNK + c) * (F_ * G_);
        float t[8];
        #pragma unroll
        for (int i = 0; i < 8; ++i) t[i] = Sb[sbase + (size_t)(f0 + i) * G_ + g];
        bf16x8 w;
        #pragma unroll
        for (int i = 0; i < 8; ++i) w[i] = (short)f2bf(p[i]);
        *reinterpret_cast<bf16x8*>(&SbT[(((size_t)bh * NCHUNK + c) * G_ + g) * F_ + f0]) = w;
        #pragma unroll
        for (int i = 0; i < 8; ++i) p[i] += t[i];
    }
    if (tid < F_) {
        float pz = 0.0f;
        for (int c = 0; c < NCHUNK; ++c) {
            size_t base = ((size_t)bh * NCHUNK + c) * F_ + tid;
            float t = zb[base];
            zb[base] = pz;
            pz += t;
        }
    }
}

// ---------------------------------------------------------------------------
// Pass C (MFMA): P = tril(QK^T); den = rowsum(P)+q.z_prefix;
// out = (P@V + Q@S_prefix)/den. grid (NCHUNK,H,B), 4 waves.
// ---------------------------------------------------------------------------
__global__ __launch_bounds__(256) void attn_mfma_kernel(
    const ushort* __restrict__ QKV, const ushort* __restrict__ SbT,
    const float* __restrict__ zb, ushort* __restrict__ Obf)
{
    __shared__ __attribute__((aligned(16))) ushort Qs[128 * 32];   //  8 KB [t][f]  sw64
    __shared__ __attribute__((aligned(16))) ushort Ks[128 * 32];   //  8 KB [s][f]  sw64
    __shared__ __attribute__((aligned(16))) ushort VsT[64 * 128];  // 16 KB [g][s]
    __shared__ __attribute__((aligned(16))) ushort Ss[64 * 32];    //  4 KB [g][f]  sw64
    __shared__ __attribute__((aligned(16))) ushort Ps[128 * 128];  // 32 KB [t][s]  swP
    __shared__ float zl[F_];
    __shared__ float denl[CHUNK];

    const int c = blockIdx.x, h = blockIdx.y, b = blockIdx.z;
    const int tid = threadIdx.x;
    const int lane = tid & 63, wave = tid >> 6;
    const int l16 = lane & 15, lk = lane >> 4;
    const size_t row0 = (size_t)b * N_ + (size_t)c * CHUNK;
    const int bh = b * H_ + h;

    // stage Q, K (source pre-swizzled -> linear LDS)
    #pragma unroll
    for (int r = 0; r < 2; ++r) {
        int fi = r * 256 + tid;
        int row = fi >> 2;
        int c8 = ((fi & 3) ^ sw64(row)) << 3;
        GLOAD_LDS16(&QKV[(row0 + row) * QKVLD + h * F_ + c8], &Qs[fi * 8]);
        GLOAD_LDS16(&QKV[(row0 + row) * QKVLD + DHAT_ + h * F_ + c8], &Ks[fi * 8]);
    }
    // stage S_prefix^T
    {
        int g = tid >> 2;
        int f8 = ((tid & 3) ^ sw64(g)) << 3;
        GLOAD_LDS16(&SbT[(((size_t)bh * NCHUNK + c) * G_ + g) * F_ + f8], &Ss[tid * 8]);
    }
    if (tid < F_) zl[tid] = zb[((size_t)bh * NCHUNK + c) * F_ + tid];
    // stage V transposed [g][s]
    {
        int s = tid & 127, gh = tid >> 7;
        const ushort* vsrc = &QKV[(row0 + s) * QKVLD + 2 * DHAT_ + h * G_ + gh * 32];
        #pragma unroll
        for (int w = 0; w < 4; ++w) {
            bf16x8 v = *reinterpret_cast<const bf16x8*>(&vsrc[w * 8]);
            #pragma unroll
            for (int i = 0; i < 8; ++i) {
                int g = gh * 32 + w * 8 + i;
                VsT[g * 128 + (s ^ ((g & 7) << 3))] = (ushort)v[i];
            }
        }
    }
    __syncthreads();

    const int mbase = wave * 32;

    bf16x8 aq[2];
    #pragma unroll
    for (int m = 0; m < 2; ++m) {
        int row = mbase + m * 16 + l16;
        aq[m] = *reinterpret_cast<const bf16x8*>(&Qs[row * 32 + ((lk ^ sw64(row)) << 3)]);
    }

    // P = Q K^T (this wave's 32 rows x 128 cols)
    f32x4 p[2][8];
    #pragma unroll
    for (int m = 0; m < 2; ++m)
        #pragma unroll
        for (int n = 0; n < 8; ++n)
            p[m][n] = (f32x4){0.f, 0.f, 0.f, 0.f};
    #pragma unroll
    for (int n = 0; n < 8; ++n) {
        int srow = n * 16 + l16;
        bf16x8 bk = *reinterpret_cast<const bf16x8*>(&Ks[srow * 32 + ((lk ^ sw64(srow)) << 3)]);
        p[0][n] = __builtin_amdgcn_mfma_f32_16x16x32_bf16(aq[0], bk, p[0][n], 0, 0, 0);
        p[1][n] = __builtin_amdgcn_mfma_f32_16x16x32_bf16(aq[1], bk, p[1][n], 0, 0, 0);
    }

    // causal mask + cvt + store Ps (swizzled)
    #pragma unroll
    for (int m = 0; m < 2; ++m)
        #pragma unroll
        for (int n = 0; n < 8; ++n) {
            int s = n * 16 + l16;
            #pragma unroll
            for (int j = 0; j < 4; ++j) {
                int t = mbase + m * 16 + lk * 4 + j;
                float v = (s <= t) ? p[m][n][j] : 0.0f;
                Ps[t * 128 + ((s & 7) | (((s >> 3) ^ swP(t)) << 3))] = f2bf(v);
            }
        }

    // den[t]
    {
        int t = tid >> 1, h2 = tid & 1;
        float rs = 0.0f;
        #pragma unroll
        for (int r = 0; r < 8; ++r) {
            int sl = h2 * 8 + r;
            bf16x8 pv = *reinterpret_cast<const bf16x8*>(&Ps[t * 128 + ((sl ^ swP(t)) << 3)]);
            #pragma unroll
            for (int i = 0; i < 8; ++i) rs += bf2f((ushort)pv[i]);
        }
        #pragma unroll
        for (int ss = 0; ss < 2; ++ss) {
            int sl = h2 * 2 + ss;
            bf16x8 qv = *reinterpret_cast<const bf16x8*>(&Qs[t * 32 + ((sl ^ sw64(t)) << 3)]);
            #pragma unroll
            for (int i = 0; i < 8; ++i) rs += bf2f((ushort)qv[i]) * zl[sl * 8 + i];
        }
        rs += __shfl_xor(rs, 1);
        if (h2 == 0) denl[t] = rs + 1e-6f;
    }

    // out = Q @ S_prefix + P @ V
    f32x4 o[2][4];
    #pragma unroll
    for (int m = 0; m < 2; ++m)
        #pragma unroll
        for (int n = 0; n < 4; ++n)
            o[m][n] = (f32x4){0.f, 0.f, 0.f, 0.f};
    #pragma unroll
    for (int n = 0; n < 4; ++n) {
        int g = n * 16 + l16;
        bf16x8 bs = *reinterpret_cast<const bf16x8*>(&Ss[g * 32 + ((lk ^ sw64(g)) << 3)]);
        o[0][n] = __builtin_amdgcn_mfma_f32_16x16x32_bf16(aq[0], bs, o[0][n], 0, 0, 0);
        o[1][n] = __builtin_amdgcn_mfma_f32_16x16x32_bf16(aq[1], bs, o[1][n], 0, 0, 0);
    }
    #pragma unroll
    for (int ks = 0; ks < 4; ++ks) {
        bf16x8 ap[2];
        #pragma unroll
        for (int m = 0; m < 2; ++m) {
            int t = mbase + m * 16 + l16;
            int sl = ks * 4 + lk;
            ap[m] = *reinterpret_cast<const bf16x8*>(&Ps[t * 128 + ((sl ^ swP(t)) << 3)]);
        }
        #pragma unroll
        for (int n = 0; n < 4; ++n) {
            int g = n * 16 + l16;
            bf16x8 bv = *reinterpret_cast<const bf16x8*>(&VsT[g * 128 + (((ks * 4 + lk) ^ (g & 7)) << 3)]);
            o[0][n] = __builtin_amdgcn_mfma_f32_16x16x32_bf16(ap[0], bv, o[0][n], 0, 0, 0);
            o[1][n] = __builtin_amdgcn_mfma_f32_16x16x32_bf16(ap[1], bv, o[1][n], 0, 0, 0);
        }
    }

    // epilogue
    #pragma unroll
    for (int m = 0; m < 2; ++m)
        #pragma unroll
        for (int j = 0; j < 4; ++j) {
            int t = mbase + m * 16 + lk * 4 + j;
            float rinv = 1.0f / denl[t];
            #pragma unroll
            for (int n = 0; n < 4; ++n) {
                int g = n * 16 + l16;
                Obf[(row0 + t) * D_ + h * G_ + g] = f2bf(o[m][n][j] * rinv);
            }
        }
}

// ---------------------------------------------------------------------------
extern "C" void kernel_launch(void* const* d_in, const int* in_sizes, int n_in,
                              void* d_out, int out_size, void* d_ws, size_t ws_size,
                              hipStream_t stream) {
    const float* x  = (const float*)d_in[0];
    const float* wq = (const float*)d_in[1];
    const float* bq = (const float*)d_in[2];
    const float* wk = (const float*)d_in[3];
    const float* bk = (const float*)d_in[4];
    const float* wv = (const float*)d_in[5];
    const float* bv = (const float*)d_in[6];
    const float* wo = (const float*)d_in[7];
    const float* bo = (const float*)d_in[8];
    float* out = (float*)d_out;

    size_t off = 0;
    char* base = (char*)d_ws;
    auto alloc = [&](size_t bytes) -> void* {
        void* p = base + off;
        off += (bytes + 255) & ~(size_t)255;
        return p;
    };
    const size_t MN = (size_t)B_ * N_;   // 4096
    ushort* QKV   = (ushort*)alloc(MN * QKVLD * 2);          // 16 MB fused Q|K|V bf16
    float*  Sb    = (float*) alloc((size_t)B_ * H_ * NCHUNK * F_ * G_ * 4);
    ushort* SbT   = (ushort*)alloc((size_t)B_ * H_ * NCHUNK * G_ * F_ * 2);
    float*  zb    = (float*) alloc((size_t)B_ * H_ * NCHUNK * F_ * 4);
    ushort* xbf   = (ushort*)alloc(MN * D_ * 2);
    ushort* wqkvT = (ushort*)alloc((size_t)QKVLD * D_ * 2);  // 4 MB [2048][1024]
    ushort* wot   = (ushort*)alloc((size_t)D_ * D_ * 2);
    float*  bqkv  = (float*) alloc((size_t)QKVLD * 4);
    ushort* obf   = (ushort*)alloc(MN * D_ * 2);

    const int M = (int)MN;   // 4096

    convert_bf16_kernel<<<dim3((M * D_ / 4 + 255) / 256), 256, 0, stream>>>(x, xbf, M * D_ / 4);
    transpose_bf16_kernel<<<dim3(DHAT_ / 32, D_ / 32), 256, 0, stream>>>(wq, wqkvT, D_, DHAT_);
    transpose_bf16_kernel<<<dim3(DHAT_ / 32, D_ / 32), 256, 0, stream>>>(wk, wqkvT + (size_t)DHAT_ * D_, D_, DHAT_);
    transpose_bf16_kernel<<<dim3(D_ / 32,    D_ / 32), 256, 0, stream>>>(wv, wqkvT + (size_t)2 * DHAT_ * D_, D_, D_);
    transpose_bf16_kernel<<<dim3(D_ / 32,    D_ / 32), 256, 0, stream>>>(wo, wot, D_, D_);
    pack_bias_kernel<<<dim3(QKVLD / 256), 256, 0, stream>>>(bq, bk, bv, bqkv);

    // fused QKV projection (phi on cols < 1024 = Q,K), bf16 out
    mfma_gemm_kernel<true><<<dim3(QKVLD / 128, M / 128), 256, 0, stream>>>(
        xbf, wqkvT, bqkv, QKV, M, D_, QKVLD, 2 * DHAT_);

    // chunked linear attention
    chunk_kv_kernel<<<dim3(NCHUNK, H_, B_), 256, 0, stream>>>(QKV, Sb, zb);
    scan_kernel<<<dim3(B_ * H_), 256, 0, stream>>>(Sb, SbT, zb);
    attn_mfma_kernel<<<dim3(NCHUNK, H_, B_), 256, 0, stream>>>(QKV, SbT, zb, obf);

    // output projection (fp32 out, no phi)
    mfma_gemm_kernel<false><<<dim3(D_ / 128, M / 128), 256, 0, stream>>>(
        obf, wot, bo, out, M, D_, D_, 0);
}

// Round 7
// 169.858 us; speedup vs baseline: 3.4365x; 1.0581x over previous
//
#include <hip/hip_runtime.h>
#include <hip/hip_bf16.h>
#include <math.h>

// Problem constants (from reference)
#define B_    2
#define N_    2048
#define D_    1024
#define DHAT_ 512
#define H_    16
#define F_    32      // qk head dim
#define G_    64      // v head dim
#define CHUNK 128
#define NCHUNK (N_ / CHUNK)   // 16
#define QKVLD 2048            // fused QKV row stride (Q 0..511 | K 512..1023 | V 1024..2047)

typedef __attribute__((ext_vector_type(8))) short bf16x8;
typedef __attribute__((ext_vector_type(4))) float f32x4;

__device__ __forceinline__ float phi_fn(float x) {
    return x > 0.0f ? x + 1.0f : expf(x);   // elu(x)+1
}

__device__ __forceinline__ ushort f2bf(float f) {
    unsigned u = __float_as_uint(f);
    u += 0x7FFFu + ((u >> 16) & 1u);
    return (ushort)(u >> 16);
}

__device__ __forceinline__ float bf2f(ushort u) {
    return __uint_as_float(((unsigned)u) << 16);
}

#define GLOAD_LDS16(g, l) __builtin_amdgcn_global_load_lds( \
    (const __attribute__((address_space(1))) void*)(g),     \
    (__attribute__((address_space(3))) void*)(l), 16, 0, 0)

// swizzle for 64B-row LDS tiles (rows of 32 bf16, 4 slots of 16B)
__device__ __forceinline__ int sw64(int row) { return (row & 3) ^ ((row >> 2) & 3); }
// swizzle for 256B-row tiles (rows of 128 bf16, 16 slots)
__device__ __forceinline__ int swP(int t) { return (t & 7) ^ (((t >> 3) & 1) << 1); }

// ---------------------------------------------------------------------------
// prep_kernel: ONE launch for  x->bf16 | 4 weight transposes | bias pack.
// Region dispatch by flat blockIdx.x:
//   [0,4096)      convert x (1 float4/thread)
//   [4096,4608)   wq -> wqkvT[0]          (16 x 32 tiles)
//   [4608,5120)   wk -> wqkvT[512*1024]   (16 x 32 tiles)
//   [5120,6144)   wv -> wqkvT[1024*1024]  (32 x 32 tiles)
//   [6144,7168)   wo -> wot               (32 x 32 tiles)
//   [7168,7176)   pack bqkv
// ---------------------------------------------------------------------------
__device__ __forceinline__ void transpose_tile(
    const float* __restrict__ W, ushort* __restrict__ Wt,
    int K, int N, int bx, int by, int tid, ushort (*tile)[33])
{
    const int ti = by * 32, tj = bx * 32;
    const int tx = tid & 31, ty = tid >> 5;
    #pragma unroll
    for (int r = 0; r < 4; ++r)
        tile[ty + r * 8][tx] = f2bf(W[(size_t)(ti + ty + r * 8) * N + tj + tx]);
    __syncthreads();
    #pragma unroll
    for (int r = 0; r < 4; ++r)
        Wt[(size_t)(tj + ty + r * 8) * K + ti + tx] = tile[tx][ty + r * 8];
}

__global__ __launch_bounds__(256) void prep_kernel(
    const float* __restrict__ x,
    const float* __restrict__ wq, const float* __restrict__ wk,
    const float* __restrict__ wv, const float* __restrict__ wo,
    const float* __restrict__ bq, const float* __restrict__ bk,
    const float* __restrict__ bv,
    ushort* __restrict__ xbf, ushort* __restrict__ wqkvT,
    ushort* __restrict__ wot, float* __restrict__ bqkv)
{
    __shared__ ushort tile[32][33];
    const int id = blockIdx.x, tid = threadIdx.x;

    if (id < 4096) {
        int i = id * 256 + tid;
        float4 a = reinterpret_cast<const float4*>(x)[i];
        ushort4 o;
        o.x = f2bf(a.x); o.y = f2bf(a.y); o.z = f2bf(a.z); o.w = f2bf(a.w);
        reinterpret_cast<ushort4*>(xbf)[i] = o;
    } else if (id < 4608) {
        int tt = id - 4096;
        transpose_tile(wq, wqkvT, D_, DHAT_, tt & 15, tt >> 4, tid, tile);
    } else if (id < 5120) {
        int tt = id - 4608;
        transpose_tile(wk, wqkvT + (size_t)DHAT_ * D_, D_, DHAT_, tt & 15, tt >> 4, tid, tile);
    } else if (id < 6144) {
        int tt = id - 5120;
        transpose_tile(wv, wqkvT + (size_t)2 * DHAT_ * D_, D_, D_, tt & 31, tt >> 5, tid, tile);
    } else if (id < 7168) {
        int tt = id - 6144;
        transpose_tile(wo, wot, D_, D_, tt & 31, tt >> 5, tid, tile);
    } else {
        int i = (id - 7168) * 256 + tid;
        float v;
        if (i < DHAT_)          v = bq[i];
        else if (i < 2 * DHAT_) v = bk[i - DHAT_];
        else                    v = bv[i - 2 * DHAT_];
        bqkv[i] = v;
    }
}

// ---------------------------------------------------------------------------
// MFMA bf16 GEMM (m97 structure). phi applied to col < phi_upto.
// BM=BN=128, BK=32; 256 threads = 4 waves (2x2), 64x64/wave, 4x4 frags.
// ---------------------------------------------------------------------------
template<bool OUTBF>
__global__ __launch_bounds__(256) void mfma_gemm_kernel(
    const ushort* __restrict__ A, const ushort* __restrict__ Wt,
    const float* __restrict__ bias, void* __restrict__ Cout,
    int M, int K, int N, int phi_upto)
{
    __shared__ __attribute__((aligned(16))) ushort Asm[128 * 32];
    __shared__ __attribute__((aligned(16))) ushort Bsm[128 * 32];

    const int tid  = threadIdx.x;
    const int lane = tid & 63;
    const int wave = tid >> 6;
    const int wr   = wave >> 1, wc = wave & 1;
    const int brow = blockIdx.y * 128, bcol = blockIdx.x * 128;
    const int l16  = lane & 15, lk = lane >> 4;

    f32x4 acc[4][4];
    #pragma unroll
    for (int m = 0; m < 4; ++m)
        #pragma unroll
        for (int n = 0; n < 4; ++n)
            acc[m][n] = (f32x4){0.f, 0.f, 0.f, 0.f};

    for (int k0 = 0; k0 < K; k0 += 32) {
        __syncthreads();
        #pragma unroll
        for (int r = 0; r < 2; ++r) {
            int fi  = r * 256 + tid;
            int row = fi >> 2;
            int c8  = (fi & 3) << 3;
            GLOAD_LDS16(&A [(size_t)(brow + row) * K + k0 + c8], &Asm[fi * 8]);
            GLOAD_LDS16(&Wt[(size_t)(bcol + row) * K + k0 + c8], &Bsm[fi * 8]);
        }
        __syncthreads();

        bf16x8 af[4], bf[4];
        #pragma unroll
        for (int m = 0; m < 4; ++m)
            af[m] = *reinterpret_cast<const bf16x8*>(&Asm[(wr * 64 + m * 16 + l16) * 32 + lk * 8]);
        #pragma unroll
        for (int n = 0; n < 4; ++n)
            bf[n] = *reinterpret_cast<const bf16x8*>(&Bsm[(wc * 64 + n * 16 + l16) * 32 + lk * 8]);
        #pragma unroll
        for (int m = 0; m < 4; ++m)
            #pragma unroll
            for (int n = 0; n < 4; ++n)
                acc[m][n] = __builtin_amdgcn_mfma_f32_16x16x32_bf16(af[m], bf[n], acc[m][n], 0, 0, 0);
    }

    // C/D layout: col=lane&15, row=(lane>>4)*4+j  [m89/m91 verified]
    #pragma unroll
    for (int n = 0; n < 4; ++n) {
        int col = bcol + wc * 64 + n * 16 + l16;
        float bv = bias[col];
        const bool do_phi = col < phi_upto;
        #pragma unroll
        for (int m = 0; m < 4; ++m) {
            int row0 = brow + wr * 64 + m * 16 + lk * 4;
            #pragma unroll
            for (int j = 0; j < 4; ++j) {
                float v = acc[m][n][j] + bv;
                if (do_phi) v = phi_fn(v);
                if (OUTBF)
                    ((ushort*)Cout)[(size_t)(row0 + j) * N + col] = f2bf(v);
                else
                    ((float*)Cout)[(size_t)(row0 + j) * N + col] = v;
            }
        }
    }
}

// ---------------------------------------------------------------------------
// Pass A (MFMA): S_c[f][g] = sum_t K[t][f]*V[t][g],  z_c[f] = sum_t K[t][f]
// ---------------------------------------------------------------------------
__global__ __launch_bounds__(256) void chunk_kv_kernel(
    const ushort* __restrict__ QKV, float* __restrict__ Sb, float* __restrict__ zb)
{
    __shared__ __attribute__((aligned(16))) ushort KsT[32 * 128];   //  8 KB [f][t]
    __shared__ __attribute__((aligned(16))) ushort VsT[64 * 128];   // 16 KB [g][t]

    const int c = blockIdx.x, h = blockIdx.y, b = blockIdx.z;
    const int tid = threadIdx.x;
    const int lane = tid & 63, wave = tid >> 6;
    const int l16 = lane & 15, lk = lane >> 4;
    const size_t row0 = (size_t)b * N_ + (size_t)c * CHUNK;

    // stage K^T [f][t]
    #pragma unroll
    for (int r = 0; r < 2; ++r) {
        int fi = r * 256 + tid;
        int t = fi >> 2, f8 = (fi & 3) << 3;
        bf16x8 v = *reinterpret_cast<const bf16x8*>(&QKV[(row0 + t) * QKVLD + DHAT_ + h * F_ + f8]);
        #pragma unroll
        for (int i = 0; i < 8; ++i) {
            int f = f8 + i;
            KsT[f * 128 + (t ^ ((f & 7) << 3))] = (ushort)v[i];
        }
    }
    // stage V^T [g][t]
    {
        int s = tid & 127, gh = tid >> 7;
        const ushort* vsrc = &QKV[(row0 + s) * QKVLD + 2 * DHAT_ + h * G_ + gh * 32];
        #pragma unroll
        for (int w = 0; w < 4; ++w) {
            bf16x8 v = *reinterpret_cast<const bf16x8*>(&vsrc[w * 8]);
            #pragma unroll
            for (int i = 0; i < 8; ++i) {
                int g = gh * 32 + w * 8 + i;
                VsT[g * 128 + (s ^ ((g & 7) << 3))] = (ushort)v[i];
            }
        }
    }
    __syncthreads();

    // wave w owns g-tile w, f-tiles 0..1
    f32x4 sacc[2];
    sacc[0] = (f32x4){0.f, 0.f, 0.f, 0.f};
    sacc[1] = (f32x4){0.f, 0.f, 0.f, 0.f};
    const int g = wave * 16 + l16;
    #pragma unroll
    for (int ks = 0; ks < 4; ++ks) {
        int sl = ks * 4 + lk;
        bf16x8 bv = *reinterpret_cast<const bf16x8*>(&VsT[g * 128 + ((sl ^ (g & 7)) << 3)]);
        #pragma unroll
        for (int m = 0; m < 2; ++m) {
            int f = m * 16 + l16;
            bf16x8 ak = *reinterpret_cast<const bf16x8*>(&KsT[f * 128 + ((sl ^ (f & 7)) << 3)]);
            sacc[m] = __builtin_amdgcn_mfma_f32_16x16x32_bf16(ak, bv, sacc[m], 0, 0, 0);
        }
    }

    const size_t sbase = ((size_t)((b * H_ + h) * NCHUNK + c)) * (F_ * G_);
    #pragma unroll
    for (int m = 0; m < 2; ++m)
        #pragma unroll
        for (int j = 0; j < 4; ++j) {
            int f = m * 16 + lk * 4 + j;
            Sb[sbase + (size_t)f * G_ + g] = sacc[m][j];
        }

    // z[f]
    {
        int f = tid >> 3, i = tid & 7;
        float zs = 0.0f;
        #pragma unroll
        for (int ss = 0; ss < 2; ++ss) {
            int sl = i * 2 + ss;
            bf16x8 kv = *reinterpret_cast<const bf16x8*>(&KsT[f * 128 + ((sl ^ (f & 7)) << 3)]);
            #pragma unroll
            for (int e = 0; e < 8; ++e) zs += bf2f((ushort)kv[e]);
        }
        zs += __shfl_xor(zs, 1);
        zs += __shfl_xor(zs, 2);
        zs += __shfl_xor(zs, 4);
        if (i == 0) zb[((size_t)(b * H_ + h) * NCHUNK + c) * F_ + f] = zs;
    }
}

// ---------------------------------------------------------------------------
// Pass B: exclusive prefix scan; writes SbT bf16 [g][f]; zb in-place.
// ---------------------------------------------------------------------------
__global__ __launch_bounds__(256) void scan_kernel(
    const float* __restrict__ Sb, ushort* __restrict__ SbT, float* __restrict__ zb)
{
    const int bh = blockIdx.x;
    const int tid = threadIdx.x;
    const int g = tid >> 2, f0 = (tid & 3) << 3;

    float p[8] = {};
    for (int c = 0; c < NCHUNK; ++c) {
        const size_t sbase = ((size_t)bh * NCHUNK + c) * (F_ * G_);
        float t[8];
        #pragma unroll
        for (int i = 0; i < 8; ++i) t[i] = Sb[sbase + (size_t)(f0 + i) * G_ + g];
        bf16x8 w;
        #pragma unroll
        for (int i = 0; i < 8; ++i) w[i] = (short)f2bf(p[i]);
        *reinterpret_cast<bf16x8*>(&SbT[(((size_t)bh * NCHUNK + c) * G_ + g) * F_ + f0]) = w;
        #pragma unroll
        for (int i = 0; i < 8; ++i) p[i] += t[i];
    }
    if (tid < F_) {
        float pz = 0.0f;
        for (int c = 0; c < NCHUNK; ++c) {
            size_t base = ((size_t)bh * NCHUNK + c) * F_ + tid;
            float t = zb[base];
            zb[base] = pz;
            pz += t;
        }
    }
}

// ---------------------------------------------------------------------------
// Pass C (MFMA): P = tril(QK^T); den = rowsum(P)+q.z_prefix;
// out = (P@V + Q@S_prefix)/den. grid (NCHUNK,H,B), 4 waves.
// ---------------------------------------------------------------------------
__global__ __launch_bounds__(256) void attn_mfma_kernel(
    const ushort* __restrict__ QKV, const ushort* __restrict__ SbT,
    const float* __restrict__ zb, ushort* __restrict__ Obf)
{
    __shared__ __attribute__((aligned(16))) ushort Qs[128 * 32];   //  8 KB [t][f]  sw64
    __shared__ __attribute__((aligned(16))) ushort Ks[128 * 32];   //  8 KB [s][f]  sw64
    __shared__ __attribute__((aligned(16))) ushort VsT[64 * 128];  // 16 KB [g][s]
    __shared__ __attribute__((aligned(16))) ushort Ss[64 * 32];    //  4 KB [g][f]  sw64
    __shared__ __attribute__((aligned(16))) ushort Ps[128 * 128];  // 32 KB [t][s]  swP
    __shared__ float zl[F_];
    __shared__ float denl[CHUNK];

    const int c = blockIdx.x, h = blockIdx.y, b = blockIdx.z;
    const int tid = threadIdx.x;
    const int lane = tid & 63, wave = tid >> 6;
    const int l16 = lane & 15, lk = lane >> 4;
    const size_t row0 = (size_t)b * N_ + (size_t)c * CHUNK;
    const int bh = b * H_ + h;

    // stage Q, K (source pre-swizzled -> linear LDS)
    #pragma unroll
    for (int r = 0; r < 2; ++r) {
        int fi = r * 256 + tid;
        int row = fi >> 2;
        int c8 = ((fi & 3) ^ sw64(row)) << 3;
        GLOAD_LDS16(&QKV[(row0 + row) * QKVLD + h * F_ + c8], &Qs[fi * 8]);
        GLOAD_LDS16(&QKV[(row0 + row) * QKVLD + DHAT_ + h * F_ + c8], &Ks[fi * 8]);
    }
    // stage S_prefix^T
    {
        int g = tid >> 2;
        int f8 = ((tid & 3) ^ sw64(g)) << 3;
        GLOAD_LDS16(&SbT[(((size_t)bh * NCHUNK + c) * G_ + g) * F_ + f8], &Ss[tid * 8]);
    }
    if (tid < F_) zl[tid] = zb[((size_t)bh * NCHUNK + c) * F_ + tid];
    // stage V transposed [g][s]
    {
        int s = tid & 127, gh = tid >> 7;
        const ushort* vsrc = &QKV[(row0 + s) * QKVLD + 2 * DHAT_ + h * G_ + gh * 32];
        #pragma unroll
        for (int w = 0; w < 4; ++w) {
            bf16x8 v = *reinterpret_cast<const bf16x8*>(&vsrc[w * 8]);
            #pragma unroll
            for (int i = 0; i < 8; ++i) {
                int g = gh * 32 + w * 8 + i;
                VsT[g * 128 + (s ^ ((g & 7) << 3))] = (ushort)v[i];
            }
        }
    }
    __syncthreads();

    const int mbase = wave * 32;

    bf16x8 aq[2];
    #pragma unroll
    for (int m = 0; m < 2; ++m) {
        int row = mbase + m * 16 + l16;
        aq[m] = *reinterpret_cast<const bf16x8*>(&Qs[row * 32 + ((lk ^ sw64(row)) << 3)]);
    }

    // P = Q K^T (wave's 32 rows x 128 cols)
    f32x4 p[2][8];
    #pragma unroll
    for (int m = 0; m < 2; ++m)
        #pragma unroll
        for (int n = 0; n < 8; ++n)
            p[m][n] = (f32x4){0.f, 0.f, 0.f, 0.f};
    #pragma unroll
    for (int n = 0; n < 8; ++n) {
        int srow = n * 16 + l16;
        bf16x8 bk = *reinterpret_cast<const bf16x8*>(&Ks[srow * 32 + ((lk ^ sw64(srow)) << 3)]);
        p[0][n] = __builtin_amdgcn_mfma_f32_16x16x32_bf16(aq[0], bk, p[0][n], 0, 0, 0);
        p[1][n] = __builtin_amdgcn_mfma_f32_16x16x32_bf16(aq[1], bk, p[1][n], 0, 0, 0);
    }

    // causal mask + cvt + store Ps (swizzled)
    #pragma unroll
    for (int m = 0; m < 2; ++m)
        #pragma unroll
        for (int n = 0; n < 8; ++n) {
            int s = n * 16 + l16;
            #pragma unroll
            for (int j = 0; j < 4; ++j) {
                int t = mbase + m * 16 + lk * 4 + j;
                float v = (s <= t) ? p[m][n][j] : 0.0f;
                Ps[t * 128 + ((s & 7) | (((s >> 3) ^ swP(t)) << 3))] = f2bf(v);
            }
        }

    // den[t]
    {
        int t = tid >> 1, h2 = tid & 1;
        float rs = 0.0f;
        #pragma unroll
        for (int r = 0; r < 8; ++r) {
            int sl = h2 * 8 + r;
            bf16x8 pv = *reinterpret_cast<const bf16x8*>(&Ps[t * 128 + ((sl ^ swP(t)) << 3)]);
            #pragma unroll
            for (int i = 0; i < 8; ++i) rs += bf2f((ushort)pv[i]);
        }
        #pragma unroll
        for (int ss = 0; ss < 2; ++ss) {
            int sl = h2 * 2 + ss;
            bf16x8 qv = *reinterpret_cast<const bf16x8*>(&Qs[t * 32 + ((sl ^ sw64(t)) << 3)]);
            #pragma unroll
            for (int i = 0; i < 8; ++i) rs += bf2f((ushort)qv[i]) * zl[sl * 8 + i];
        }
        rs += __shfl_xor(rs, 1);
        if (h2 == 0) denl[t] = rs + 1e-6f;
    }

    // out = Q @ S_prefix + P @ V
    f32x4 o[2][4];
    #pragma unroll
    for (int m = 0; m < 2; ++m)
        #pragma unroll
        for (int n = 0; n < 4; ++n)
            o[m][n] = (f32x4){0.f, 0.f, 0.f, 0.f};
    #pragma unroll
    for (int n = 0; n < 4; ++n) {
        int g = n * 16 + l16;
        bf16x8 bs = *reinterpret_cast<const bf16x8*>(&Ss[g * 32 + ((lk ^ sw64(g)) << 3)]);
        o[0][n] = __builtin_amdgcn_mfma_f32_16x16x32_bf16(aq[0], bs, o[0][n], 0, 0, 0);
        o[1][n] = __builtin_amdgcn_mfma_f32_16x16x32_bf16(aq[1], bs, o[1][n], 0, 0, 0);
    }
    #pragma unroll
    for (int ks = 0; ks < 4; ++ks) {
        bf16x8 ap[2];
        #pragma unroll
        for (int m = 0; m < 2; ++m) {
            int t = mbase + m * 16 + l16;
            int sl = ks * 4 + lk;
            ap[m] = *reinterpret_cast<const bf16x8*>(&Ps[t * 128 + ((sl ^ swP(t)) << 3)]);
        }
        #pragma unroll
        for (int n = 0; n < 4; ++n) {
            int g = n * 16 + l16;
            bf16x8 bv = *reinterpret_cast<const bf16x8*>(&VsT[g * 128 + (((ks * 4 + lk) ^ (g & 7)) << 3)]);
            o[0][n] = __builtin_amdgcn_mfma_f32_16x16x32_bf16(ap[0], bv, o[0][n], 0, 0, 0);
            o[1][n] = __builtin_amdgcn_mfma_f32_16x16x32_bf16(ap[1], bv, o[1][n], 0, 0, 0);
        }
    }

    // epilogue
    #pragma unroll
    for (int m = 0; m < 2; ++m)
        #pragma unroll
        for (int j = 0; j < 4; ++j) {
            int t = mbase + m * 16 + lk * 4 + j;
            float rinv = 1.0f / denl[t];
            #pragma unroll
            for (int n = 0; n < 4; ++n) {
                int g = n * 16 + l16;
                Obf[(row0 + t) * D_ + h * G_ + g] = f2bf(o[m][n][j] * rinv);
            }
        }
}

// ---------------------------------------------------------------------------
extern "C" void kernel_launch(void* const* d_in, const int* in_sizes, int n_in,
                              void* d_out, int out_size, void* d_ws, size_t ws_size,
                              hipStream_t stream) {
    const float* x  = (const float*)d_in[0];
    const float* wq = (const float*)d_in[1];
    const float* bq = (const float*)d_in[2];
    const float* wk = (const float*)d_in[3];
    const float* bk = (const float*)d_in[4];
    const float* wv = (const float*)d_in[5];
    const float* bv = (const float*)d_in[6];
    const float* wo = (const float*)d_in[7];
    const float* bo = (const float*)d_in[8];
    float* out = (float*)d_out;

    size_t off = 0;
    char* base = (char*)d_ws;
    auto alloc = [&](size_t bytes) -> void* {
        void* p = base + off;
        off += (bytes + 255) & ~(size_t)255;
        return p;
    };
    const size_t MN = (size_t)B_ * N_;   // 4096
    ushort* QKV   = (ushort*)alloc(MN * QKVLD * 2);
    float*  Sb    = (float*) alloc((size_t)B_ * H_ * NCHUNK * F_ * G_ * 4);
    ushort* SbT   = (ushort*)alloc((size_t)B_ * H_ * NCHUNK * G_ * F_ * 2);
    float*  zb    = (float*) alloc((size_t)B_ * H_ * NCHUNK * F_ * 4);
    ushort* xbf   = (ushort*)alloc(MN * D_ * 2);
    ushort* wqkvT = (ushort*)alloc((size_t)QKVLD * D_ * 2);
    ushort* wot   = (ushort*)alloc((size_t)D_ * D_ * 2);
    float*  bqkv  = (float*) alloc((size_t)QKVLD * 4);
    ushort* obf   = (ushort*)alloc(MN * D_ * 2);

    const int M = (int)MN;   // 4096

    // one prep launch: convert + 4 transposes + bias pack
    prep_kernel<<<dim3(7176), 256, 0, stream>>>(
        x, wq, wk, wv, wo, bq, bk, bv, xbf, wqkvT, wot, bqkv);

    // fused QKV projection (phi on cols < 1024 = Q,K), bf16 out
    mfma_gemm_kernel<true><<<dim3(QKVLD / 128, M / 128), 256, 0, stream>>>(
        xbf, wqkvT, bqkv, QKV, M, D_, QKVLD, 2 * DHAT_);

    // chunked linear attention (3 plain launches — cooperative launch fails on
    // this harness; verified-correct round-4 structure)
    chunk_kv_kernel<<<dim3(NCHUNK, H_, B_), 256, 0, stream>>>(QKV, Sb, zb);
    scan_kernel<<<dim3(B_ * H_), 256, 0, stream>>>(Sb, SbT, zb);
    attn_mfma_kernel<<<dim3(NCHUNK, H_, B_), 256, 0, stream>>>(QKV, SbT, zb, obf);

    // output projection (fp32 out, no phi)
    mfma_gemm_kernel<false><<<dim3(D_ / 128, M / 128), 256, 0, stream>>>(
        obf, wot, bo, out, M, D_, D_, 0);
}

// Round 8
// 165.434 us; speedup vs baseline: 3.5284x; 1.0267x over previous
//
#include <hip/hip_runtime.h>
#include <hip/hip_bf16.h>
#include <math.h>

// Problem constants (from reference)
#define B_    2
#define N_    2048
#define D_    1024
#define DHAT_ 512
#define H_    16
#define F_    32      // qk head dim
#define G_    64      // v head dim
#define CHUNK 128
#define NCHUNK (N_ / CHUNK)   // 16
#define QKVLD 2048            // fused QKV row stride (Q 0..511 | K 512..1023 | V 1024..2047)

typedef __attribute__((ext_vector_type(8))) short bf16x8;
typedef __attribute__((ext_vector_type(4))) float f32x4;

__device__ __forceinline__ float phi_fn(float x) {
    return x > 0.0f ? x + 1.0f : expf(x);   // elu(x)+1
}

__device__ __forceinline__ ushort f2bf(float f) {
    unsigned u = __float_as_uint(f);
    u += 0x7FFFu + ((u >> 16) & 1u);
    return (ushort)(u >> 16);
}

__device__ __forceinline__ float bf2f(ushort u) {
    return __uint_as_float(((unsigned)u) << 16);
}

#define GLOAD_LDS16(g, l) __builtin_amdgcn_global_load_lds( \
    (const __attribute__((address_space(1))) void*)(g),     \
    (__attribute__((address_space(3))) void*)(l), 16, 0, 0)

// swizzle for 64B-row LDS tiles (rows of 32 bf16, 4 slots of 16B)
__device__ __forceinline__ int sw64(int row) { return (row & 3) ^ ((row >> 2) & 3); }
// swizzle for 256B-row tiles (rows of 128 bf16, 16 slots)
__device__ __forceinline__ int swP(int t) { return (t & 7) ^ (((t >> 3) & 1) << 1); }

// ---------------------------------------------------------------------------
// prep_kernel: ONE launch for  x->bf16 | 4 weight transposes | bias pack.
// ---------------------------------------------------------------------------
__device__ __forceinline__ void transpose_tile(
    const float* __restrict__ W, ushort* __restrict__ Wt,
    int K, int N, int bx, int by, int tid, ushort (*tile)[33])
{
    const int ti = by * 32, tj = bx * 32;
    const int tx = tid & 31, ty = tid >> 5;
    #pragma unroll
    for (int r = 0; r < 4; ++r)
        tile[ty + r * 8][tx] = f2bf(W[(size_t)(ti + ty + r * 8) * N + tj + tx]);
    __syncthreads();
    #pragma unroll
    for (int r = 0; r < 4; ++r)
        Wt[(size_t)(tj + ty + r * 8) * K + ti + tx] = tile[tx][ty + r * 8];
}

__global__ __launch_bounds__(256) void prep_kernel(
    const float* __restrict__ x,
    const float* __restrict__ wq, const float* __restrict__ wk,
    const float* __restrict__ wv, const float* __restrict__ wo,
    const float* __restrict__ bq, const float* __restrict__ bk,
    const float* __restrict__ bv,
    ushort* __restrict__ xbf, ushort* __restrict__ wqkvT,
    ushort* __restrict__ wot, float* __restrict__ bqkv)
{
    __shared__ ushort tile[32][33];
    const int id = blockIdx.x, tid = threadIdx.x;

    if (id < 4096) {
        int i = id * 256 + tid;
        float4 a = reinterpret_cast<const float4*>(x)[i];
        ushort4 o;
        o.x = f2bf(a.x); o.y = f2bf(a.y); o.z = f2bf(a.z); o.w = f2bf(a.w);
        reinterpret_cast<ushort4*>(xbf)[i] = o;
    } else if (id < 4608) {
        int tt = id - 4096;
        transpose_tile(wq, wqkvT, D_, DHAT_, tt & 15, tt >> 4, tid, tile);
    } else if (id < 5120) {
        int tt = id - 4608;
        transpose_tile(wk, wqkvT + (size_t)DHAT_ * D_, D_, DHAT_, tt & 15, tt >> 4, tid, tile);
    } else if (id < 6144) {
        int tt = id - 5120;
        transpose_tile(wv, wqkvT + (size_t)2 * DHAT_ * D_, D_, D_, tt & 31, tt >> 5, tid, tile);
    } else if (id < 7168) {
        int tt = id - 6144;
        transpose_tile(wo, wot, D_, D_, tt & 31, tt >> 5, tid, tile);
    } else {
        int i = (id - 7168) * 256 + tid;
        float v;
        if (i < DHAT_)          v = bq[i];
        else if (i < 2 * DHAT_) v = bk[i - DHAT_];
        else                    v = bv[i - 2 * DHAT_];
        bqkv[i] = v;
    }
}

// ---------------------------------------------------------------------------
// MFMA bf16 GEMM (m97 structure) + T1 XCD swizzle. phi on col < phi_upto.
// BM=128, BN template (128 or 64); 256 thr = 4 waves (2x2), wave = 64 x BN/2.
// BN=64 variant keeps grid at 512 WGs (2/CU) for narrow-N GEMMs.
// ---------------------------------------------------------------------------
template<bool OUTBF, int BN>
__global__ __launch_bounds__(256) void mfma_gemm_kernel(
    const ushort* __restrict__ A, const ushort* __restrict__ Wt,
    const float* __restrict__ bias, void* __restrict__ Cout,
    int M, int K, int N, int phi_upto)
{
    constexpr int NF = BN / 32;               // n-frags per wave (128->4, 64->2)
    __shared__ __attribute__((aligned(16))) ushort Asm[128 * 32];
    __shared__ __attribute__((aligned(16))) ushort Bsm[BN * 32];

    const int tid  = threadIdx.x;
    const int lane = tid & 63;
    const int wave = tid >> 6;
    const int wr   = wave >> 1, wc = wave & 1;

    // T1: XCD-aware bijective remap (nwg % 8 == 0 for all our grids).
    // Consecutive swz within an XCD walk bx fastest -> A row-panel L2-resident.
    const int nwg  = gridDim.x * gridDim.y;
    const int flat = blockIdx.y * gridDim.x + blockIdx.x;
    const int cpx  = nwg >> 3;
    const int swz  = (flat & 7) * cpx + (flat >> 3);
    const int bx   = swz % gridDim.x, by = swz / gridDim.x;

    const int brow = by * 128, bcol = bx * BN;
    const int l16  = lane & 15, lk = lane >> 4;

    f32x4 acc[4][NF];
    #pragma unroll
    for (int m = 0; m < 4; ++m)
        #pragma unroll
        for (int n = 0; n < NF; ++n)
            acc[m][n] = (f32x4){0.f, 0.f, 0.f, 0.f};

    for (int k0 = 0; k0 < K; k0 += 32) {
        __syncthreads();
        #pragma unroll
        for (int r = 0; r < 2; ++r) {         // A: 512 slots
            int fi  = r * 256 + tid;
            int row = fi >> 2;
            int c8  = (fi & 3) << 3;
            GLOAD_LDS16(&A[(size_t)(brow + row) * K + k0 + c8], &Asm[fi * 8]);
        }
        #pragma unroll
        for (int r = 0; r < BN / 64; ++r) {   // B: BN*4 slots
            int fi  = r * 256 + tid;
            int row = fi >> 2;
            int c8  = (fi & 3) << 3;
            GLOAD_LDS16(&Wt[(size_t)(bcol + row) * K + k0 + c8], &Bsm[fi * 8]);
        }
        __syncthreads();

        bf16x8 af[4], bf[NF];
        #pragma unroll
        for (int m = 0; m < 4; ++m)
            af[m] = *reinterpret_cast<const bf16x8*>(&Asm[(wr * 64 + m * 16 + l16) * 32 + lk * 8]);
        #pragma unroll
        for (int n = 0; n < NF; ++n)
            bf[n] = *reinterpret_cast<const bf16x8*>(&Bsm[(wc * (BN / 2) + n * 16 + l16) * 32 + lk * 8]);
        #pragma unroll
        for (int m = 0; m < 4; ++m)
            #pragma unroll
            for (int n = 0; n < NF; ++n)
                acc[m][n] = __builtin_amdgcn_mfma_f32_16x16x32_bf16(af[m], bf[n], acc[m][n], 0, 0, 0);
    }

    // C/D layout: col=lane&15, row=(lane>>4)*4+j  [m89/m91 verified]
    #pragma unroll
    for (int n = 0; n < NF; ++n) {
        int col = bcol + wc * (BN / 2) + n * 16 + l16;
        float bv = bias[col];
        const bool do_phi = col < phi_upto;
        #pragma unroll
        for (int m = 0; m < 4; ++m) {
            int row0 = brow + wr * 64 + m * 16 + lk * 4;
            #pragma unroll
            for (int j = 0; j < 4; ++j) {
                float v = acc[m][n][j] + bv;
                if (do_phi) v = phi_fn(v);
                if (OUTBF)
                    ((ushort*)Cout)[(size_t)(row0 + j) * N + col] = f2bf(v);
                else
                    ((float*)Cout)[(size_t)(row0 + j) * N + col] = v;
            }
        }
    }
}

// ---------------------------------------------------------------------------
// Pass A (MFMA): S_c[f][g] = sum_t K[t][f]*V[t][g],  z_c[f] = sum_t K[t][f]
// ---------------------------------------------------------------------------
__global__ __launch_bounds__(256) void chunk_kv_kernel(
    const ushort* __restrict__ QKV, float* __restrict__ Sb, float* __restrict__ zb)
{
    __shared__ __attribute__((aligned(16))) ushort KsT[32 * 128];   //  8 KB [f][t]
    __shared__ __attribute__((aligned(16))) ushort VsT[64 * 128];   // 16 KB [g][t]

    const int c = blockIdx.x, h = blockIdx.y, b = blockIdx.z;
    const int tid = threadIdx.x;
    const int lane = tid & 63, wave = tid >> 6;
    const int l16 = lane & 15, lk = lane >> 4;
    const size_t row0 = (size_t)b * N_ + (size_t)c * CHUNK;

    // stage K^T [f][t]
    #pragma unroll
    for (int r = 0; r < 2; ++r) {
        int fi = r * 256 + tid;
        int t = fi >> 2, f8 = (fi & 3) << 3;
        bf16x8 v = *reinterpret_cast<const bf16x8*>(&QKV[(row0 + t) * QKVLD + DHAT_ + h * F_ + f8]);
        #pragma unroll
        for (int i = 0; i < 8; ++i) {
            int f = f8 + i;
            KsT[f * 128 + (t ^ ((f & 7) << 3))] = (ushort)v[i];
        }
    }
    // stage V^T [g][t]
    {
        int s = tid & 127, gh = tid >> 7;
        const ushort* vsrc = &QKV[(row0 + s) * QKVLD + 2 * DHAT_ + h * G_ + gh * 32];
        #pragma unroll
        for (int w = 0; w < 4; ++w) {
            bf16x8 v = *reinterpret_cast<const bf16x8*>(&vsrc[w * 8]);
            #pragma unroll
            for (int i = 0; i < 8; ++i) {
                int g = gh * 32 + w * 8 + i;
                VsT[g * 128 + (s ^ ((g & 7) << 3))] = (ushort)v[i];
            }
        }
    }
    __syncthreads();

    // wave w owns g-tile w, f-tiles 0..1
    f32x4 sacc[2];
    sacc[0] = (f32x4){0.f, 0.f, 0.f, 0.f};
    sacc[1] = (f32x4){0.f, 0.f, 0.f, 0.f};
    const int g = wave * 16 + l16;
    #pragma unroll
    for (int ks = 0; ks < 4; ++ks) {
        int sl = ks * 4 + lk;
        bf16x8 bv = *reinterpret_cast<const bf16x8*>(&VsT[g * 128 + ((sl ^ (g & 7)) << 3)]);
        #pragma unroll
        for (int m = 0; m < 2; ++m) {
            int f = m * 16 + l16;
            bf16x8 ak = *reinterpret_cast<const bf16x8*>(&KsT[f * 128 + ((sl ^ (f & 7)) << 3)]);
            sacc[m] = __builtin_amdgcn_mfma_f32_16x16x32_bf16(ak, bv, sacc[m], 0, 0, 0);
        }
    }

    const size_t sbase = ((size_t)((b * H_ + h) * NCHUNK + c)) * (F_ * G_);
    #pragma unroll
    for (int m = 0; m < 2; ++m)
        #pragma unroll
        for (int j = 0; j < 4; ++j) {
            int f = m * 16 + lk * 4 + j;
            Sb[sbase + (size_t)f * G_ + g] = sacc[m][j];
        }

    // z[f]
    {
        int f = tid >> 3, i = tid & 7;
        float zs = 0.0f;
        #pragma unroll
        for (int ss = 0; ss < 2; ++ss) {
            int sl = i * 2 + ss;
            bf16x8 kv = *reinterpret_cast<const bf16x8*>(&KsT[f * 128 + ((sl ^ (f & 7)) << 3)]);
            #pragma unroll
            for (int e = 0; e < 8; ++e) zs += bf2f((ushort)kv[e]);
        }
        zs += __shfl_xor(zs, 1);
        zs += __shfl_xor(zs, 2);
        zs += __shfl_xor(zs, 4);
        if (i == 0) zb[((size_t)(b * H_ + h) * NCHUNK + c) * F_ + f] = zs;
    }
}

// ---------------------------------------------------------------------------
// Pass B: exclusive prefix scan; writes SbT bf16 [g][f]; zb in-place.
// ---------------------------------------------------------------------------
__global__ __launch_bounds__(256) void scan_kernel(
    const float* __restrict__ Sb, ushort* __restrict__ SbT, float* __restrict__ zb)
{
    const int bh = blockIdx.x;
    const int tid = threadIdx.x;
    const int g = tid >> 2, f0 = (tid & 3) << 3;

    float p[8] = {};
    for (int c = 0; c < NCHUNK; ++c) {
        const size_t sbase = ((size_t)bh * NCHUNK + c) * (F_ * G_);
        float t[8];
        #pragma unroll
        for (int i = 0; i < 8; ++i) t[i] = Sb[sbase + (size_t)(f0 + i) * G_ + g];
        bf16x8 w;
        #pragma unroll
        for (int i = 0; i < 8; ++i) w[i] = (short)f2bf(p[i]);
        *reinterpret_cast<bf16x8*>(&SbT[(((size_t)bh * NCHUNK + c) * G_ + g) * F_ + f0]) = w;
        #pragma unroll
        for (int i = 0; i < 8; ++i) p[i] += t[i];
    }
    if (tid < F_) {
        float pz = 0.0f;
        for (int c = 0; c < NCHUNK; ++c) {
            size_t base = ((size_t)bh * NCHUNK + c) * F_ + tid;
            float t = zb[base];
            zb[base] = pz;
            pz += t;
        }
    }
}

// ---------------------------------------------------------------------------
// Pass C (MFMA): P = tril(QK^T); den = rowsum(P)+q.z_prefix;
// out = (P@V + Q@S_prefix)/den. grid (NCHUNK,H,B), 4 waves.
// ---------------------------------------------------------------------------
__global__ __launch_bounds__(256) void attn_mfma_kernel(
    const ushort* __restrict__ QKV, const ushort* __restrict__ SbT,
    const float* __restrict__ zb, ushort* __restrict__ Obf)
{
    __shared__ __attribute__((aligned(16))) ushort Qs[128 * 32];   //  8 KB [t][f]  sw64
    __shared__ __attribute__((aligned(16))) ushort Ks[128 * 32];   //  8 KB [s][f]  sw64
    __shared__ __attribute__((aligned(16))) ushort VsT[64 * 128];  // 16 KB [g][s]
    __shared__ __attribute__((aligned(16))) ushort Ss[64 * 32];    //  4 KB [g][f]  sw64
    __shared__ __attribute__((aligned(16))) ushort Ps[128 * 128];  // 32 KB [t][s]  swP
    __shared__ float zl[F_];
    __shared__ float denl[CHUNK];

    const int c = blockIdx.x, h = blockIdx.y, b = blockIdx.z;
    const int tid = threadIdx.x;
    const int lane = tid & 63, wave = tid >> 6;
    const int l16 = lane & 15, lk = lane >> 4;
    const size_t row0 = (size_t)b * N_ + (size_t)c * CHUNK;
    const int bh = b * H_ + h;

    // stage Q, K (source pre-swizzled -> linear LDS)
    #pragma unroll
    for (int r = 0; r < 2; ++r) {
        int fi = r * 256 + tid;
        int row = fi >> 2;
        int c8 = ((fi & 3) ^ sw64(row)) << 3;
        GLOAD_LDS16(&QKV[(row0 + row) * QKVLD + h * F_ + c8], &Qs[fi * 8]);
        GLOAD_LDS16(&QKV[(row0 + row) * QKVLD + DHAT_ + h * F_ + c8], &Ks[fi * 8]);
    }
    // stage S_prefix^T
    {
        int g = tid >> 2;
        int f8 = ((tid & 3) ^ sw64(g)) << 3;
        GLOAD_LDS16(&SbT[(((size_t)bh * NCHUNK + c) * G_ + g) * F_ + f8], &Ss[tid * 8]);
    }
    if (tid < F_) zl[tid] = zb[((size_t)bh * NCHUNK + c) * F_ + tid];
    // stage V transposed [g][s]
    {
        int s = tid & 127, gh = tid >> 7;
        const ushort* vsrc = &QKV[(row0 + s) * QKVLD + 2 * DHAT_ + h * G_ + gh * 32];
        #pragma unroll
        for (int w = 0; w < 4; ++w) {
            bf16x8 v = *reinterpret_cast<const bf16x8*>(&vsrc[w * 8]);
            #pragma unroll
            for (int i = 0; i < 8; ++i) {
                int g = gh * 32 + w * 8 + i;
                VsT[g * 128 + (s ^ ((g & 7) << 3))] = (ushort)v[i];
            }
        }
    }
    __syncthreads();

    const int mbase = wave * 32;

    bf16x8 aq[2];
    #pragma unroll
    for (int m = 0; m < 2; ++m) {
        int row = mbase + m * 16 + l16;
        aq[m] = *reinterpret_cast<const bf16x8*>(&Qs[row * 32 + ((lk ^ sw64(row)) << 3)]);
    }

    // P = Q K^T (wave's 32 rows x 128 cols)
    f32x4 p[2][8];
    #pragma unroll
    for (int m = 0; m < 2; ++m)
        #pragma unroll
        for (int n = 0; n < 8; ++n)
            p[m][n] = (f32x4){0.f, 0.f, 0.f, 0.f};
    #pragma unroll
    for (int n = 0; n < 8; ++n) {
        int srow = n * 16 + l16;
        bf16x8 bk = *reinterpret_cast<const bf16x8*>(&Ks[srow * 32 + ((lk ^ sw64(srow)) << 3)]);
        p[0][n] = __builtin_amdgcn_mfma_f32_16x16x32_bf16(aq[0], bk, p[0][n], 0, 0, 0);
        p[1][n] = __builtin_amdgcn_mfma_f32_16x16x32_bf16(aq[1], bk, p[1][n], 0, 0, 0);
    }

    // causal mask + cvt + store Ps (swizzled)
    #pragma unroll
    for (int m = 0; m < 2; ++m)
        #pragma unroll
        for (int n = 0; n < 8; ++n) {
            int s = n * 16 + l16;
            #pragma unroll
            for (int j = 0; j < 4; ++j) {
                int t = mbase + m * 16 + lk * 4 + j;
                float v = (s <= t) ? p[m][n][j] : 0.0f;
                Ps[t * 128 + ((s & 7) | (((s >> 3) ^ swP(t)) << 3))] = f2bf(v);
            }
        }

    // den[t]
    {
        int t = tid >> 1, h2 = tid & 1;
        float rs = 0.0f;
        #pragma unroll
        for (int r = 0; r < 8; ++r) {
            int sl = h2 * 8 + r;
            bf16x8 pv = *reinterpret_cast<const bf16x8*>(&Ps[t * 128 + ((sl ^ swP(t)) << 3)]);
            #pragma unroll
            for (int i = 0; i < 8; ++i) rs += bf2f((ushort)pv[i]);
        }
        #pragma unroll
        for (int ss = 0; ss < 2; ++ss) {
            int sl = h2 * 2 + ss;
            bf16x8 qv = *reinterpret_cast<const bf16x8*>(&Qs[t * 32 + ((sl ^ sw64(t)) << 3)]);
            #pragma unroll
            for (int i = 0; i < 8; ++i) rs += bf2f((ushort)qv[i]) * zl[sl * 8 + i];
        }
        rs += __shfl_xor(rs, 1);
        if (h2 == 0) denl[t] = rs + 1e-6f;
    }

    // out = Q @ S_prefix + P @ V
    f32x4 o[2][4];
    #pragma unroll
    for (int m = 0; m < 2; ++m)
        #pragma unroll
        for (int n = 0; n < 4; ++n)
            o[m][n] = (f32x4){0.f, 0.f, 0.f, 0.f};
    #pragma unroll
    for (int n = 0; n < 4; ++n) {
        int g = n * 16 + l16;
        bf16x8 bs = *reinterpret_cast<const bf16x8*>(&Ss[g * 32 + ((lk ^ sw64(g)) << 3)]);
        o[0][n] = __builtin_amdgcn_mfma_f32_16x16x32_bf16(aq[0], bs, o[0][n], 0, 0, 0);
        o[1][n] = __builtin_amdgcn_mfma_f32_16x16x32_bf16(aq[1], bs, o[1][n], 0, 0, 0);
    }
    #pragma unroll
    for (int ks = 0; ks < 4; ++ks) {
        bf16x8 ap[2];
        #pragma unroll
        for (int m = 0; m < 2; ++m) {
            int t = mbase + m * 16 + l16;
            int sl = ks * 4 + lk;
            ap[m] = *reinterpret_cast<const bf16x8*>(&Ps[t * 128 + ((sl ^ swP(t)) << 3)]);
        }
        #pragma unroll
        for (int n = 0; n < 4; ++n) {
            int g = n * 16 + l16;
            bf16x8 bv = *reinterpret_cast<const bf16x8*>(&VsT[g * 128 + (((ks * 4 + lk) ^ (g & 7)) << 3)]);
            o[0][n] = __builtin_amdgcn_mfma_f32_16x16x32_bf16(ap[0], bv, o[0][n], 0, 0, 0);
            o[1][n] = __builtin_amdgcn_mfma_f32_16x16x32_bf16(ap[1], bv, o[1][n], 0, 0, 0);
        }
    }

    // epilogue
    #pragma unroll
    for (int m = 0; m < 2; ++m)
        #pragma unroll
        for (int j = 0; j < 4; ++j) {
            int t = mbase + m * 16 + lk * 4 + j;
            float rinv = 1.0f / denl[t];
            #pragma unroll
            for (int n = 0; n < 4; ++n) {
                int g = n * 16 + l16;
                Obf[(row0 + t) * D_ + h * G_ + g] = f2bf(o[m][n][j] * rinv);
            }
        }
}

// ---------------------------------------------------------------------------
extern "C" void kernel_launch(void* const* d_in, const int* in_sizes, int n_in,
                              void* d_out, int out_size, void* d_ws, size_t ws_size,
                              hipStream_t stream) {
    const float* x  = (const float*)d_in[0];
    const float* wq = (const float*)d_in[1];
    const float* bq = (const float*)d_in[2];
    const float* wk = (const float*)d_in[3];
    const float* bk = (const float*)d_in[4];
    const float* wv = (const float*)d_in[5];
    const float* bv = (const float*)d_in[6];
    const float* wo = (const float*)d_in[7];
    const float* bo = (const float*)d_in[8];
    float* out = (float*)d_out;

    size_t off = 0;
    char* base = (char*)d_ws;
    auto alloc = [&](size_t bytes) -> void* {
        void* p = base + off;
        off += (bytes + 255) & ~(size_t)255;
        return p;
    };
    const size_t MN = (size_t)B_ * N_;   // 4096
    ushort* QKV   = (ushort*)alloc(MN * QKVLD * 2);
    float*  Sb    = (float*) alloc((size_t)B_ * H_ * NCHUNK * F_ * G_ * 4);
    ushort* SbT   = (ushort*)alloc((size_t)B_ * H_ * NCHUNK * G_ * F_ * 2);
    float*  zb    = (float*) alloc((size_t)B_ * H_ * NCHUNK * F_ * 4);
    ushort* xbf   = (ushort*)alloc(MN * D_ * 2);
    ushort* wqkvT = (ushort*)alloc((size_t)QKVLD * D_ * 2);
    ushort* wot   = (ushort*)alloc((size_t)D_ * D_ * 2);
    float*  bqkv  = (float*) alloc((size_t)QKVLD * 4);
    ushort* obf   = (ushort*)alloc(MN * D_ * 2);

    const int M = (int)MN;   // 4096

    // one prep launch: convert + 4 transposes + bias pack
    prep_kernel<<<dim3(7176), 256, 0, stream>>>(
        x, wq, wk, wv, wo, bq, bk, bv, xbf, wqkvT, wot, bqkv);

    // fused QKV projection (phi on cols < 1024 = Q,K), bf16 out
    // grid (16,32) = 512 WGs (2/CU), XCD-swizzled
    mfma_gemm_kernel<true, 128><<<dim3(QKVLD / 128, M / 128), 256, 0, stream>>>(
        xbf, wqkvT, bqkv, QKV, M, D_, QKVLD, 2 * DHAT_);

    // chunked linear attention
    chunk_kv_kernel<<<dim3(NCHUNK, H_, B_), 256, 0, stream>>>(QKV, Sb, zb);
    scan_kernel<<<dim3(B_ * H_), 256, 0, stream>>>(Sb, SbT, zb);
    attn_mfma_kernel<<<dim3(NCHUNK, H_, B_), 256, 0, stream>>>(QKV, SbT, zb, obf);

    // output projection: BN=64 -> grid (16,32) = 512 WGs (2/CU vs 1/CU at BN=128)
    mfma_gemm_kernel<false, 64><<<dim3(D_ / 64, M / 128), 256, 0, stream>>>(
        obf, wot, bo, out, M, D_, D_, 0);
}

// Round 9
// 156.395 us; speedup vs baseline: 3.7323x; 1.0578x over previous
//
#include <hip/hip_runtime.h>
#include <hip/hip_bf16.h>
#include <math.h>

// Problem constants (from reference)
#define B_    2
#define N_    2048
#define D_    1024
#define DHAT_ 512
#define H_    16
#define F_    32      // qk head dim
#define G_    64      // v head dim
#define CHUNK 128
#define NCHUNK (N_ / CHUNK)   // 16
#define QKVLD 2048            // fused QKV row stride (Q 0..511 | K 512..1023 | V 1024..2047)

typedef __attribute__((ext_vector_type(8))) short bf16x8;
typedef __attribute__((ext_vector_type(4))) float f32x4;

__device__ __forceinline__ float phi_fn(float x) {
    return x > 0.0f ? x + 1.0f : expf(x);   // elu(x)+1
}

__device__ __forceinline__ ushort f2bf(float f) {
    unsigned u = __float_as_uint(f);
    u += 0x7FFFu + ((u >> 16) & 1u);
    return (ushort)(u >> 16);
}

__device__ __forceinline__ float bf2f(ushort u) {
    return __uint_as_float(((unsigned)u) << 16);
}

#define GLOAD_LDS16(g, l) __builtin_amdgcn_global_load_lds( \
    (const __attribute__((address_space(1))) void*)(g),     \
    (__attribute__((address_space(3))) void*)(l), 16, 0, 0)

// swizzle for 64B-row LDS tiles (rows of 32 bf16, 4 slots of 16B)
__device__ __forceinline__ int sw64(int row) { return (row & 3) ^ ((row >> 2) & 3); }
// swizzle for 256B-row tiles (rows of 128 bf16, 16 slots)
__device__ __forceinline__ int swP(int t) { return (t & 7) ^ (((t >> 3) & 1) << 1); }

// ---------------------------------------------------------------------------
// prep_kernel: ONE launch for  x->bf16 | 4 weight transposes | bias pack.
// ---------------------------------------------------------------------------
__device__ __forceinline__ void transpose_tile(
    const float* __restrict__ W, ushort* __restrict__ Wt,
    int K, int N, int bx, int by, int tid, ushort (*tile)[33])
{
    const int ti = by * 32, tj = bx * 32;
    const int tx = tid & 31, ty = tid >> 5;
    #pragma unroll
    for (int r = 0; r < 4; ++r)
        tile[ty + r * 8][tx] = f2bf(W[(size_t)(ti + ty + r * 8) * N + tj + tx]);
    __syncthreads();
    #pragma unroll
    for (int r = 0; r < 4; ++r)
        Wt[(size_t)(tj + ty + r * 8) * K + ti + tx] = tile[tx][ty + r * 8];
}

__global__ __launch_bounds__(256) void prep_kernel(
    const float* __restrict__ x,
    const float* __restrict__ wq, const float* __restrict__ wk,
    const float* __restrict__ wv, const float* __restrict__ wo,
    const float* __restrict__ bq, const float* __restrict__ bk,
    const float* __restrict__ bv,
    ushort* __restrict__ xbf, ushort* __restrict__ wqkvT,
    ushort* __restrict__ wot, float* __restrict__ bqkv)
{
    __shared__ ushort tile[32][33];
    const int id = blockIdx.x, tid = threadIdx.x;

    if (id < 4096) {
        int i = id * 256 + tid;
        float4 a = reinterpret_cast<const float4*>(x)[i];
        ushort4 o;
        o.x = f2bf(a.x); o.y = f2bf(a.y); o.z = f2bf(a.z); o.w = f2bf(a.w);
        reinterpret_cast<ushort4*>(xbf)[i] = o;
    } else if (id < 4608) {
        int tt = id - 4096;
        transpose_tile(wq, wqkvT, D_, DHAT_, tt & 15, tt >> 4, tid, tile);
    } else if (id < 5120) {
        int tt = id - 4608;
        transpose_tile(wk, wqkvT + (size_t)DHAT_ * D_, D_, DHAT_, tt & 15, tt >> 4, tid, tile);
    } else if (id < 6144) {
        int tt = id - 5120;
        transpose_tile(wv, wqkvT + (size_t)2 * DHAT_ * D_, D_, D_, tt & 31, tt >> 5, tid, tile);
    } else if (id < 7168) {
        int tt = id - 6144;
        transpose_tile(wo, wot, D_, D_, tt & 31, tt >> 5, tid, tile);
    } else {
        int i = (id - 7168) * 256 + tid;
        float v;
        if (i < DHAT_)          v = bq[i];
        else if (i < 2 * DHAT_) v = bk[i - DHAT_];
        else                    v = bv[i - 2 * DHAT_];
        bqkv[i] = v;
    }
}

// ---------------------------------------------------------------------------
// MFMA bf16 GEMM, BK=64 (16 K-iterations at K=1024) + T1 XCD swizzle.
// LDS rows are 128 B -> slot ^= (row&7) XOR swizzle, applied on the GLOBAL
// source address (global_load_lds writes linearly; both-sides rule) and on
// the ds_read slot index. MFMA order identical to BK=32 version (kk=0,1).
// BM=128, BN in {128,64}; 256 thr = 4 waves (2x2).
// ---------------------------------------------------------------------------
template<bool OUTBF, int BN>
__global__ __launch_bounds__(256) void mfma_gemm_kernel(
    const ushort* __restrict__ A, const ushort* __restrict__ Wt,
    const float* __restrict__ bias, void* __restrict__ Cout,
    int M, int K, int N, int phi_upto)
{
    constexpr int NF = BN / 32;               // n-frags per wave (128->4, 64->2)
    __shared__ __attribute__((aligned(16))) ushort Asm[128 * 64];   // 16 KB
    __shared__ __attribute__((aligned(16))) ushort Bsm[BN * 64];    // 16/8 KB

    const int tid  = threadIdx.x;
    const int lane = tid & 63;
    const int wave = tid >> 6;
    const int wr   = wave >> 1, wc = wave & 1;

    // T1: XCD-aware bijective remap (nwg % 8 == 0 for all our grids).
    const int nwg  = gridDim.x * gridDim.y;
    const int flat = blockIdx.y * gridDim.x + blockIdx.x;
    const int cpx  = nwg >> 3;
    const int swz  = (flat & 7) * cpx + (flat >> 3);
    const int bx   = swz % gridDim.x, by = swz / gridDim.x;

    const int brow = by * 128, bcol = bx * BN;
    const int l16  = lane & 15, lk = lane >> 4;

    f32x4 acc[4][NF];
    #pragma unroll
    for (int m = 0; m < 4; ++m)
        #pragma unroll
        for (int n = 0; n < NF; ++n)
            acc[m][n] = (f32x4){0.f, 0.f, 0.f, 0.f};

    for (int k0 = 0; k0 < K; k0 += 64) {
        __syncthreads();
        #pragma unroll
        for (int r = 0; r < 4; ++r) {         // A: 128 rows x 8 slots = 1024
            int fi  = r * 256 + tid;
            int row = fi >> 3, sl = fi & 7;
            GLOAD_LDS16(&A[(size_t)(brow + row) * K + k0 + ((sl ^ (row & 7)) << 3)],
                        &Asm[fi * 8]);
        }
        #pragma unroll
        for (int r = 0; r < BN / 32; ++r) {   // B: BN rows x 8 slots
            int fi  = r * 256 + tid;
            int row = fi >> 3, sl = fi & 7;
            GLOAD_LDS16(&Wt[(size_t)(bcol + row) * K + k0 + ((sl ^ (row & 7)) << 3)],
                        &Bsm[fi * 8]);
        }
        __syncthreads();

        #pragma unroll
        for (int kk = 0; kk < 2; ++kk) {
            bf16x8 af[4], bf[NF];
            #pragma unroll
            for (int m = 0; m < 4; ++m) {
                int row = wr * 64 + m * 16 + l16;
                af[m] = *reinterpret_cast<const bf16x8*>(
                    &Asm[row * 64 + (((kk * 4 + lk) ^ (row & 7)) << 3)]);
            }
            #pragma unroll
            for (int n = 0; n < NF; ++n) {
                int row = wc * (BN / 2) + n * 16 + l16;
                bf[n] = *reinterpret_cast<const bf16x8*>(
                    &Bsm[row * 64 + (((kk * 4 + lk) ^ (row & 7)) << 3)]);
            }
            #pragma unroll
            for (int m = 0; m < 4; ++m)
                #pragma unroll
                for (int n = 0; n < NF; ++n)
                    acc[m][n] = __builtin_amdgcn_mfma_f32_16x16x32_bf16(af[m], bf[n], acc[m][n], 0, 0, 0);
        }
    }

    // C/D layout: col=lane&15, row=(lane>>4)*4+j  [m89/m91 verified]
    #pragma unroll
    for (int n = 0; n < NF; ++n) {
        int col = bcol + wc * (BN / 2) + n * 16 + l16;
        float bv = bias[col];
        const bool do_phi = col < phi_upto;
        #pragma unroll
        for (int m = 0; m < 4; ++m) {
            int row0 = brow + wr * 64 + m * 16 + lk * 4;
            #pragma unroll
            for (int j = 0; j < 4; ++j) {
                float v = acc[m][n][j] + bv;
                if (do_phi) v = phi_fn(v);
                if (OUTBF)
                    ((ushort*)Cout)[(size_t)(row0 + j) * N + col] = f2bf(v);
                else
                    ((float*)Cout)[(size_t)(row0 + j) * N + col] = v;
            }
        }
    }
}

// ---------------------------------------------------------------------------
// Pass A (MFMA): S_c[f][g] = sum_t K[t][f]*V[t][g],  z_c[f] = sum_t K[t][f]
// ---------------------------------------------------------------------------
__global__ __launch_bounds__(256) void chunk_kv_kernel(
    const ushort* __restrict__ QKV, float* __restrict__ Sb, float* __restrict__ zb)
{
    __shared__ __attribute__((aligned(16))) ushort KsT[32 * 128];   //  8 KB [f][t]
    __shared__ __attribute__((aligned(16))) ushort VsT[64 * 128];   // 16 KB [g][t]

    const int c = blockIdx.x, h = blockIdx.y, b = blockIdx.z;
    const int tid = threadIdx.x;
    const int lane = tid & 63, wave = tid >> 6;
    const int l16 = lane & 15, lk = lane >> 4;
    const size_t row0 = (size_t)b * N_ + (size_t)c * CHUNK;

    // stage K^T [f][t]
    #pragma unroll
    for (int r = 0; r < 2; ++r) {
        int fi = r * 256 + tid;
        int t = fi >> 2, f8 = (fi & 3) << 3;
        bf16x8 v = *reinterpret_cast<const bf16x8*>(&QKV[(row0 + t) * QKVLD + DHAT_ + h * F_ + f8]);
        #pragma unroll
        for (int i = 0; i < 8; ++i) {
            int f = f8 + i;
            KsT[f * 128 + (t ^ ((f & 7) << 3))] = (ushort)v[i];
        }
    }
    // stage V^T [g][t]
    {
        int s = tid & 127, gh = tid >> 7;
        const ushort* vsrc = &QKV[(row0 + s) * QKVLD + 2 * DHAT_ + h * G_ + gh * 32];
        #pragma unroll
        for (int w = 0; w < 4; ++w) {
            bf16x8 v = *reinterpret_cast<const bf16x8*>(&vsrc[w * 8]);
            #pragma unroll
            for (int i = 0; i < 8; ++i) {
                int g = gh * 32 + w * 8 + i;
                VsT[g * 128 + (s ^ ((g & 7) << 3))] = (ushort)v[i];
            }
        }
    }
    __syncthreads();

    // wave w owns g-tile w, f-tiles 0..1
    f32x4 sacc[2];
    sacc[0] = (f32x4){0.f, 0.f, 0.f, 0.f};
    sacc[1] = (f32x4){0.f, 0.f, 0.f, 0.f};
    const int g = wave * 16 + l16;
    #pragma unroll
    for (int ks = 0; ks < 4; ++ks) {
        int sl = ks * 4 + lk;
        bf16x8 bv = *reinterpret_cast<const bf16x8*>(&VsT[g * 128 + ((sl ^ (g & 7)) << 3)]);
        #pragma unroll
        for (int m = 0; m < 2; ++m) {
            int f = m * 16 + l16;
            bf16x8 ak = *reinterpret_cast<const bf16x8*>(&KsT[f * 128 + ((sl ^ (f & 7)) << 3)]);
            sacc[m] = __builtin_amdgcn_mfma_f32_16x16x32_bf16(ak, bv, sacc[m], 0, 0, 0);
        }
    }

    const size_t sbase = ((size_t)((b * H_ + h) * NCHUNK + c)) * (F_ * G_);
    #pragma unroll
    for (int m = 0; m < 2; ++m)
        #pragma unroll
        for (int j = 0; j < 4; ++j) {
            int f = m * 16 + lk * 4 + j;
            Sb[sbase + (size_t)f * G_ + g] = sacc[m][j];
        }

    // z[f]
    {
        int f = tid >> 3, i = tid & 7;
        float zs = 0.0f;
        #pragma unroll
        for (int ss = 0; ss < 2; ++ss) {
            int sl = i * 2 + ss;
            bf16x8 kv = *reinterpret_cast<const bf16x8*>(&KsT[f * 128 + ((sl ^ (f & 7)) << 3)]);
            #pragma unroll
            for (int e = 0; e < 8; ++e) zs += bf2f((ushort)kv[e]);
        }
        zs += __shfl_xor(zs, 1);
        zs += __shfl_xor(zs, 2);
        zs += __shfl_xor(zs, 4);
        if (i == 0) zb[((size_t)(b * H_ + h) * NCHUNK + c) * F_ + f] = zs;
    }
}

// ---------------------------------------------------------------------------
// Pass C (MFMA, scan fused): each block sums its own S_prefix/z_prefix from
// the fp32 per-chunk states (L2-hot, <= 15 chunks), then
// P = tril(QK^T); den = rowsum(P)+q.z_prefix; out = (P@V + Q@S_prefix)/den.
// grid (NCHUNK,H,B), 4 waves. Rounding points identical to the scan version.
// ---------------------------------------------------------------------------
__global__ __launch_bounds__(256) void attn_mfma_kernel(
    const ushort* __restrict__ QKV, const float* __restrict__ Sb,
    const float* __restrict__ zb, ushort* __restrict__ Obf)
{
    __shared__ __attribute__((aligned(16))) ushort Qs[128 * 32];   //  8 KB [t][f]  sw64
    __shared__ __attribute__((aligned(16))) ushort Ks[128 * 32];   //  8 KB [s][f]  sw64
    __shared__ __attribute__((aligned(16))) ushort VsT[64 * 128];  // 16 KB [g][s]
    __shared__ __attribute__((aligned(16))) ushort Ss[64 * 32];    //  4 KB [g][f]  sw64
    __shared__ __attribute__((aligned(16))) ushort Ps[128 * 128];  // 32 KB [t][s]  swP
    __shared__ float zl[F_];
    __shared__ float denl[CHUNK];

    const int c = blockIdx.x, h = blockIdx.y, b = blockIdx.z;
    const int tid = threadIdx.x;
    const int lane = tid & 63, wave = tid >> 6;
    const int l16 = lane & 15, lk = lane >> 4;
    const size_t row0 = (size_t)b * N_ + (size_t)c * CHUNK;
    const int bh = b * H_ + h;

    // stage Q, K (source pre-swizzled -> linear LDS)
    #pragma unroll
    for (int r = 0; r < 2; ++r) {
        int fi = r * 256 + tid;
        int row = fi >> 2;
        int c8 = ((fi & 3) ^ sw64(row)) << 3;
        GLOAD_LDS16(&QKV[(row0 + row) * QKVLD + h * F_ + c8], &Qs[fi * 8]);
        GLOAD_LDS16(&QKV[(row0 + row) * QKVLD + DHAT_ + h * F_ + c8], &Ks[fi * 8]);
    }
    // S_prefix: sum fp32 chunk states cc < c, cvt bf16, write Ss [g][f] sw64
    {
        int g = tid >> 2, f0 = (tid & 3) << 3;
        float s[8] = {};
        for (int cc = 0; cc < c; ++cc) {
            const float* sp = &Sb[((size_t)bh * NCHUNK + cc) * (F_ * G_)];
            #pragma unroll
            for (int i = 0; i < 8; ++i) s[i] += sp[(size_t)(f0 + i) * G_ + g];
        }
        bf16x8 w;
        #pragma unroll
        for (int i = 0; i < 8; ++i) w[i] = (short)f2bf(s[i]);
        *reinterpret_cast<bf16x8*>(&Ss[g * 32 + ((((f0 >> 3)) ^ sw64(g)) << 3)]) = w;
    }
    // z_prefix
    if (tid < F_) {
        float pz = 0.0f;
        for (int cc = 0; cc < c; ++cc)
            pz += zb[((size_t)bh * NCHUNK + cc) * F_ + tid];
        zl[tid] = pz;
    }
    // stage V transposed [g][s]
    {
        int s = tid & 127, gh = tid >> 7;
        const ushort* vsrc = &QKV[(row0 + s) * QKVLD + 2 * DHAT_ + h * G_ + gh * 32];
        #pragma unroll
        for (int w = 0; w < 4; ++w) {
            bf16x8 v = *reinterpret_cast<const bf16x8*>(&vsrc[w * 8]);
            #pragma unroll
            for (int i = 0; i < 8; ++i) {
                int g = gh * 32 + w * 8 + i;
                VsT[g * 128 + (s ^ ((g & 7) << 3))] = (ushort)v[i];
            }
        }
    }
    __syncthreads();

    const int mbase = wave * 32;

    bf16x8 aq[2];
    #pragma unroll
    for (int m = 0; m < 2; ++m) {
        int row = mbase + m * 16 + l16;
        aq[m] = *reinterpret_cast<const bf16x8*>(&Qs[row * 32 + ((lk ^ sw64(row)) << 3)]);
    }

    // P = Q K^T (wave's 32 rows x 128 cols)
    f32x4 p[2][8];
    #pragma unroll
    for (int m = 0; m < 2; ++m)
        #pragma unroll
        for (int n = 0; n < 8; ++n)
            p[m][n] = (f32x4){0.f, 0.f, 0.f, 0.f};
    #pragma unroll
    for (int n = 0; n < 8; ++n) {
        int srow = n * 16 + l16;
        bf16x8 bk = *reinterpret_cast<const bf16x8*>(&Ks[srow * 32 + ((lk ^ sw64(srow)) << 3)]);
        p[0][n] = __builtin_amdgcn_mfma_f32_16x16x32_bf16(aq[0], bk, p[0][n], 0, 0, 0);
        p[1][n] = __builtin_amdgcn_mfma_f32_16x16x32_bf16(aq[1], bk, p[1][n], 0, 0, 0);
    }

    // causal mask + cvt + store Ps (swizzled)
    #pragma unroll
    for (int m = 0; m < 2; ++m)
        #pragma unroll
        for (int n = 0; n < 8; ++n) {
            int s = n * 16 + l16;
            #pragma unroll
            for (int j = 0; j < 4; ++j) {
                int t = mbase + m * 16 + lk * 4 + j;
                float v = (s <= t) ? p[m][n][j] : 0.0f;
                Ps[t * 128 + ((s & 7) | (((s >> 3) ^ swP(t)) << 3))] = f2bf(v);
            }
        }

    // den[t]
    {
        int t = tid >> 1, h2 = tid & 1;
        float rs = 0.0f;
        #pragma unroll
        for (int r = 0; r < 8; ++r) {
            int sl = h2 * 8 + r;
            bf16x8 pv = *reinterpret_cast<const bf16x8*>(&Ps[t * 128 + ((sl ^ swP(t)) << 3)]);
            #pragma unroll
            for (int i = 0; i < 8; ++i) rs += bf2f((ushort)pv[i]);
        }
        #pragma unroll
        for (int ss = 0; ss < 2; ++ss) {
            int sl = h2 * 2 + ss;
            bf16x8 qv = *reinterpret_cast<const bf16x8*>(&Qs[t * 32 + ((sl ^ sw64(t)) << 3)]);
            #pragma unroll
            for (int i = 0; i < 8; ++i) rs += bf2f((ushort)qv[i]) * zl[sl * 8 + i];
        }
        rs += __shfl_xor(rs, 1);
        if (h2 == 0) denl[t] = rs + 1e-6f;
    }

    // out = Q @ S_prefix + P @ V
    f32x4 o[2][4];
    #pragma unroll
    for (int m = 0; m < 2; ++m)
        #pragma unroll
        for (int n = 0; n < 4; ++n)
            o[m][n] = (f32x4){0.f, 0.f, 0.f, 0.f};
    #pragma unroll
    for (int n = 0; n < 4; ++n) {
        int g = n * 16 + l16;
        bf16x8 bs = *reinterpret_cast<const bf16x8*>(&Ss[g * 32 + ((lk ^ sw64(g)) << 3)]);
        o[0][n] = __builtin_amdgcn_mfma_f32_16x16x32_bf16(aq[0], bs, o[0][n], 0, 0, 0);
        o[1][n] = __builtin_amdgcn_mfma_f32_16x16x32_bf16(aq[1], bs, o[1][n], 0, 0, 0);
    }
    #pragma unroll
    for (int ks = 0; ks < 4; ++ks) {
        bf16x8 ap[2];
        #pragma unroll
        for (int m = 0; m < 2; ++m) {
            int t = mbase + m * 16 + l16;
            int sl = ks * 4 + lk;
            ap[m] = *reinterpret_cast<const bf16x8*>(&Ps[t * 128 + ((sl ^ swP(t)) << 3)]);
        }
        #pragma unroll
        for (int n = 0; n < 4; ++n) {
            int g = n * 16 + l16;
            bf16x8 bv = *reinterpret_cast<const bf16x8*>(&VsT[g * 128 + (((ks * 4 + lk) ^ (g & 7)) << 3)]);
            o[0][n] = __builtin_amdgcn_mfma_f32_16x16x32_bf16(ap[0], bv, o[0][n], 0, 0, 0);
            o[1][n] = __builtin_amdgcn_mfma_f32_16x16x32_bf16(ap[1], bv, o[1][n], 0, 0, 0);
        }
    }

    // epilogue
    #pragma unroll
    for (int m = 0; m < 2; ++m)
        #pragma unroll
        for (int j = 0; j < 4; ++j) {
            int t = mbase + m * 16 + lk * 4 + j;
            float rinv = 1.0f / denl[t];
            #pragma unroll
            for (int n = 0; n < 4; ++n) {
                int g = n * 16 + l16;
                Obf[(row0 + t) * D_ + h * G_ + g] = f2bf(o[m][n][j] * rinv);
            }
        }
}

// ---------------------------------------------------------------------------
extern "C" void kernel_launch(void* const* d_in, const int* in_sizes, int n_in,
                              void* d_out, int out_size, void* d_ws, size_t ws_size,
                              hipStream_t stream) {
    const float* x  = (const float*)d_in[0];
    const float* wq = (const float*)d_in[1];
    const float* bq = (const float*)d_in[2];
    const float* wk = (const float*)d_in[3];
    const float* bk = (const float*)d_in[4];
    const float* wv = (const float*)d_in[5];
    const float* bv = (const float*)d_in[6];
    const float* wo = (const float*)d_in[7];
    const float* bo = (const float*)d_in[8];
    float* out = (float*)d_out;

    size_t off = 0;
    char* base = (char*)d_ws;
    auto alloc = [&](size_t bytes) -> void* {
        void* p = base + off;
        off += (bytes + 255) & ~(size_t)255;
        return p;
    };
    const size_t MN = (size_t)B_ * N_;   // 4096
    ushort* QKV   = (ushort*)alloc(MN * QKVLD * 2);
    float*  Sb    = (float*) alloc((size_t)B_ * H_ * NCHUNK * F_ * G_ * 4);
    float*  zb    = (float*) alloc((size_t)B_ * H_ * NCHUNK * F_ * 4);
    ushort* xbf   = (ushort*)alloc(MN * D_ * 2);
    ushort* wqkvT = (ushort*)alloc((size_t)QKVLD * D_ * 2);
    ushort* wot   = (ushort*)alloc((size_t)D_ * D_ * 2);
    float*  bqkv  = (float*) alloc((size_t)QKVLD * 4);
    ushort* obf   = (ushort*)alloc(MN * D_ * 2);

    const int M = (int)MN;   // 4096

    // one prep launch: convert + 4 transposes + bias pack
    prep_kernel<<<dim3(7176), 256, 0, stream>>>(
        x, wq, wk, wv, wo, bq, bk, bv, xbf, wqkvT, wot, bqkv);

    // fused QKV projection (phi on cols < 1024 = Q,K), bf16 out, BK=64
    mfma_gemm_kernel<true, 128><<<dim3(QKVLD / 128, M / 128), 256, 0, stream>>>(
        xbf, wqkvT, bqkv, QKV, M, D_, QKVLD, 2 * DHAT_);

    // chunked linear attention (scan fused into attn)
    chunk_kv_kernel<<<dim3(NCHUNK, H_, B_), 256, 0, stream>>>(QKV, Sb, zb);
    attn_mfma_kernel<<<dim3(NCHUNK, H_, B_), 256, 0, stream>>>(QKV, Sb, zb, obf);

    // output projection: BN=64 -> 512 WGs (2/CU), BK=64
    mfma_gemm_kernel<false, 64><<<dim3(D_ / 64, M / 128), 256, 0, stream>>>(
        obf, wot, bo, out, M, D_, D_, 0);
}

// Round 10
// 156.102 us; speedup vs baseline: 3.7393x; 1.0019x over previous
//
#include <hip/hip_runtime.h>
#include <hip/hip_bf16.h>
#include <math.h>

// Problem constants (from reference)
#define B_    2
#define N_    2048
#define D_    1024
#define DHAT_ 512
#define H_    16
#define F_    32      // qk head dim
#define G_    64      // v head dim
#define CHUNK 128
#define NCHUNK (N_ / CHUNK)   // 16
#define QKVLD 2048            // fused QKV row stride (Q 0..511 | K 512..1023 | V 1024..2047)

typedef __attribute__((ext_vector_type(8))) short bf16x8;
typedef __attribute__((ext_vector_type(4))) float f32x4;

__device__ __forceinline__ float phi_fn(float x) {
    return x > 0.0f ? x + 1.0f : expf(x);   // elu(x)+1
}

__device__ __forceinline__ ushort f2bf(float f) {
    unsigned u = __float_as_uint(f);
    u += 0x7FFFu + ((u >> 16) & 1u);
    return (ushort)(u >> 16);
}

__device__ __forceinline__ float bf2f(ushort u) {
    return __uint_as_float(((unsigned)u) << 16);
}

#define GLOAD_LDS16(g, l) __builtin_amdgcn_global_load_lds( \
    (const __attribute__((address_space(1))) void*)(g),     \
    (__attribute__((address_space(3))) void*)(l), 16, 0, 0)

// swizzle for 64B-row LDS tiles (rows of 32 bf16, 4 slots of 16B)
__device__ __forceinline__ int sw64(int row) { return (row & 3) ^ ((row >> 2) & 3); }
// swizzle for 256B-row tiles (rows of 128 bf16, 16 slots)
__device__ __forceinline__ int swP(int t) { return (t & 7) ^ (((t >> 3) & 1) << 1); }

// ---------------------------------------------------------------------------
// prep_kernel: ONE launch for  x->bf16 | 4 weight transposes | bias pack.
// ---------------------------------------------------------------------------
__device__ __forceinline__ void transpose_tile(
    const float* __restrict__ W, ushort* __restrict__ Wt,
    int K, int N, int bx, int by, int tid, ushort (*tile)[33])
{
    const int ti = by * 32, tj = bx * 32;
    const int tx = tid & 31, ty = tid >> 5;
    #pragma unroll
    for (int r = 0; r < 4; ++r)
        tile[ty + r * 8][tx] = f2bf(W[(size_t)(ti + ty + r * 8) * N + tj + tx]);
    __syncthreads();
    #pragma unroll
    for (int r = 0; r < 4; ++r)
        Wt[(size_t)(tj + ty + r * 8) * K + ti + tx] = tile[tx][ty + r * 8];
}

__global__ __launch_bounds__(256) void prep_kernel(
    const float* __restrict__ x,
    const float* __restrict__ wq, const float* __restrict__ wk,
    const float* __restrict__ wv, const float* __restrict__ wo,
    const float* __restrict__ bq, const float* __restrict__ bk,
    const float* __restrict__ bv,
    ushort* __restrict__ xbf, ushort* __restrict__ wqkvT,
    ushort* __restrict__ wot, float* __restrict__ bqkv)
{
    __shared__ ushort tile[32][33];
    const int id = blockIdx.x, tid = threadIdx.x;

    if (id < 4096) {
        int i = id * 256 + tid;
        float4 a = reinterpret_cast<const float4*>(x)[i];
        ushort4 o;
        o.x = f2bf(a.x); o.y = f2bf(a.y); o.z = f2bf(a.z); o.w = f2bf(a.w);
        reinterpret_cast<ushort4*>(xbf)[i] = o;
    } else if (id < 4608) {
        int tt = id - 4096;
        transpose_tile(wq, wqkvT, D_, DHAT_, tt & 15, tt >> 4, tid, tile);
    } else if (id < 5120) {
        int tt = id - 4608;
        transpose_tile(wk, wqkvT + (size_t)DHAT_ * D_, D_, DHAT_, tt & 15, tt >> 4, tid, tile);
    } else if (id < 6144) {
        int tt = id - 5120;
        transpose_tile(wv, wqkvT + (size_t)2 * DHAT_ * D_, D_, D_, tt & 31, tt >> 5, tid, tile);
    } else if (id < 7168) {
        int tt = id - 6144;
        transpose_tile(wo, wot, D_, D_, tt & 31, tt >> 5, tid, tile);
    } else {
        int i = (id - 7168) * 256 + tid;
        float v;
        if (i < DHAT_)          v = bq[i];
        else if (i < 2 * DHAT_) v = bk[i - DHAT_];
        else                    v = bv[i - 2 * DHAT_];
        bqkv[i] = v;
    }
}

// ---------------------------------------------------------------------------
// MFMA bf16 GEMM, BK=64, DOUBLE-BUFFERED LDS, ONE barrier per K-step
// (T3 minimum-2-phase recipe: STAGE(next) issued BEFORE compute(cur), the
// barrier's implicit vmcnt(0) drain then overlaps with the MFMA phase).
// LDS rows 128 B -> slot ^= (row&7) swizzle, pre-swizzled global source
// (both-sides rule). MFMA order identical to round-8 (absmax-preserving).
// BM=128, BN in {128,64}; 256 thr = 4 waves (2x2). + T1 XCD swizzle.
// ---------------------------------------------------------------------------
template<bool OUTBF, int BN>
__global__ __launch_bounds__(256) void mfma_gemm_kernel(
    const ushort* __restrict__ A, const ushort* __restrict__ Wt,
    const float* __restrict__ bias, void* __restrict__ Cout,
    int M, int K, int N, int phi_upto)
{
    constexpr int NF = BN / 32;               // n-frags per wave (128->4, 64->2)
    __shared__ __attribute__((aligned(16))) ushort Asm[2][128 * 64];  // 2x16 KB
    __shared__ __attribute__((aligned(16))) ushort Bsm[2][BN * 64];   // 2x16/8 KB

    const int tid  = threadIdx.x;
    const int lane = tid & 63;
    const int wave = tid >> 6;
    const int wr   = wave >> 1, wc = wave & 1;

    // T1: XCD-aware bijective remap (nwg % 8 == 0 for all our grids).
    const int nwg  = gridDim.x * gridDim.y;
    const int flat = blockIdx.y * gridDim.x + blockIdx.x;
    const int cpx  = nwg >> 3;
    const int swz  = (flat & 7) * cpx + (flat >> 3);
    const int bx   = swz % gridDim.x, by = swz / gridDim.x;

    const int brow = by * 128, bcol = bx * BN;
    const int l16  = lane & 15, lk = lane >> 4;

    auto stage = [&](int buf, int k0) {
        #pragma unroll
        for (int r = 0; r < 4; ++r) {         // A: 128 rows x 8 slots = 1024
            int fi  = r * 256 + tid;
            int row = fi >> 3, sl = fi & 7;
            GLOAD_LDS16(&A[(size_t)(brow + row) * K + k0 + ((sl ^ (row & 7)) << 3)],
                        &Asm[buf][fi * 8]);
        }
        #pragma unroll
        for (int r = 0; r < BN / 32; ++r) {   // B: BN rows x 8 slots
            int fi  = r * 256 + tid;
            int row = fi >> 3, sl = fi & 7;
            GLOAD_LDS16(&Wt[(size_t)(bcol + row) * K + k0 + ((sl ^ (row & 7)) << 3)],
                        &Bsm[buf][fi * 8]);
        }
    };

    f32x4 acc[4][NF];
    #pragma unroll
    for (int m = 0; m < 4; ++m)
        #pragma unroll
        for (int n = 0; n < NF; ++n)
            acc[m][n] = (f32x4){0.f, 0.f, 0.f, 0.f};

    stage(0, 0);
    __syncthreads();          // implicit vmcnt(0): buf0 ready

    int cur = 0;
    for (int k0 = 0; k0 < K; k0 += 64) {
        if (k0 + 64 < K) stage(cur ^ 1, k0 + 64);   // issue next-tile loads FIRST

        #pragma unroll
        for (int kk = 0; kk < 2; ++kk) {
            bf16x8 af[4], bf[NF];
            #pragma unroll
            for (int m = 0; m < 4; ++m) {
                int row = wr * 64 + m * 16 + l16;
                af[m] = *reinterpret_cast<const bf16x8*>(
                    &Asm[cur][row * 64 + (((kk * 4 + lk) ^ (row & 7)) << 3)]);
            }
            #pragma unroll
            for (int n = 0; n < NF; ++n) {
                int row = wc * (BN / 2) + n * 16 + l16;
                bf[n] = *reinterpret_cast<const bf16x8*>(
                    &Bsm[cur][row * 64 + (((kk * 4 + lk) ^ (row & 7)) << 3)]);
            }
            #pragma unroll
            for (int m = 0; m < 4; ++m)
                #pragma unroll
                for (int n = 0; n < NF; ++n)
                    acc[m][n] = __builtin_amdgcn_mfma_f32_16x16x32_bf16(af[m], bf[n], acc[m][n], 0, 0, 0);
        }

        __syncthreads();      // ONE barrier/K-step: drains next-tile loads
        cur ^= 1;             // (issued pre-compute -> latency hidden) + read-done
    }

    // C/D layout: col=lane&15, row=(lane>>4)*4+j  [m89/m91 verified]
    #pragma unroll
    for (int n = 0; n < NF; ++n) {
        int col = bcol + wc * (BN / 2) + n * 16 + l16;
        float bv = bias[col];
        const bool do_phi = col < phi_upto;
        #pragma unroll
        for (int m = 0; m < 4; ++m) {
            int row0 = brow + wr * 64 + m * 16 + lk * 4;
            #pragma unroll
            for (int j = 0; j < 4; ++j) {
                float v = acc[m][n][j] + bv;
                if (do_phi) v = phi_fn(v);
                if (OUTBF)
                    ((ushort*)Cout)[(size_t)(row0 + j) * N + col] = f2bf(v);
                else
                    ((float*)Cout)[(size_t)(row0 + j) * N + col] = v;
            }
        }
    }
}

// ---------------------------------------------------------------------------
// Pass A (MFMA): S_c[f][g] = sum_t K[t][f]*V[t][g],  z_c[f] = sum_t K[t][f]
// ---------------------------------------------------------------------------
__global__ __launch_bounds__(256) void chunk_kv_kernel(
    const ushort* __restrict__ QKV, float* __restrict__ Sb, float* __restrict__ zb)
{
    __shared__ __attribute__((aligned(16))) ushort KsT[32 * 128];   //  8 KB [f][t]
    __shared__ __attribute__((aligned(16))) ushort VsT[64 * 128];   // 16 KB [g][t]

    const int c = blockIdx.x, h = blockIdx.y, b = blockIdx.z;
    const int tid = threadIdx.x;
    const int lane = tid & 63, wave = tid >> 6;
    const int l16 = lane & 15, lk = lane >> 4;
    const size_t row0 = (size_t)b * N_ + (size_t)c * CHUNK;

    // stage K^T [f][t]
    #pragma unroll
    for (int r = 0; r < 2; ++r) {
        int fi = r * 256 + tid;
        int t = fi >> 2, f8 = (fi & 3) << 3;
        bf16x8 v = *reinterpret_cast<const bf16x8*>(&QKV[(row0 + t) * QKVLD + DHAT_ + h * F_ + f8]);
        #pragma unroll
        for (int i = 0; i < 8; ++i) {
            int f = f8 + i;
            KsT[f * 128 + (t ^ ((f & 7) << 3))] = (ushort)v[i];
        }
    }
    // stage V^T [g][t]
    {
        int s = tid & 127, gh = tid >> 7;
        const ushort* vsrc = &QKV[(row0 + s) * QKVLD + 2 * DHAT_ + h * G_ + gh * 32];
        #pragma unroll
        for (int w = 0; w < 4; ++w) {
            bf16x8 v = *reinterpret_cast<const bf16x8*>(&vsrc[w * 8]);
            #pragma unroll
            for (int i = 0; i < 8; ++i) {
                int g = gh * 32 + w * 8 + i;
                VsT[g * 128 + (s ^ ((g & 7) << 3))] = (ushort)v[i];
            }
        }
    }
    __syncthreads();

    // wave w owns g-tile w, f-tiles 0..1
    f32x4 sacc[2];
    sacc[0] = (f32x4){0.f, 0.f, 0.f, 0.f};
    sacc[1] = (f32x4){0.f, 0.f, 0.f, 0.f};
    const int g = wave * 16 + l16;
    #pragma unroll
    for (int ks = 0; ks < 4; ++ks) {
        int sl = ks * 4 + lk;
        bf16x8 bv = *reinterpret_cast<const bf16x8*>(&VsT[g * 128 + ((sl ^ (g & 7)) << 3)]);
        #pragma unroll
        for (int m = 0; m < 2; ++m) {
            int f = m * 16 + l16;
            bf16x8 ak = *reinterpret_cast<const bf16x8*>(&KsT[f * 128 + ((sl ^ (f & 7)) << 3)]);
            sacc[m] = __builtin_amdgcn_mfma_f32_16x16x32_bf16(ak, bv, sacc[m], 0, 0, 0);
        }
    }

    const size_t sbase = ((size_t)((b * H_ + h) * NCHUNK + c)) * (F_ * G_);
    #pragma unroll
    for (int m = 0; m < 2; ++m)
        #pragma unroll
        for (int j = 0; j < 4; ++j) {
            int f = m * 16 + lk * 4 + j;
            Sb[sbase + (size_t)f * G_ + g] = sacc[m][j];
        }

    // z[f]
    {
        int f = tid >> 3, i = tid & 7;
        float zs = 0.0f;
        #pragma unroll
        for (int ss = 0; ss < 2; ++ss) {
            int sl = i * 2 + ss;
            bf16x8 kv = *reinterpret_cast<const bf16x8*>(&KsT[f * 128 + ((sl ^ (f & 7)) << 3)]);
            #pragma unroll
            for (int e = 0; e < 8; ++e) zs += bf2f((ushort)kv[e]);
        }
        zs += __shfl_xor(zs, 1);
        zs += __shfl_xor(zs, 2);
        zs += __shfl_xor(zs, 4);
        if (i == 0) zb[((size_t)(b * H_ + h) * NCHUNK + c) * F_ + f] = zs;
    }
}

// ---------------------------------------------------------------------------
// Pass C (MFMA, scan fused): block sums its own S_prefix/z_prefix (L2-hot),
// then P = tril(QK^T); den = rowsum(P)+q.z_prefix; out = (P@V+Q@S)/den.
// ---------------------------------------------------------------------------
__global__ __launch_bounds__(256) void attn_mfma_kernel(
    const ushort* __restrict__ QKV, const float* __restrict__ Sb,
    const float* __restrict__ zb, ushort* __restrict__ Obf)
{
    __shared__ __attribute__((aligned(16))) ushort Qs[128 * 32];   //  8 KB [t][f]  sw64
    __shared__ __attribute__((aligned(16))) ushort Ks[128 * 32];   //  8 KB [s][f]  sw64
    __shared__ __attribute__((aligned(16))) ushort VsT[64 * 128];  // 16 KB [g][s]
    __shared__ __attribute__((aligned(16))) ushort Ss[64 * 32];    //  4 KB [g][f]  sw64
    __shared__ __attribute__((aligned(16))) ushort Ps[128 * 128];  // 32 KB [t][s]  swP
    __shared__ float zl[F_];
    __shared__ float denl[CHUNK];

    const int c = blockIdx.x, h = blockIdx.y, b = blockIdx.z;
    const int tid = threadIdx.x;
    const int lane = tid & 63, wave = tid >> 6;
    const int l16 = lane & 15, lk = lane >> 4;
    const size_t row0 = (size_t)b * N_ + (size_t)c * CHUNK;
    const int bh = b * H_ + h;

    // stage Q, K (source pre-swizzled -> linear LDS)
    #pragma unroll
    for (int r = 0; r < 2; ++r) {
        int fi = r * 256 + tid;
        int row = fi >> 2;
        int c8 = ((fi & 3) ^ sw64(row)) << 3;
        GLOAD_LDS16(&QKV[(row0 + row) * QKVLD + h * F_ + c8], &Qs[fi * 8]);
        GLOAD_LDS16(&QKV[(row0 + row) * QKVLD + DHAT_ + h * F_ + c8], &Ks[fi * 8]);
    }
    // S_prefix: sum fp32 chunk states cc < c, cvt bf16, write Ss [g][f] sw64
    {
        int g = tid >> 2, f0 = (tid & 3) << 3;
        float s[8] = {};
        for (int cc = 0; cc < c; ++cc) {
            const float* sp = &Sb[((size_t)bh * NCHUNK + cc) * (F_ * G_)];
            #pragma unroll
            for (int i = 0; i < 8; ++i) s[i] += sp[(size_t)(f0 + i) * G_ + g];
        }
        bf16x8 w;
        #pragma unroll
        for (int i = 0; i < 8; ++i) w[i] = (short)f2bf(s[i]);
        *reinterpret_cast<bf16x8*>(&Ss[g * 32 + ((((f0 >> 3)) ^ sw64(g)) << 3)]) = w;
    }
    // z_prefix
    if (tid < F_) {
        float pz = 0.0f;
        for (int cc = 0; cc < c; ++cc)
            pz += zb[((size_t)bh * NCHUNK + cc) * F_ + tid];
        zl[tid] = pz;
    }
    // stage V transposed [g][s]
    {
        int s = tid & 127, gh = tid >> 7;
        const ushort* vsrc = &QKV[(row0 + s) * QKVLD + 2 * DHAT_ + h * G_ + gh * 32];
        #pragma unroll
        for (int w = 0; w < 4; ++w) {
            bf16x8 v = *reinterpret_cast<const bf16x8*>(&vsrc[w * 8]);
            #pragma unroll
            for (int i = 0; i < 8; ++i) {
                int g = gh * 32 + w * 8 + i;
                VsT[g * 128 + (s ^ ((g & 7) << 3))] = (ushort)v[i];
            }
        }
    }
    __syncthreads();

    const int mbase = wave * 32;

    bf16x8 aq[2];
    #pragma unroll
    for (int m = 0; m < 2; ++m) {
        int row = mbase + m * 16 + l16;
        aq[m] = *reinterpret_cast<const bf16x8*>(&Qs[row * 32 + ((lk ^ sw64(row)) << 3)]);
    }

    // P = Q K^T (wave's 32 rows x 128 cols)
    f32x4 p[2][8];
    #pragma unroll
    for (int m = 0; m < 2; ++m)
        #pragma unroll
        for (int n = 0; n < 8; ++n)
            p[m][n] = (f32x4){0.f, 0.f, 0.f, 0.f};
    #pragma unroll
    for (int n = 0; n < 8; ++n) {
        int srow = n * 16 + l16;
        bf16x8 bk = *reinterpret_cast<const bf16x8*>(&Ks[srow * 32 + ((lk ^ sw64(srow)) << 3)]);
        p[0][n] = __builtin_amdgcn_mfma_f32_16x16x32_bf16(aq[0], bk, p[0][n], 0, 0, 0);
        p[1][n] = __builtin_amdgcn_mfma_f32_16x16x32_bf16(aq[1], bk, p[1][n], 0, 0, 0);
    }

    // causal mask + cvt + store Ps (swizzled)
    #pragma unroll
    for (int m = 0; m < 2; ++m)
        #pragma unroll
        for (int n = 0; n < 8; ++n) {
            int s = n * 16 + l16;
            #pragma unroll
            for (int j = 0; j < 4; ++j) {
                int t = mbase + m * 16 + lk * 4 + j;
                float v = (s <= t) ? p[m][n][j] : 0.0f;
                Ps[t * 128 + ((s & 7) | (((s >> 3) ^ swP(t)) << 3))] = f2bf(v);
            }
        }

    // den[t]
    {
        int t = tid >> 1, h2 = tid & 1;
        float rs = 0.0f;
        #pragma unroll
        for (int r = 0; r < 8; ++r) {
            int sl = h2 * 8 + r;
            bf16x8 pv = *reinterpret_cast<const bf16x8*>(&Ps[t * 128 + ((sl ^ swP(t)) << 3)]);
            #pragma unroll
            for (int i = 0; i < 8; ++i) rs += bf2f((ushort)pv[i]);
        }
        #pragma unroll
        for (int ss = 0; ss < 2; ++ss) {
            int sl = h2 * 2 + ss;
            bf16x8 qv = *reinterpret_cast<const bf16x8*>(&Qs[t * 32 + ((sl ^ sw64(t)) << 3)]);
            #pragma unroll
            for (int i = 0; i < 8; ++i) rs += bf2f((ushort)qv[i]) * zl[sl * 8 + i];
        }
        rs += __shfl_xor(rs, 1);
        if (h2 == 0) denl[t] = rs + 1e-6f;
    }

    // out = Q @ S_prefix + P @ V
    f32x4 o[2][4];
    #pragma unroll
    for (int m = 0; m < 2; ++m)
        #pragma unroll
        for (int n = 0; n < 4; ++n)
            o[m][n] = (f32x4){0.f, 0.f, 0.f, 0.f};
    #pragma unroll
    for (int n = 0; n < 4; ++n) {
        int g = n * 16 + l16;
        bf16x8 bs = *reinterpret_cast<const bf16x8*>(&Ss[g * 32 + ((lk ^ sw64(g)) << 3)]);
        o[0][n] = __builtin_amdgcn_mfma_f32_16x16x32_bf16(aq[0], bs, o[0][n], 0, 0, 0);
        o[1][n] = __builtin_amdgcn_mfma_f32_16x16x32_bf16(aq[1], bs, o[1][n], 0, 0, 0);
    }
    #pragma unroll
    for (int ks = 0; ks < 4; ++ks) {
        bf16x8 ap[2];
        #pragma unroll
        for (int m = 0; m < 2; ++m) {
            int t = mbase + m * 16 + l16;
            int sl = ks * 4 + lk;
            ap[m] = *reinterpret_cast<const bf16x8*>(&Ps[t * 128 + ((sl ^ swP(t)) << 3)]);
        }
        #pragma unroll
        for (int n = 0; n < 4; ++n) {
            int g = n * 16 + l16;
            bf16x8 bv = *reinterpret_cast<const bf16x8*>(&VsT[g * 128 + (((ks * 4 + lk) ^ (g & 7)) << 3)]);
            o[0][n] = __builtin_amdgcn_mfma_f32_16x16x32_bf16(ap[0], bv, o[0][n], 0, 0, 0);
            o[1][n] = __builtin_amdgcn_mfma_f32_16x16x32_bf16(ap[1], bv, o[1][n], 0, 0, 0);
        }
    }

    // epilogue
    #pragma unroll
    for (int m = 0; m < 2; ++m)
        #pragma unroll
        for (int j = 0; j < 4; ++j) {
            int t = mbase + m * 16 + lk * 4 + j;
            float rinv = 1.0f / denl[t];
            #pragma unroll
            for (int n = 0; n < 4; ++n) {
                int g = n * 16 + l16;
                Obf[(row0 + t) * D_ + h * G_ + g] = f2bf(o[m][n][j] * rinv);
            }
        }
}

// ---------------------------------------------------------------------------
extern "C" void kernel_launch(void* const* d_in, const int* in_sizes, int n_in,
                              void* d_out, int out_size, void* d_ws, size_t ws_size,
                              hipStream_t stream) {
    const float* x  = (const float*)d_in[0];
    const float* wq = (const float*)d_in[1];
    const float* bq = (const float*)d_in[2];
    const float* wk = (const float*)d_in[3];
    const float* bk = (const float*)d_in[4];
    const float* wv = (const float*)d_in[5];
    const float* bv = (const float*)d_in[6];
    const float* wo = (const float*)d_in[7];
    const float* bo = (const float*)d_in[8];
    float* out = (float*)d_out;

    size_t off = 0;
    char* base = (char*)d_ws;
    auto alloc = [&](size_t bytes) -> void* {
        void* p = base + off;
        off += (bytes + 255) & ~(size_t)255;
        return p;
    };
    const size_t MN = (size_t)B_ * N_;   // 4096
    ushort* QKV   = (ushort*)alloc(MN * QKVLD * 2);
    float*  Sb    = (float*) alloc((size_t)B_ * H_ * NCHUNK * F_ * G_ * 4);
    float*  zb    = (float*) alloc((size_t)B_ * H_ * NCHUNK * F_ * 4);
    ushort* xbf   = (ushort*)alloc(MN * D_ * 2);
    ushort* wqkvT = (ushort*)alloc((size_t)QKVLD * D_ * 2);
    ushort* wot   = (ushort*)alloc((size_t)D_ * D_ * 2);
    float*  bqkv  = (float*) alloc((size_t)QKVLD * 4);
    ushort* obf   = (ushort*)alloc(MN * D_ * 2);

    const int M = (int)MN;   // 4096

    // one prep launch: convert + 4 transposes + bias pack
    prep_kernel<<<dim3(7176), 256, 0, stream>>>(
        x, wq, wk, wv, wo, bq, bk, bv, xbf, wqkvT, wot, bqkv);

    // fused QKV projection (phi on cols < 1024 = Q,K), bf16 out, BK=64 dbuf
    mfma_gemm_kernel<true, 128><<<dim3(QKVLD / 128, M / 128), 256, 0, stream>>>(
        xbf, wqkvT, bqkv, QKV, M, D_, QKVLD, 2 * DHAT_);

    // chunked linear attention (scan fused into attn)
    chunk_kv_kernel<<<dim3(NCHUNK, H_, B_), 256, 0, stream>>>(QKV, Sb, zb);
    attn_mfma_kernel<<<dim3(NCHUNK, H_, B_), 256, 0, stream>>>(QKV, Sb, zb, obf);

    // output projection: BN=64 -> 512 WGs (2/CU), BK=64 dbuf
    mfma_gemm_kernel<false, 64><<<dim3(D_ / 64, M / 128), 256, 0, stream>>>(
        obf, wot, bo, out, M, D_, D_, 0);
}

// Round 11
// 153.416 us; speedup vs baseline: 3.8048x; 1.0175x over previous
//
#include <hip/hip_runtime.h>
#include <hip/hip_bf16.h>
#include <math.h>

// Problem constants (from reference)
#define B_    2
#define N_    2048
#define D_    1024
#define DHAT_ 512
#define H_    16
#define F_    32      // qk head dim
#define G_    64      // v head dim
#define CHUNK 128
#define NCHUNK (N_ / CHUNK)   // 16
#define QKVLD 2048            // fused QKV row stride (Q 0..511 | K 512..1023 | V 1024..2047)

typedef __attribute__((ext_vector_type(8))) short bf16x8;
typedef __attribute__((ext_vector_type(4))) float f32x4;

__device__ __forceinline__ float phi_fn(float x) {
    return x > 0.0f ? x + 1.0f : expf(x);   // elu(x)+1
}

__device__ __forceinline__ ushort f2bf(float f) {
    unsigned u = __float_as_uint(f);
    u += 0x7FFFu + ((u >> 16) & 1u);
    return (ushort)(u >> 16);
}

__device__ __forceinline__ float bf2f(ushort u) {
    return __uint_as_float(((unsigned)u) << 16);
}

#define GLOAD_LDS16(g, l) __builtin_amdgcn_global_load_lds( \
    (const __attribute__((address_space(1))) void*)(g),     \
    (__attribute__((address_space(3))) void*)(l), 16, 0, 0)

// swizzle for 64B-row LDS tiles (rows of 32 bf16, 4 slots of 16B)
__device__ __forceinline__ int sw64(int row) { return (row & 3) ^ ((row >> 2) & 3); }
// swizzle for 256B-row tiles (rows of 128 bf16, 16 slots)
__device__ __forceinline__ int swP(int t) { return (t & 7) ^ (((t >> 3) & 1) << 1); }

// ---------------------------------------------------------------------------
// prep_kernel: ONE launch for  x->bf16 | 4 weight transposes | bias pack.
// ---------------------------------------------------------------------------
__device__ __forceinline__ void transpose_tile(
    const float* __restrict__ W, ushort* __restrict__ Wt,
    int K, int N, int bx, int by, int tid, ushort (*tile)[33])
{
    const int ti = by * 32, tj = bx * 32;
    const int tx = tid & 31, ty = tid >> 5;
    #pragma unroll
    for (int r = 0; r < 4; ++r)
        tile[ty + r * 8][tx] = f2bf(W[(size_t)(ti + ty + r * 8) * N + tj + tx]);
    __syncthreads();
    #pragma unroll
    for (int r = 0; r < 4; ++r)
        Wt[(size_t)(tj + ty + r * 8) * K + ti + tx] = tile[tx][ty + r * 8];
}

__global__ __launch_bounds__(256) void prep_kernel(
    const float* __restrict__ x,
    const float* __restrict__ wq, const float* __restrict__ wk,
    const float* __restrict__ wv, const float* __restrict__ wo,
    const float* __restrict__ bq, const float* __restrict__ bk,
    const float* __restrict__ bv,
    ushort* __restrict__ xbf, ushort* __restrict__ wqkvT,
    ushort* __restrict__ wot, float* __restrict__ bqkv)
{
    __shared__ ushort tile[32][33];
    const int id = blockIdx.x, tid = threadIdx.x;

    if (id < 4096) {
        int i = id * 256 + tid;
        float4 a = reinterpret_cast<const float4*>(x)[i];
        ushort4 o;
        o.x = f2bf(a.x); o.y = f2bf(a.y); o.z = f2bf(a.z); o.w = f2bf(a.w);
        reinterpret_cast<ushort4*>(xbf)[i] = o;
    } else if (id < 4608) {
        int tt = id - 4096;
        transpose_tile(wq, wqkvT, D_, DHAT_, tt & 15, tt >> 4, tid, tile);
    } else if (id < 5120) {
        int tt = id - 4608;
        transpose_tile(wk, wqkvT + (size_t)DHAT_ * D_, D_, DHAT_, tt & 15, tt >> 4, tid, tile);
    } else if (id < 6144) {
        int tt = id - 5120;
        transpose_tile(wv, wqkvT + (size_t)2 * DHAT_ * D_, D_, D_, tt & 31, tt >> 5, tid, tile);
    } else if (id < 7168) {
        int tt = id - 6144;
        transpose_tile(wo, wot, D_, D_, tt & 31, tt >> 5, tid, tile);
    } else {
        int i = (id - 7168) * 256 + tid;
        float v;
        if (i < DHAT_)          v = bq[i];
        else if (i < 2 * DHAT_) v = bk[i - DHAT_];
        else                    v = bv[i - 2 * DHAT_];
        bqkv[i] = v;
    }
}

// ---------------------------------------------------------------------------
// MFMA bf16 GEMM, BM=64, BK=64, single-buffer 2-barrier loop.
// BM=64 -> 1024-WG grids -> 4 blocks/CU = 4 waves/SIMD (vs 2 at BM=128):
// wave-level overlap (m114) is the latency-hiding mechanism; dbuf was null.
// LDS rows 128 B -> slot ^= (row&7) swizzle, pre-swizzled global source.
// 4 waves (2x2): wave tile 32 x BN/2. + T1 XCD swizzle. phi on col<phi_upto.
// ---------------------------------------------------------------------------
template<bool OUTBF, int BN>
__global__ __launch_bounds__(256) void mfma_gemm_kernel(
    const ushort* __restrict__ A, const ushort* __restrict__ Wt,
    const float* __restrict__ bias, void* __restrict__ Cout,
    int M, int K, int N, int phi_upto)
{
    constexpr int NF = BN / 32;               // n-frags per wave (128->4, 64->2)
    __shared__ __attribute__((aligned(16))) ushort Asm[64 * 64];    //  8 KB
    __shared__ __attribute__((aligned(16))) ushort Bsm[BN * 64];    // 16/8 KB

    const int tid  = threadIdx.x;
    const int lane = tid & 63;
    const int wave = tid >> 6;
    const int wr   = wave >> 1, wc = wave & 1;

    // T1: XCD-aware bijective remap (nwg % 8 == 0 for all our grids).
    const int nwg  = gridDim.x * gridDim.y;
    const int flat = blockIdx.y * gridDim.x + blockIdx.x;
    const int cpx  = nwg >> 3;
    const int swz  = (flat & 7) * cpx + (flat >> 3);
    const int bx   = swz % gridDim.x, by = swz / gridDim.x;

    const int brow = by * 64, bcol = bx * BN;
    const int l16  = lane & 15, lk = lane >> 4;

    f32x4 acc[2][NF];
    #pragma unroll
    for (int m = 0; m < 2; ++m)
        #pragma unroll
        for (int n = 0; n < NF; ++n)
            acc[m][n] = (f32x4){0.f, 0.f, 0.f, 0.f};

    for (int k0 = 0; k0 < K; k0 += 64) {
        __syncthreads();
        #pragma unroll
        for (int r = 0; r < 2; ++r) {         // A: 64 rows x 8 slots = 512
            int fi  = r * 256 + tid;
            int row = fi >> 3, sl = fi & 7;
            GLOAD_LDS16(&A[(size_t)(brow + row) * K + k0 + ((sl ^ (row & 7)) << 3)],
                        &Asm[fi * 8]);
        }
        #pragma unroll
        for (int r = 0; r < BN / 32; ++r) {   // B: BN rows x 8 slots
            int fi  = r * 256 + tid;
            int row = fi >> 3, sl = fi & 7;
            GLOAD_LDS16(&Wt[(size_t)(bcol + row) * K + k0 + ((sl ^ (row & 7)) << 3)],
                        &Bsm[fi * 8]);
        }
        __syncthreads();

        #pragma unroll
        for (int kk = 0; kk < 2; ++kk) {
            bf16x8 af[2], bf[NF];
            #pragma unroll
            for (int m = 0; m < 2; ++m) {
                int row = wr * 32 + m * 16 + l16;
                af[m] = *reinterpret_cast<const bf16x8*>(
                    &Asm[row * 64 + (((kk * 4 + lk) ^ (row & 7)) << 3)]);
            }
            #pragma unroll
            for (int n = 0; n < NF; ++n) {
                int row = wc * (BN / 2) + n * 16 + l16;
                bf[n] = *reinterpret_cast<const bf16x8*>(
                    &Bsm[row * 64 + (((kk * 4 + lk) ^ (row & 7)) << 3)]);
            }
            #pragma unroll
            for (int m = 0; m < 2; ++m)
                #pragma unroll
                for (int n = 0; n < NF; ++n)
                    acc[m][n] = __builtin_amdgcn_mfma_f32_16x16x32_bf16(af[m], bf[n], acc[m][n], 0, 0, 0);
        }
    }

    // C/D layout: col=lane&15, row=(lane>>4)*4+j  [m89/m91 verified]
    #pragma unroll
    for (int n = 0; n < NF; ++n) {
        int col = bcol + wc * (BN / 2) + n * 16 + l16;
        float bv = bias[col];
        const bool do_phi = col < phi_upto;
        #pragma unroll
        for (int m = 0; m < 2; ++m) {
            int row0 = brow + wr * 32 + m * 16 + lk * 4;
            #pragma unroll
            for (int j = 0; j < 4; ++j) {
                float v = acc[m][n][j] + bv;
                if (do_phi) v = phi_fn(v);
                if (OUTBF)
                    ((ushort*)Cout)[(size_t)(row0 + j) * N + col] = f2bf(v);
                else
                    ((float*)Cout)[(size_t)(row0 + j) * N + col] = v;
            }
        }
    }
}

// ---------------------------------------------------------------------------
// Pass A (MFMA): S_c[f][g] = sum_t K[t][f]*V[t][g],  z_c[f] = sum_t K[t][f]
// ---------------------------------------------------------------------------
__global__ __launch_bounds__(256) void chunk_kv_kernel(
    const ushort* __restrict__ QKV, float* __restrict__ Sb, float* __restrict__ zb)
{
    __shared__ __attribute__((aligned(16))) ushort KsT[32 * 128];   //  8 KB [f][t]
    __shared__ __attribute__((aligned(16))) ushort VsT[64 * 128];   // 16 KB [g][t]

    const int c = blockIdx.x, h = blockIdx.y, b = blockIdx.z;
    const int tid = threadIdx.x;
    const int lane = tid & 63, wave = tid >> 6;
    const int l16 = lane & 15, lk = lane >> 4;
    const size_t row0 = (size_t)b * N_ + (size_t)c * CHUNK;

    // stage K^T [f][t]
    #pragma unroll
    for (int r = 0; r < 2; ++r) {
        int fi = r * 256 + tid;
        int t = fi >> 2, f8 = (fi & 3) << 3;
        bf16x8 v = *reinterpret_cast<const bf16x8*>(&QKV[(row0 + t) * QKVLD + DHAT_ + h * F_ + f8]);
        #pragma unroll
        for (int i = 0; i < 8; ++i) {
            int f = f8 + i;
            KsT[f * 128 + (t ^ ((f & 7) << 3))] = (ushort)v[i];
        }
    }
    // stage V^T [g][t]
    {
        int s = tid & 127, gh = tid >> 7;
        const ushort* vsrc = &QKV[(row0 + s) * QKVLD + 2 * DHAT_ + h * G_ + gh * 32];
        #pragma unroll
        for (int w = 0; w < 4; ++w) {
            bf16x8 v = *reinterpret_cast<const bf16x8*>(&vsrc[w * 8]);
            #pragma unroll
            for (int i = 0; i < 8; ++i) {
                int g = gh * 32 + w * 8 + i;
                VsT[g * 128 + (s ^ ((g & 7) << 3))] = (ushort)v[i];
            }
        }
    }
    __syncthreads();

    // wave w owns g-tile w, f-tiles 0..1
    f32x4 sacc[2];
    sacc[0] = (f32x4){0.f, 0.f, 0.f, 0.f};
    sacc[1] = (f32x4){0.f, 0.f, 0.f, 0.f};
    const int g = wave * 16 + l16;
    #pragma unroll
    for (int ks = 0; ks < 4; ++ks) {
        int sl = ks * 4 + lk;
        bf16x8 bv = *reinterpret_cast<const bf16x8*>(&VsT[g * 128 + ((sl ^ (g & 7)) << 3)]);
        #pragma unroll
        for (int m = 0; m < 2; ++m) {
            int f = m * 16 + l16;
            bf16x8 ak = *reinterpret_cast<const bf16x8*>(&KsT[f * 128 + ((sl ^ (f & 7)) << 3)]);
            sacc[m] = __builtin_amdgcn_mfma_f32_16x16x32_bf16(ak, bv, sacc[m], 0, 0, 0);
        }
    }

    const size_t sbase = ((size_t)((b * H_ + h) * NCHUNK + c)) * (F_ * G_);
    #pragma unroll
    for (int m = 0; m < 2; ++m)
        #pragma unroll
        for (int j = 0; j < 4; ++j) {
            int f = m * 16 + lk * 4 + j;
            Sb[sbase + (size_t)f * G_ + g] = sacc[m][j];
        }

    // z[f]
    {
        int f = tid >> 3, i = tid & 7;
        float zs = 0.0f;
        #pragma unroll
        for (int ss = 0; ss < 2; ++ss) {
            int sl = i * 2 + ss;
            bf16x8 kv = *reinterpret_cast<const bf16x8*>(&KsT[f * 128 + ((sl ^ (f & 7)) << 3)]);
            #pragma unroll
            for (int e = 0; e < 8; ++e) zs += bf2f((ushort)kv[e]);
        }
        zs += __shfl_xor(zs, 1);
        zs += __shfl_xor(zs, 2);
        zs += __shfl_xor(zs, 4);
        if (i == 0) zb[((size_t)(b * H_ + h) * NCHUNK + c) * F_ + f] = zs;
    }
}

// ---------------------------------------------------------------------------
// Pass C (MFMA, scan fused): block sums its own S_prefix/z_prefix (L2-hot),
// then P = tril(QK^T); den = rowsum(P)+q.z_prefix; out = (P@V+Q@S)/den.
// ---------------------------------------------------------------------------
__global__ __launch_bounds__(256) void attn_mfma_kernel(
    const ushort* __restrict__ QKV, const float* __restrict__ Sb,
    const float* __restrict__ zb, ushort* __restrict__ Obf)
{
    __shared__ __attribute__((aligned(16))) ushort Qs[128 * 32];   //  8 KB [t][f]  sw64
    __shared__ __attribute__((aligned(16))) ushort Ks[128 * 32];   //  8 KB [s][f]  sw64
    __shared__ __attribute__((aligned(16))) ushort VsT[64 * 128];  // 16 KB [g][s]
    __shared__ __attribute__((aligned(16))) ushort Ss[64 * 32];    //  4 KB [g][f]  sw64
    __shared__ __attribute__((aligned(16))) ushort Ps[128 * 128];  // 32 KB [t][s]  swP
    __shared__ float zl[F_];
    __shared__ float denl[CHUNK];

    const int c = blockIdx.x, h = blockIdx.y, b = blockIdx.z;
    const int tid = threadIdx.x;
    const int lane = tid & 63, wave = tid >> 6;
    const int l16 = lane & 15, lk = lane >> 4;
    const size_t row0 = (size_t)b * N_ + (size_t)c * CHUNK;
    const int bh = b * H_ + h;

    // stage Q, K (source pre-swizzled -> linear LDS)
    #pragma unroll
    for (int r = 0; r < 2; ++r) {
        int fi = r * 256 + tid;
        int row = fi >> 2;
        int c8 = ((fi & 3) ^ sw64(row)) << 3;
        GLOAD_LDS16(&QKV[(row0 + row) * QKVLD + h * F_ + c8], &Qs[fi * 8]);
        GLOAD_LDS16(&QKV[(row0 + row) * QKVLD + DHAT_ + h * F_ + c8], &Ks[fi * 8]);
    }
    // S_prefix: sum fp32 chunk states cc < c, cvt bf16, write Ss [g][f] sw64
    {
        int g = tid >> 2, f0 = (tid & 3) << 3;
        float s[8] = {};
        for (int cc = 0; cc < c; ++cc) {
            const float* sp = &Sb[((size_t)bh * NCHUNK + cc) * (F_ * G_)];
            #pragma unroll
            for (int i = 0; i < 8; ++i) s[i] += sp[(size_t)(f0 + i) * G_ + g];
        }
        bf16x8 w;
        #pragma unroll
        for (int i = 0; i < 8; ++i) w[i] = (short)f2bf(s[i]);
        *reinterpret_cast<bf16x8*>(&Ss[g * 32 + ((((f0 >> 3)) ^ sw64(g)) << 3)]) = w;
    }
    // z_prefix
    if (tid < F_) {
        float pz = 0.0f;
        for (int cc = 0; cc < c; ++cc)
            pz += zb[((size_t)bh * NCHUNK + cc) * F_ + tid];
        zl[tid] = pz;
    }
    // stage V transposed [g][s]
    {
        int s = tid & 127, gh = tid >> 7;
        const ushort* vsrc = &QKV[(row0 + s) * QKVLD + 2 * DHAT_ + h * G_ + gh * 32];
        #pragma unroll
        for (int w = 0; w < 4; ++w) {
            bf16x8 v = *reinterpret_cast<const bf16x8*>(&vsrc[w * 8]);
            #pragma unroll
            for (int i = 0; i < 8; ++i) {
                int g = gh * 32 + w * 8 + i;
                VsT[g * 128 + (s ^ ((g & 7) << 3))] = (ushort)v[i];
            }
        }
    }
    __syncthreads();

    const int mbase = wave * 32;

    bf16x8 aq[2];
    #pragma unroll
    for (int m = 0; m < 2; ++m) {
        int row = mbase + m * 16 + l16;
        aq[m] = *reinterpret_cast<const bf16x8*>(&Qs[row * 32 + ((lk ^ sw64(row)) << 3)]);
    }

    // P = Q K^T (wave's 32 rows x 128 cols)
    f32x4 p[2][8];
    #pragma unroll
    for (int m = 0; m < 2; ++m)
        #pragma unroll
        for (int n = 0; n < 8; ++n)
            p[m][n] = (f32x4){0.f, 0.f, 0.f, 0.f};
    #pragma unroll
    for (int n = 0; n < 8; ++n) {
        int srow = n * 16 + l16;
        bf16x8 bk = *reinterpret_cast<const bf16x8*>(&Ks[srow * 32 + ((lk ^ sw64(srow)) << 3)]);
        p[0][n] = __builtin_amdgcn_mfma_f32_16x16x32_bf16(aq[0], bk, p[0][n], 0, 0, 0);
        p[1][n] = __builtin_amdgcn_mfma_f32_16x16x32_bf16(aq[1], bk, p[1][n], 0, 0, 0);
    }

    // causal mask + cvt + store Ps (swizzled)
    #pragma unroll
    for (int m = 0; m < 2; ++m)
        #pragma unroll
        for (int n = 0; n < 8; ++n) {
            int s = n * 16 + l16;
            #pragma unroll
            for (int j = 0; j < 4; ++j) {
                int t = mbase + m * 16 + lk * 4 + j;
                float v = (s <= t) ? p[m][n][j] : 0.0f;
                Ps[t * 128 + ((s & 7) | (((s >> 3) ^ swP(t)) << 3))] = f2bf(v);
            }
        }

    // den[t]
    {
        int t = tid >> 1, h2 = tid & 1;
        float rs = 0.0f;
        #pragma unroll
        for (int r = 0; r < 8; ++r) {
            int sl = h2 * 8 + r;
            bf16x8 pv = *reinterpret_cast<const bf16x8*>(&Ps[t * 128 + ((sl ^ swP(t)) << 3)]);
            #pragma unroll
            for (int i = 0; i < 8; ++i) rs += bf2f((ushort)pv[i]);
        }
        #pragma unroll
        for (int ss = 0; ss < 2; ++ss) {
            int sl = h2 * 2 + ss;
            bf16x8 qv = *reinterpret_cast<const bf16x8*>(&Qs[t * 32 + ((sl ^ sw64(t)) << 3)]);
            #pragma unroll
            for (int i = 0; i < 8; ++i) rs += bf2f((ushort)qv[i]) * zl[sl * 8 + i];
        }
        rs += __shfl_xor(rs, 1);
        if (h2 == 0) denl[t] = rs + 1e-6f;
    }

    // out = Q @ S_prefix + P @ V
    f32x4 o[2][4];
    #pragma unroll
    for (int m = 0; m < 2; ++m)
        #pragma unroll
        for (int n = 0; n < 4; ++n)
            o[m][n] = (f32x4){0.f, 0.f, 0.f, 0.f};
    #pragma unroll
    for (int n = 0; n < 4; ++n) {
        int g = n * 16 + l16;
        bf16x8 bs = *reinterpret_cast<const bf16x8*>(&Ss[g * 32 + ((lk ^ sw64(g)) << 3)]);
        o[0][n] = __builtin_amdgcn_mfma_f32_16x16x32_bf16(aq[0], bs, o[0][n], 0, 0, 0);
        o[1][n] = __builtin_amdgcn_mfma_f32_16x16x32_bf16(aq[1], bs, o[1][n], 0, 0, 0);
    }
    #pragma unroll
    for (int ks = 0; ks < 4; ++ks) {
        bf16x8 ap[2];
        #pragma unroll
        for (int m = 0; m < 2; ++m) {
            int t = mbase + m * 16 + l16;
            int sl = ks * 4 + lk;
            ap[m] = *reinterpret_cast<const bf16x8*>(&Ps[t * 128 + ((sl ^ swP(t)) << 3)]);
        }
        #pragma unroll
        for (int n = 0; n < 4; ++n) {
            int g = n * 16 + l16;
            bf16x8 bv = *reinterpret_cast<const bf16x8*>(&VsT[g * 128 + (((ks * 4 + lk) ^ (g & 7)) << 3)]);
            o[0][n] = __builtin_amdgcn_mfma_f32_16x16x32_bf16(ap[0], bv, o[0][n], 0, 0, 0);
            o[1][n] = __builtin_amdgcn_mfma_f32_16x16x32_bf16(ap[1], bv, o[1][n], 0, 0, 0);
        }
    }

    // epilogue
    #pragma unroll
    for (int m = 0; m < 2; ++m)
        #pragma unroll
        for (int j = 0; j < 4; ++j) {
            int t = mbase + m * 16 + lk * 4 + j;
            float rinv = 1.0f / denl[t];
            #pragma unroll
            for (int n = 0; n < 4; ++n) {
                int g = n * 16 + l16;
                Obf[(row0 + t) * D_ + h * G_ + g] = f2bf(o[m][n][j] * rinv);
            }
        }
}

// ---------------------------------------------------------------------------
extern "C" void kernel_launch(void* const* d_in, const int* in_sizes, int n_in,
                              void* d_out, int out_size, void* d_ws, size_t ws_size,
                              hipStream_t stream) {
    const float* x  = (const float*)d_in[0];
    const float* wq = (const float*)d_in[1];
    const float* bq = (const float*)d_in[2];
    const float* wk = (const float*)d_in[3];
    const float* bk = (const float*)d_in[4];
    const float* wv = (const float*)d_in[5];
    const float* bv = (const float*)d_in[6];
    const float* wo = (const float*)d_in[7];
    const float* bo = (const float*)d_in[8];
    float* out = (float*)d_out;

    size_t off = 0;
    char* base = (char*)d_ws;
    auto alloc = [&](size_t bytes) -> void* {
        void* p = base + off;
        off += (bytes + 255) & ~(size_t)255;
        return p;
    };
    const size_t MN = (size_t)B_ * N_;   // 4096
    ushort* QKV   = (ushort*)alloc(MN * QKVLD * 2);
    float*  Sb    = (float*) alloc((size_t)B_ * H_ * NCHUNK * F_ * G_ * 4);
    float*  zb    = (float*) alloc((size_t)B_ * H_ * NCHUNK * F_ * 4);
    ushort* xbf   = (ushort*)alloc(MN * D_ * 2);
    ushort* wqkvT = (ushort*)alloc((size_t)QKVLD * D_ * 2);
    ushort* wot   = (ushort*)alloc((size_t)D_ * D_ * 2);
    float*  bqkv  = (float*) alloc((size_t)QKVLD * 4);
    ushort* obf   = (ushort*)alloc(MN * D_ * 2);

    const int M = (int)MN;   // 4096

    // one prep launch: convert + 4 transposes + bias pack
    prep_kernel<<<dim3(7176), 256, 0, stream>>>(
        x, wq, wk, wv, wo, bq, bk, bv, xbf, wqkvT, wot, bqkv);

    // fused QKV projection: BM=64 -> grid (16,64) = 1024 WGs = 4 blocks/CU
    mfma_gemm_kernel<true, 128><<<dim3(QKVLD / 128, M / 64), 256, 0, stream>>>(
        xbf, wqkvT, bqkv, QKV, M, D_, QKVLD, 2 * DHAT_);

    // chunked linear attention (scan fused into attn)
    chunk_kv_kernel<<<dim3(NCHUNK, H_, B_), 256, 0, stream>>>(QKV, Sb, zb);
    attn_mfma_kernel<<<dim3(NCHUNK, H_, B_), 256, 0, stream>>>(QKV, Sb, zb, obf);

    // output projection: BM=64/BN=64 -> grid (16,64) = 1024 WGs = 4 blocks/CU
    mfma_gemm_kernel<false, 64><<<dim3(D_ / 64, M / 64), 256, 0, stream>>>(
        obf, wot, bo, out, M, D_, D_, 0);
}